// Round 7
// baseline (124.439 us; speedup 1.0000x reference)
//
#include <hip/hip_runtime.h>

typedef unsigned short u16;
typedef float f32x4 __attribute__((ext_vector_type(4)));
typedef unsigned short u16x8 __attribute__((ext_vector_type(8)));
typedef unsigned short u16x4 __attribute__((ext_vector_type(4)));
typedef unsigned short u16x2 __attribute__((ext_vector_type(2)));
typedef __bf16 bf16x8 __attribute__((ext_vector_type(8)));

union Frag { u16x8 u; bf16x8 b; };
union Frag44 { u16x4 h[2]; u16x8 u; bf16x8 b; };
union Frag22 { u16x2 q[4]; u16x8 u; bf16x8 b; };

#define DEVFN static __device__ __forceinline__

DEVFN u16 f2bf(float f) {
  unsigned u = __builtin_bit_cast(unsigned, f);
  u += 0x7FFFu + ((u >> 16) & 1u);
  return (u16)(u >> 16);
}
DEVFN float bf2f(u16 h) {
  return __builtin_bit_cast(float, ((unsigned)h) << 16);
}
DEVFN int bswz(int n, int k) { return k ^ ((((n >> 4) ^ n) & 7) << 3); }

DEVFN void gl16(const u16* g, u16* l) {
  __builtin_amdgcn_global_load_lds(
      (const __attribute__((address_space(1))) unsigned int*)g,
      (__attribute__((address_space(3))) unsigned int*)l, 16, 0, 0);
}

// combined scale folded into Q: softmax(s*SCALE) == normalize(2^(s*SCALE*log2e))
#define QSC (0.17677669529663687f * 1.44269504088896341f)

// ---------------- prep ----------------
__global__ __launch_bounds__(256) void k_prep(
    const float* __restrict__ w_qkv, const float* __restrict__ w_v,
    const float* __restrict__ w_proj, const float* __restrict__ w_temp,
    const float* __restrict__ b_temp,
    u16* __restrict__ w_qt, float* __restrict__ qbias,
    u16* __restrict__ w_qkv_bf, u16* __restrict__ w_proj_bf) {
  __shared__ float wvr[256];
  __shared__ float red[256];
  int t = threadIdx.x, blk = blockIdx.x;
  if (blk < 256) {
    wvr[t] = w_v[blk * 256 + t];
    __syncthreads();
    for (int c = t; c < 512; c += 256) {
      float acc = 0.f;
      for (int m = 0; m < 256; ++m) acc += wvr[m] * w_temp[m * 512 + c];
      w_qt[blk * 512 + c] = f2bf(acc);
    }
    red[t] = wvr[t] * b_temp[t];
    __syncthreads();
    for (int s = 128; s > 0; s >>= 1) {
      if (t < s) red[t] += red[t + s];
      __syncthreads();
    }
    if (t == 0) qbias[blk] = red[0];
  } else {
    int e = (blk - 256) * 256 + t;
    if (e < 512 * 256) w_qkv_bf[e] = f2bf(w_qkv[e]);
    else {
      int e2 = e - 512 * 256;
      w_proj_bf[e2] = f2bf(w_proj[e2]);
    }
  }
}

// ---------------- x transpose+cvt: [b][c=256][p=4096] f32 -> [b][p][c] bf16 ----------------
__global__ __launch_bounds__(256) void k_xt(
    const float* __restrict__ x, u16* __restrict__ xt) {
  __shared__ float lds[64][65];
  int t = threadIdx.x, bid = blockIdx.x;
  int b = bid >> 8, rem = bid & 255;
  int c0 = (rem >> 6) << 6;
  int p0 = (rem & 63) << 6;
  int cr = t >> 2, pc = (t & 3) * 16;
  const float* src = x + (size_t)(b * 256 + c0 + cr) * 4096 + p0 + pc;
#pragma unroll
  for (int i = 0; i < 4; ++i) {
    f32x4 v = *(const f32x4*)(src + 4 * i);
#pragma unroll
    for (int j = 0; j < 4; ++j) lds[cr][pc + 4 * i + j] = v[j];
  }
  __syncthreads();
  int pr = t >> 2, cq = (t & 3) * 16;
  u16x8 o0, o1;
#pragma unroll
  for (int j = 0; j < 8; ++j) {
    o0[j] = f2bf(lds[cq + j][pr]);
    o1[j] = f2bf(lds[cq + 8 + j][pr]);
  }
  u16* dst = xt + ((size_t)(b * 4096) + p0 + pr) * 256 + c0 + cq;
  *(u16x8*)dst = o0;
  *(u16x8*)(dst + 8) = o1;
}

// ---------------- qsmall GEMM (64x64, reg staging, f32 B) ----------------
__global__ __launch_bounds__(256) void k_gemm0(
    const u16* __restrict__ A, const float* __restrict__ Bf, float* __restrict__ Cf) {
  constexpr int N = 256, K = 512;
  const int t = threadIdx.x;
  const int lane = t & 63;
  const int wv = t >> 6;
  const int n0 = blockIdx.x * 64;
  const int m0 = blockIdx.y * 64;
  const int b = blockIdx.z;

  __shared__ __align__(16) u16 lds[2 * 64 * 72];
  u16(*lds_a)[72] = (u16(*)[72])lds;
  u16(*lds_b)[72] = (u16(*)[72])(lds + 64 * 72);

  f32x4 acc[2][2] = {};
  const int mq = (wv >> 1) * 32, nq = (wv & 1) * 32;
  const int lr = lane & 15, lg = lane >> 4;

  for (int k0 = 0; k0 < K; k0 += 64) {
    __syncthreads();
    {
      int m = t >> 2, c0 = (t & 3) * 16;
      const u16* src = A + (size_t)(m0 + m) * K + k0 + c0;
      *(u16x8*)&lds_a[m][c0] = *(const u16x8*)src;
      *(u16x8*)&lds_a[m][c0 + 8] = *(const u16x8*)(src + 8);
    }
    {
      int k = t >> 2, nn0 = (t & 3) * 16;
      const float* src = Bf + (size_t)b * K * N + (size_t)(k0 + k) * N + n0 + nn0;
#pragma unroll
      for (int i4 = 0; i4 < 4; ++i4) {
        f32x4 v = *(const f32x4*)(src + i4 * 4);
#pragma unroll
        for (int j = 0; j < 4; ++j) {
          int n = nn0 + i4 * 4 + j;
          lds_b[n][bswz(n, k)] = f2bf(v[j]);
        }
      }
    }
    __syncthreads();
#pragma unroll
    for (int kk = 0; kk < 2; ++kk) {
      Frag af[2], bfr[2];
#pragma unroll
      for (int i = 0; i < 2; ++i) {
        af[i].u = *(const u16x8*)&lds_a[mq + 16 * i + lr][kk * 32 + 8 * lg];
        int n = nq + 16 * i + lr;
        bfr[i].u = *(const u16x8*)&lds_b[n][bswz(n, kk * 32 + 8 * lg)];
      }
#pragma unroll
      for (int mi = 0; mi < 2; ++mi)
#pragma unroll
        for (int ni = 0; ni < 2; ++ni)
          acc[mi][ni] = __builtin_amdgcn_mfma_f32_16x16x32_bf16(
              af[mi].b, bfr[ni].b, acc[mi][ni], 0, 0, 0);
    }
  }
#pragma unroll
  for (int mi = 0; mi < 2; ++mi)
#pragma unroll
    for (int ni = 0; ni < 2; ++ni) {
      int mbase = m0 + mq + 16 * mi + 4 * lg;
      int n = n0 + nq + 16 * ni + lr;
      *(f32x4*)(Cf + ((size_t)b * 256 + n) * 256 + mbase) = acc[mi][ni];
    }
}

// ---------------- DMA-staged 64x128 GEMM ----------------
// V=1: kv = w_qkv[512x256] x x_t[N][K] -> Kb [b][h][p][d] (m<256), Vt [b][h][d][p] (m>=256)
// V=2: out = w_proj[256x256] x o_buf[N][K] + bias + x -> f32
template <int V>
__global__ __launch_bounds__(256) void k_gemmx(
    const u16* __restrict__ A, const u16* __restrict__ Bh, float* __restrict__ Cf,
    u16* __restrict__ Kb, u16* __restrict__ Vt,
    const float* __restrict__ bias, const float* __restrict__ Xres) {
  const int t = threadIdx.x, lane = t & 63, wv = t >> 6;
  const int lr = lane & 15, lg = lane >> 4;
  // XCD-grouped decode: blocks sharing a B tile land on the same XCD slot
  int bid = blockIdx.x;
  int s = bid & 7, w = bid >> 3;
  int gid, mt;
  if constexpr (V == 1) { gid = (w & ~7) | s; mt = w & 7; }
  else { gid = ((w >> 2) << 3) | s; mt = w & 3; }
  const int nt = gid & 31, b = gid >> 5;
  const int m0 = mt * 64, n0 = nt * 128;

  __shared__ __align__(16) u16 ldsAB[192 * 64];  // A rows 0..63, B rows 64..191, linear + src-swizzled

  f32x4 acc[2][4] = {};
  const int mq = (wv >> 1) * 32, nq = (wv & 1) * 64;
  const size_t bOff = (size_t)b * 4096 * 256;
  const int sub = lane >> 3, c = lane & 7;

  for (int k0 = 0; k0 < 256; k0 += 64) {
    __syncthreads();
#pragma unroll
    for (int i = wv; i < 24; i += 4) {
      const u16* g;
      if (i < 8) g = A + (size_t)(m0 + i * 8 + sub) * 256 + k0 + ((c ^ sub) << 3);
      else g = Bh + bOff + (size_t)(n0 + i * 8 + sub - 64) * 256 + k0 + ((c ^ sub) << 3);
      gl16(g, &ldsAB[i * 512]);
    }
    __syncthreads();
#pragma unroll
    for (int kk = 0; kk < 2; ++kk) {
      Frag af[2], bfr[4];
#pragma unroll
      for (int mi = 0; mi < 2; ++mi) {
        int r = mq + 16 * mi + lr;
        af[mi].u = *(const u16x8*)&ldsAB[r * 64 + (((kk * 4 + lg) ^ (r & 7)) << 3)];
      }
#pragma unroll
      for (int ni = 0; ni < 4; ++ni) {
        int rn = nq + 16 * ni + lr;
        bfr[ni].u = *(const u16x8*)&ldsAB[(64 + rn) * 64 + (((kk * 4 + lg) ^ (rn & 7)) << 3)];
      }
#pragma unroll
      for (int mi = 0; mi < 2; ++mi)
#pragma unroll
        for (int ni = 0; ni < 4; ++ni)
          acc[mi][ni] = __builtin_amdgcn_mfma_f32_16x16x32_bf16(
              af[mi].b, bfr[ni].b, acc[mi][ni], 0, 0, 0);
    }
  }

  if constexpr (V == 1) {
    if (m0 < 256) {  // K heads -> Kb [b][h][p][d]
#pragma unroll
      for (int mi = 0; mi < 2; ++mi)
#pragma unroll
        for (int ni = 0; ni < 4; ++ni) {
          int mbase = m0 + mq + 16 * mi + 4 * lg;
          int n = n0 + nq + 16 * ni + lr;
          u16x4 pk;
#pragma unroll
          for (int j = 0; j < 4; ++j) pk[j] = f2bf(acc[mi][ni][j]);
          int head = mbase >> 5, d = mbase & 31;
          *(u16x4*)(Kb + ((size_t)(b * 8 + head) * 4096 + n) * 32 + d) = pk;
        }
    } else {  // V heads -> Vt [b][h][d][p] via 2-round LDS transpose
      float(*lds_t)[68] = (float(*)[68])ldsAB;
#pragma unroll 1
      for (int r = 0; r < 2; ++r) {
        __syncthreads();
        if ((wv & 1) == r) {
#pragma unroll
          for (int mi = 0; mi < 2; ++mi)
#pragma unroll
            for (int ni = 0; ni < 4; ++ni)
#pragma unroll
              for (int j = 0; j < 4; ++j)
                lds_t[mq + 16 * mi + 4 * lg + j][16 * ni + lr] = acc[mi][ni][j];
        }
        __syncthreads();
        int dloc = t >> 2, nc = (t & 3) * 16;
        int dg = (m0 - 256) + dloc;
        int head = dg >> 5, d = dg & 31;
        u16x8 o0, o1;
#pragma unroll
        for (int i = 0; i < 8; ++i) {
          o0[i] = f2bf(lds_t[dloc][nc + i]);
          o1[i] = f2bf(lds_t[dloc][nc + 8 + i]);
        }
        u16* dst = Vt + ((size_t)(b * 8 + head) * 32 + d) * 4096 + n0 + 64 * r + nc;
        *(u16x8*)dst = o0;
        *(u16x8*)(dst + 8) = o1;
      }
    }
  } else {
#pragma unroll
    for (int mi = 0; mi < 2; ++mi)
#pragma unroll
      for (int ni = 0; ni < 4; ++ni) {
        int mbase = m0 + mq + 16 * mi + 4 * lg;
        int n = n0 + nq + 16 * ni + lr;
#pragma unroll
        for (int j = 0; j < 4; ++j) {
          int m = mbase + j;
          size_t off = ((size_t)b * 256 + m) * 4096 + n;
          Cf[off] = acc[mi][ni][j] + bias[m] + Xres[off];
        }
      }
  }
}

// ---------------- bilinear 16x16 -> 64x64 upsample of qsmall, + qbias, * QSC ----------------
DEVFN void blc(int y, int& i0, int& i1, float& w) {
  float fy = 0.25f * y - 0.375f;
  float ff = floorf(fy);
  w = fy - ff;
  int i = (int)ff;
  i0 = i < 0 ? 0 : i;
  i1 = (i + 1 > 15) ? 15 : i + 1;
}

__global__ __launch_bounds__(256) void k_resize(
    const float* __restrict__ qsmall, const float* __restrict__ qbias,
    u16* __restrict__ Qb) {
  int gid = blockIdx.x * 256 + threadIdx.x;
  int c8 = gid & 31;
  int p = (gid >> 5) & 4095;
  int b = gid >> 17;
  int y = p >> 6, x = p & 63;
  int y0, y1, x0, x1;
  float wy, wx;
  blc(y, y0, y1, wy);
  blc(x, x0, x1, wx);
  const float* base = qsmall + (size_t)b * 65536;
  int o0 = c8 * 8;
  const float* r00 = base + (y0 * 16 + x0) * 256 + o0;
  const float* r01 = base + (y0 * 16 + x1) * 256 + o0;
  const float* r10 = base + (y1 * 16 + x0) * 256 + o0;
  const float* r11 = base + (y1 * 16 + x1) * 256 + o0;
  float w00 = (1 - wy) * (1 - wx), w01 = (1 - wy) * wx;
  float w10 = wy * (1 - wx), w11 = wy * wx;
  u16x8 outv;
#pragma unroll
  for (int i = 0; i < 8; ++i) {
    float v = w00 * r00[i] + w01 * r01[i] + w10 * r10[i] + w11 * r11[i] + qbias[o0 + i];
    outv[i] = f2bf(v * QSC);
  }
  int head = o0 >> 5, d = o0 & 31;
  *(u16x8*)(Qb + ((size_t)(b * 8 + head) * 4096 + p) * 32 + d) = outv;
}

// ---------------- MFMA attention (all heads) ----------------
// P-network NOTE: ds_bpermute pulls the SOURCE lane's data operand, so the
// half-select must happen at the DESTINATION, after the permute. Full path:
// 8 bpermutes (pk0..pk3 raw) + dest-side selects. ws4/ws2: 4 bpermutes + select-0.
__global__ __launch_bounds__(256) void k_attn(
    const u16* __restrict__ Qb, const u16* __restrict__ Kb,
    const u16* __restrict__ Vt, u16* __restrict__ Ob) {
  const int t = threadIdx.x, lane = t & 63, wv = t >> 6;
  const int lr = lane & 15, lg = lane >> 4;
  const int bid = blockIdx.x;
  const bool split = (bid < 512);

  __shared__ float sm_o[4][4][4][64];  // [wave][frag][j][lane], one h-phase at a time
  __shared__ float sm_l[4][4][16];

  const int addrA = (32 * (lg & 1) + lr) * 4;
  const int addrB = addrA + 64;
  const bool lo_half = (lg < 2);

  // 4-bpermute network for 16-key paths (second half zero)
  auto pnet16 = [&](unsigned pk0, unsigned pk1, Frag& out) {
    union { unsigned w[4]; Frag fr; } pb;
    int a0 = __builtin_amdgcn_ds_bpermute(addrA, (int)pk0);
    int a1 = __builtin_amdgcn_ds_bpermute(addrA, (int)pk1);
    int a2 = __builtin_amdgcn_ds_bpermute(addrB, (int)pk0);
    int a3 = __builtin_amdgcn_ds_bpermute(addrB, (int)pk1);
    pb.w[0] = lo_half ? (unsigned)a0 : 0u;
    pb.w[1] = lo_half ? (unsigned)a1 : 0u;
    pb.w[2] = lo_half ? (unsigned)a2 : 0u;
    pb.w[3] = lo_half ? (unsigned)a3 : 0u;
    out = pb.fr;
  };

  int b, head, lws, i0, by, bx, j_begin, j_end;
  if (split) {
    int idx = bid;
    b = idx >> 6;
    int qg = idx & 63;
    head = 4; lws = 5;
    int w = qg >> 4;
    i0 = (qg & 15) * 64;
    by = (w >> 1) * 32;
    bx = (w & 1) * 32;
    j_begin = wv * 256;
    j_end = j_begin + 256;
  } else {
    int u = (bid - 512) * 4 + wv;
    if (u >= 3072) {  // ---- ws=2 (head 0): 4 windows of 4 keys per frag, masked ----
      int r = u - 3072;
      int b2 = r >> 6;
      int qw = r & 63;
      const size_t hb0 = (size_t)(b2 * 8 + 0) * 131072;
      const u16* vb0 = Vt + hb0 + (size_t)lr * 4096;
      const u16* vb1 = Vt + hb0 + (size_t)(16 + lr) * 4096;
      const bool valid = (lg == (lr >> 2));
      const int lgm = lg & 1;
#pragma unroll
      for (int f = 0; f < 4; ++f) {
        int g = qw * 4 + f;              // frag index: windows g*4 .. g*4+3
        int W = g * 4 + (lr >> 2);       // this lane's window (q slot lr)
        int wbase = (W >> 5) * 128 + (W & 31) * 2;
        int qj = lr & 3;
        int posq = wbase + ((qj >> 1) << 6) + (qj & 1);
        Frag qf2, kf2;
        qf2.u = *(const u16x8*)(Qb + hb0 + (size_t)posq * 32 + 8 * lg);
        kf2.u = *(const u16x8*)(Kb + hb0 + (size_t)posq * 32 + 8 * lg);
        int W0 = g * 4 + 2 * lgm;
        int base0 = (W0 >> 5) * 128 + (W0 & 31) * 2;
        int W1 = W0 + 1;
        int base1 = (W1 >> 5) * 128 + (W1 & 31) * 2;
        Frag22 v0u, v1u;
        v0u.q[0] = *(const u16x2*)(vb0 + base0);
        v0u.q[1] = *(const u16x2*)(vb0 + base0 + 64);
        v0u.q[2] = *(const u16x2*)(vb0 + base1);
        v0u.q[3] = *(const u16x2*)(vb0 + base1 + 64);
        v1u.q[0] = *(const u16x2*)(vb1 + base0);
        v1u.q[1] = *(const u16x2*)(vb1 + base0 + 64);
        v1u.q[2] = *(const u16x2*)(vb1 + base1);
        v1u.q[3] = *(const u16x2*)(vb1 + base1 + 64);
        f32x4 zz = {};
        f32x4 s0 = __builtin_amdgcn_mfma_f32_16x16x32_bf16(kf2.b, qf2.b, zz, 0, 0, 0);
        float p[4];
        float ls = 0.f;
#pragma unroll
        for (int j = 0; j < 4; ++j) {
          p[j] = valid ? exp2f(s0[j]) : 0.f;
          ls += p[j];
        }
        unsigned pk0, pk1;
        asm("v_cvt_pk_bf16_f32 %0, %1, %2" : "=v"(pk0) : "v"(p[0]), "v"(p[1]));
        asm("v_cvt_pk_bf16_f32 %0, %1, %2" : "=v"(pk1) : "v"(p[2]), "v"(p[3]));
        Frag pfr;
        pnet16(pk0, pk1, pfr);
        f32x4 o0 = {}, o1 = {};
        o0 = __builtin_amdgcn_mfma_f32_16x16x32_bf16(v0u.b, pfr.b, o0, 0, 0, 0);
        o1 = __builtin_amdgcn_mfma_f32_16x16x32_bf16(v1u.b, pfr.b, o1, 0, 0, 0);
        ls += __shfl_xor(ls, 16, 64);
        ls += __shfl_xor(ls, 32, 64);
        float inv = 1.f / ls;
        u16x4 lo4, hi4;
#pragma unroll
        for (int j = 0; j < 4; ++j) {
          lo4[j] = f2bf(o0[j] * inv);
          hi4[j] = f2bf(o1[j] * inv);
        }
        u16* dst = Ob + ((size_t)b2 * 4096 + posq) * 256;
        *(u16x4*)(dst + 4 * lg) = lo4;
        *(u16x4*)(dst + 16 + 4 * lg) = hi4;
      }
      return;
    }
    if (u >= 2560) {  // ---- ws=4 (head 1) ----
      int r = u - 2560;
      int b4 = r >> 6;
      int qw = r & 63;
      const size_t hb1 = (size_t)(b4 * 8 + 1) * 131072;
      const u16* vb0 = Vt + hb1 + (size_t)lr * 4096;
      const u16* vb1 = Vt + hb1 + (size_t)(16 + lr) * 4096;
#pragma unroll
      for (int f = 0; f < 4; ++f) {
        int w = qw * 4 + f;
        int pbase = ((w >> 4) << 8) + ((w & 15) << 2);
        int posq = pbase + ((lr >> 2) << 6) + (lr & 3);
        Frag qf4, kf4;
        qf4.u = *(const u16x8*)(Qb + hb1 + (size_t)posq * 32 + 8 * lg);
        kf4.u = *(const u16x8*)(Kb + hb1 + (size_t)posq * 32 + 8 * lg);
        int a1 = pbase + 2 * (lg & 1) * 64;
        Frag44 v0u, v1u;
        v0u.h[0] = *(const u16x4*)(vb0 + a1);
        v0u.h[1] = *(const u16x4*)(vb0 + a1 + 64);
        v1u.h[0] = *(const u16x4*)(vb1 + a1);
        v1u.h[1] = *(const u16x4*)(vb1 + a1 + 64);
        f32x4 zz = {};
        f32x4 s0 = __builtin_amdgcn_mfma_f32_16x16x32_bf16(kf4.b, qf4.b, zz, 0, 0, 0);
        float p[4];
        float ls = 0.f;
#pragma unroll
        for (int j = 0; j < 4; ++j) {
          p[j] = exp2f(s0[j]);
          ls += p[j];
        }
        unsigned pk0, pk1;
        asm("v_cvt_pk_bf16_f32 %0, %1, %2" : "=v"(pk0) : "v"(p[0]), "v"(p[1]));
        asm("v_cvt_pk_bf16_f32 %0, %1, %2" : "=v"(pk1) : "v"(p[2]), "v"(p[3]));
        Frag pfr;
        pnet16(pk0, pk1, pfr);
        f32x4 o0 = {}, o1 = {};
        o0 = __builtin_amdgcn_mfma_f32_16x16x32_bf16(v0u.b, pfr.b, o0, 0, 0, 0);
        o1 = __builtin_amdgcn_mfma_f32_16x16x32_bf16(v1u.b, pfr.b, o1, 0, 0, 0);
        ls += __shfl_xor(ls, 16, 64);
        ls += __shfl_xor(ls, 32, 64);
        float inv = 1.f / ls;
        u16x4 lo4, hi4;
#pragma unroll
        for (int j = 0; j < 4; ++j) {
          lo4[j] = f2bf(o0[j] * inv);
          hi4[j] = f2bf(o1[j] * inv);
        }
        u16* dst = Ob + ((size_t)b4 * 4096 + posq) * 256 + 32;
        *(u16x4*)(dst + 4 * lg) = lo4;
        *(u16x4*)(dst + 16 + 4 * lg) = hi4;
      }
      return;
    }
    if (u < 512) {
      head = 3; lws = 4;
      b = u >> 6;
      int qb = (u & 63) << 6;
      int w = qb >> 8;
      i0 = qb & 255;
      by = (w >> 2) * 16;
      bx = (w & 3) * 16;
      j_begin = 0; j_end = 256;
    } else if (u < 1024) {
      head = 2; lws = 3;
      int u2 = u - 512;
      b = u2 >> 6;
      int w = u2 & 63;
      i0 = 0;
      by = (w >> 3) * 8;
      bx = (w & 7) * 8;
      j_begin = 0; j_end = 64;
    } else {
      int r = u - 1024;
      b = r / 192;
      int rr = r % 192;
      head = 5 + (rr >> 6);
      lws = 6;
      by = rr & 63; bx = 0; i0 = 0;
      j_begin = 0; j_end = 64;
    }
  }
  const int wsm = (1 << lws) - 1;
  const size_t hb = (size_t)(b * 8 + head) * 131072;
  auto mapP = [&](int i) { return ((by + (i >> lws)) << 6) + bx + (i & wsm); };

  Frag qf[4];
#pragma unroll
  for (int f = 0; f < 4; ++f)
    qf[f].u = *(const u16x8*)(Qb + hb + (size_t)mapP(i0 + 16 * f + lr) * 32 + 8 * lg);

  f32x4 oT[4][2] = {};
  float lsum[4] = {0.f, 0.f, 0.f, 0.f};

  auto chunk = [&](const Frag& k0, const Frag& k1, const Frag& v0, const Frag& v1) {
#pragma unroll
    for (int f = 0; f < 4; ++f) {
      f32x4 zz = {};
      f32x4 s0 = __builtin_amdgcn_mfma_f32_16x16x32_bf16(k0.b, qf[f].b, zz, 0, 0, 0);
      f32x4 s1 = __builtin_amdgcn_mfma_f32_16x16x32_bf16(k1.b, qf[f].b, zz, 0, 0, 0);
      float p[8];
#pragma unroll
      for (int j = 0; j < 4; ++j) {
        p[j] = exp2f(s0[j]);
        p[4 + j] = exp2f(s1[j]);
      }
#pragma unroll
      for (int j = 0; j < 8; ++j) lsum[f] += p[j];
      unsigned pk0, pk1, pk2, pk3;
      asm("v_cvt_pk_bf16_f32 %0, %1, %2" : "=v"(pk0) : "v"(p[0]), "v"(p[1]));
      asm("v_cvt_pk_bf16_f32 %0, %1, %2" : "=v"(pk1) : "v"(p[2]), "v"(p[3]));
      asm("v_cvt_pk_bf16_f32 %0, %1, %2" : "=v"(pk2) : "v"(p[4]), "v"(p[5]));
      asm("v_cvt_pk_bf16_f32 %0, %1, %2" : "=v"(pk3) : "v"(p[6]), "v"(p[7]));
      int a0 = __builtin_amdgcn_ds_bpermute(addrA, (int)pk0);
      int a1 = __builtin_amdgcn_ds_bpermute(addrA, (int)pk1);
      int a2 = __builtin_amdgcn_ds_bpermute(addrB, (int)pk0);
      int a3 = __builtin_amdgcn_ds_bpermute(addrB, (int)pk1);
      int b0 = __builtin_amdgcn_ds_bpermute(addrA, (int)pk2);
      int b1 = __builtin_amdgcn_ds_bpermute(addrA, (int)pk3);
      int b2 = __builtin_amdgcn_ds_bpermute(addrB, (int)pk2);
      int b3 = __builtin_amdgcn_ds_bpermute(addrB, (int)pk3);
      union { unsigned w[4]; Frag fr; } pb;
      pb.w[0] = (unsigned)(lo_half ? a0 : b0);
      pb.w[1] = (unsigned)(lo_half ? a1 : b1);
      pb.w[2] = (unsigned)(lo_half ? a2 : b2);
      pb.w[3] = (unsigned)(lo_half ? a3 : b3);
      oT[f][0] = __builtin_amdgcn_mfma_f32_16x16x32_bf16(v0.b, pb.fr.b, oT[f][0], 0, 0, 0);
      oT[f][1] = __builtin_amdgcn_mfma_f32_16x16x32_bf16(v1.b, pb.fr.b, oT[f][1], 0, 0, 0);
    }
  };

  Frag k0A, k1A, v0A, v1A, k0B, k1B, v0B, v1B;
  auto loadKV = [&](int j0, Frag& a, Frag& c, Frag& d, Frag& e) {
    a.u = *(const u16x8*)(Kb + hb + (size_t)mapP(j0 + lr) * 32 + 8 * lg);
    c.u = *(const u16x8*)(Kb + hb + (size_t)mapP(j0 + 16 + lr) * 32 + 8 * lg);
    int pv = mapP(j0 + 8 * lg);
    d.u = *(const u16x8*)(Vt + hb + (size_t)lr * 4096 + pv);
    e.u = *(const u16x8*)(Vt + hb + (size_t)(16 + lr) * 4096 + pv);
  };

  loadKV(j_begin, k0A, k1A, v0A, v1A);
  for (int j0 = j_begin; j0 < j_end; j0 += 64) {
    loadKV(j0 + 32, k0B, k1B, v0B, v1B);
    chunk(k0A, k1A, v0A, v1A);
    if (j0 + 64 < j_end) loadKV(j0 + 64, k0A, k1A, v0A, v1A);
    chunk(k0B, k1B, v0B, v1B);
  }

  if (!split) {
#pragma unroll
    for (int f = 0; f < 4; ++f) {
      float s = lsum[f];
      s += __shfl_xor(s, 16, 64);
      s += __shfl_xor(s, 32, 64);
      float inv = 1.f / s;
      int q = i0 + 16 * f + lr;
      u16x4 lo, hi;
#pragma unroll
      for (int j = 0; j < 4; ++j) {
        lo[j] = f2bf(oT[f][0][j] * inv);
        hi[j] = f2bf(oT[f][1][j] * inv);
      }
      if (head < 5) {
        int p = mapP(q);
        u16* dst = Ob + ((size_t)b * 4096 + p) * 256 + head * 32;
        *(u16x4*)(dst + 4 * lg) = lo;
        *(u16x4*)(dst + 16 + 4 * lg) = hi;
      } else {
        int n = head - 5;
        int g32 = ((n * 64 + by) << 6) + q;
        int m3 = g32 % 3, sp = g32 / 3;
        u16* dst = Ob + ((size_t)b * 4096 + sp) * 256 + 160 + 32 * m3;
        *(u16x4*)(dst + 4 * lg) = lo;
        *(u16x4*)(dst + 16 + 4 * lg) = hi;
      }
    }
  } else {
    // split-K combine: two h-phases through 17KB LDS
    float ot0[4], ot1[4];
    float ls = 0.f;
#pragma unroll 1
    for (int h = 0; h < 2; ++h) {
      __syncthreads();
#pragma unroll
      for (int f = 0; f < 4; ++f) {
#pragma unroll
        for (int j = 0; j < 4; ++j) sm_o[wv][f][j][lane] = oT[f][h][j];
        if (h == 0) {
          float s = lsum[f];
          s += __shfl_xor(s, 16, 64);
          s += __shfl_xor(s, 32, 64);
          if (lg == 0) sm_l[wv][f][lr] = s;
        }
      }
      __syncthreads();
      int f = wv;
      float* ot = (h == 0) ? ot0 : ot1;
#pragma unroll
      for (int j = 0; j < 4; ++j) ot[j] = 0.f;
#pragma unroll
      for (int w = 0; w < 4; ++w) {
        if (h == 0) ls += sm_l[w][f][lr];
#pragma unroll
        for (int j = 0; j < 4; ++j) ot[j] += sm_o[w][f][j][lane];
      }
    }
    float inv = 1.f / ls;
    int f = wv;
    int q = i0 + 16 * f + lr;
    int p = mapP(q);
    u16x4 lo, hi;
#pragma unroll
    for (int j = 0; j < 4; ++j) {
      lo[j] = f2bf(ot0[j] * inv);
      hi[j] = f2bf(ot1[j] * inv);
    }
    u16* dst = Ob + ((size_t)b * 4096 + p) * 256 + head * 32;
    *(u16x4*)(dst + 4 * lg) = lo;
    *(u16x4*)(dst + 16 + 4 * lg) = hi;
  }
}

extern "C" void kernel_launch(void* const* d_in, const int* in_sizes, int n_in,
                              void* d_out, int out_size, void* d_ws, size_t ws_size,
                              hipStream_t stream) {
  const float* x = (const float*)d_in[0];
  const float* temp = (const float*)d_in[1];
  const float* w_qkv = (const float*)d_in[2];
  const float* w_v = (const float*)d_in[3];
  const float* w_proj = (const float*)d_in[4];
  const float* b_proj = (const float*)d_in[5];
  const float* w_temp = (const float*)d_in[6];
  const float* b_temp = (const float*)d_in[7];
  (void)in_sizes; (void)n_in; (void)out_size; (void)ws_size;

  char* ws = (char*)d_ws;
  u16* w_qt = (u16*)(ws + 0);              // 262144 B
  u16* w_qkv_bf = (u16*)(ws + 262144);     // 262144 B
  u16* w_proj_bf = (u16*)(ws + 524288);    // 131072 B
  float* qbias = (float*)(ws + 655360);    // 1024 B
  float* qsmall = (float*)(ws + 656384);   // 2097152 B  [b][p16][o]
  u16* q_buf = (u16*)(ws + 2753536);       // 16777216 B [b][h][p][d]
  u16* k_buf = (u16*)(ws + 19530752);      // 16777216 B [b][h][p][d]
  u16* v_t = (u16*)(ws + 53085184);        // 16777216 B [b][h][d][p]
  u16* o_buf = (u16*)(ws + 69862400);      // 16777216 B [b][p][c]  (aliased: x_t before attn)
  u16* x_t = o_buf;                        // [b][p][c] bf16 — dead before o_buf written
  float* out = (float*)d_out;

  k_prep<<<1024, 256, 0, stream>>>(w_qkv, w_v, w_proj, w_temp, b_temp,
                                   w_qt, qbias, w_qkv_bf, w_proj_bf);
  k_xt<<<2048, 256, 0, stream>>>(x, x_t);
  k_gemm0<<<dim3(4, 4, 8), 256, 0, stream>>>(w_qt, temp, qsmall);
  k_resize<<<4096, 256, 0, stream>>>(qsmall, qbias, q_buf);
  k_gemmx<1><<<2048, 256, 0, stream>>>(w_qkv_bf, x_t, nullptr, k_buf, v_t,
                                       nullptr, nullptr);
  k_attn<<<1408, 256, 0, stream>>>(q_buf, k_buf, v_t, o_buf);
  k_gemmx<2><<<1024, 256, 0, stream>>>(w_proj_bf, o_buf, out, nullptr, nullptr,
                                       b_proj, x);
}

// Round 8
// 120.258 us; speedup vs baseline: 1.0348x; 1.0348x over previous
//
#include <hip/hip_runtime.h>

typedef unsigned short u16;
typedef float f32x4 __attribute__((ext_vector_type(4)));
typedef unsigned short u16x8 __attribute__((ext_vector_type(8)));
typedef unsigned short u16x4 __attribute__((ext_vector_type(4)));
typedef unsigned short u16x2 __attribute__((ext_vector_type(2)));
typedef __bf16 bf16x8 __attribute__((ext_vector_type(8)));

union Frag { u16x8 u; bf16x8 b; };
union Frag44 { u16x4 h[2]; u16x8 u; bf16x8 b; };
union Frag22 { u16x2 q[4]; u16x8 u; bf16x8 b; };

#define DEVFN static __device__ __forceinline__

DEVFN u16 f2bf(float f) {
  unsigned u = __builtin_bit_cast(unsigned, f);
  u += 0x7FFFu + ((u >> 16) & 1u);
  return (u16)(u >> 16);
}
DEVFN float bf2f(u16 h) {
  return __builtin_bit_cast(float, ((unsigned)h) << 16);
}
DEVFN int bswz(int n, int k) { return k ^ ((((n >> 4) ^ n) & 7) << 3); }

// raw v_exp_f32: args are bounded (|s| ~< 1) so OCML's range/denormal fixup
// (~6 extra VALU per call) is pure overhead.
DEVFN float fexp2(float x) {
#if __has_builtin(__builtin_amdgcn_exp2f)
  return __builtin_amdgcn_exp2f(x);
#else
  float r;
  asm volatile("v_exp_f32 %0, %1\n\ts_nop 1" : "=v"(r) : "v"(x));
  return r;
#endif
}

DEVFN void gl16(const u16* g, u16* l) {
  __builtin_amdgcn_global_load_lds(
      (const __attribute__((address_space(1))) unsigned int*)g,
      (__attribute__((address_space(3))) unsigned int*)l, 16, 0, 0);
}

// combined scale folded into Q: softmax(s*SCALE) == normalize(2^(s*SCALE*log2e))
#define QSC (0.17677669529663687f * 1.44269504088896341f)

// ---------------- prep ----------------
__global__ __launch_bounds__(256) void k_prep(
    const float* __restrict__ w_qkv, const float* __restrict__ w_v,
    const float* __restrict__ w_proj, const float* __restrict__ w_temp,
    const float* __restrict__ b_temp,
    u16* __restrict__ w_qt, float* __restrict__ qbias,
    u16* __restrict__ w_qkv_bf, u16* __restrict__ w_proj_bf) {
  __shared__ float wvr[256];
  __shared__ float red[256];
  int t = threadIdx.x, blk = blockIdx.x;
  if (blk < 256) {
    wvr[t] = w_v[blk * 256 + t];
    __syncthreads();
    for (int c = t; c < 512; c += 256) {
      float acc = 0.f;
      for (int m = 0; m < 256; ++m) acc += wvr[m] * w_temp[m * 512 + c];
      w_qt[blk * 512 + c] = f2bf(acc);
    }
    red[t] = wvr[t] * b_temp[t];
    __syncthreads();
    for (int s = 128; s > 0; s >>= 1) {
      if (t < s) red[t] += red[t + s];
      __syncthreads();
    }
    if (t == 0) qbias[blk] = red[0];
  } else {
    int e = (blk - 256) * 256 + t;
    if (e < 512 * 256) w_qkv_bf[e] = f2bf(w_qkv[e]);
    else {
      int e2 = e - 512 * 256;
      w_proj_bf[e2] = f2bf(w_proj[e2]);
    }
  }
}

// ---------------- x transpose+cvt: [b][c=256][p=4096] f32 -> [b][p][c] bf16 ----------------
__global__ __launch_bounds__(256) void k_xt(
    const float* __restrict__ x, u16* __restrict__ xt) {
  __shared__ float lds[64][65];
  int t = threadIdx.x, bid = blockIdx.x;
  int b = bid >> 8, rem = bid & 255;
  int c0 = (rem >> 6) << 6;
  int p0 = (rem & 63) << 6;
  int cr = t >> 2, pc = (t & 3) * 16;
  const float* src = x + (size_t)(b * 256 + c0 + cr) * 4096 + p0 + pc;
#pragma unroll
  for (int i = 0; i < 4; ++i) {
    f32x4 v = *(const f32x4*)(src + 4 * i);
#pragma unroll
    for (int j = 0; j < 4; ++j) lds[cr][pc + 4 * i + j] = v[j];
  }
  __syncthreads();
  int pr = t >> 2, cq = (t & 3) * 16;
  u16x8 o0, o1;
#pragma unroll
  for (int j = 0; j < 8; ++j) {
    o0[j] = f2bf(lds[cq + j][pr]);
    o1[j] = f2bf(lds[cq + 8 + j][pr]);
  }
  u16* dst = xt + ((size_t)(b * 4096) + p0 + pr) * 256 + c0 + cq;
  *(u16x8*)dst = o0;
  *(u16x8*)(dst + 8) = o1;
}

// ---------------- qsmall GEMM (64x64, reg staging, f32 B) ----------------
__global__ __launch_bounds__(256) void k_gemm0(
    const u16* __restrict__ A, const float* __restrict__ Bf, float* __restrict__ Cf) {
  constexpr int N = 256, K = 512;
  const int t = threadIdx.x;
  const int lane = t & 63;
  const int wv = t >> 6;
  const int n0 = blockIdx.x * 64;
  const int m0 = blockIdx.y * 64;
  const int b = blockIdx.z;

  __shared__ __align__(16) u16 lds[2 * 64 * 72];
  u16(*lds_a)[72] = (u16(*)[72])lds;
  u16(*lds_b)[72] = (u16(*)[72])(lds + 64 * 72);

  f32x4 acc[2][2] = {};
  const int mq = (wv >> 1) * 32, nq = (wv & 1) * 32;
  const int lr = lane & 15, lg = lane >> 4;

  for (int k0 = 0; k0 < K; k0 += 64) {
    __syncthreads();
    {
      int m = t >> 2, c0 = (t & 3) * 16;
      const u16* src = A + (size_t)(m0 + m) * K + k0 + c0;
      *(u16x8*)&lds_a[m][c0] = *(const u16x8*)src;
      *(u16x8*)&lds_a[m][c0 + 8] = *(const u16x8*)(src + 8);
    }
    {
      int k = t >> 2, nn0 = (t & 3) * 16;
      const float* src = Bf + (size_t)b * K * N + (size_t)(k0 + k) * N + n0 + nn0;
#pragma unroll
      for (int i4 = 0; i4 < 4; ++i4) {
        f32x4 v = *(const f32x4*)(src + i4 * 4);
#pragma unroll
        for (int j = 0; j < 4; ++j) {
          int n = nn0 + i4 * 4 + j;
          lds_b[n][bswz(n, k)] = f2bf(v[j]);
        }
      }
    }
    __syncthreads();
#pragma unroll
    for (int kk = 0; kk < 2; ++kk) {
      Frag af[2], bfr[2];
#pragma unroll
      for (int i = 0; i < 2; ++i) {
        af[i].u = *(const u16x8*)&lds_a[mq + 16 * i + lr][kk * 32 + 8 * lg];
        int n = nq + 16 * i + lr;
        bfr[i].u = *(const u16x8*)&lds_b[n][bswz(n, kk * 32 + 8 * lg)];
      }
#pragma unroll
      for (int mi = 0; mi < 2; ++mi)
#pragma unroll
        for (int ni = 0; ni < 2; ++ni)
          acc[mi][ni] = __builtin_amdgcn_mfma_f32_16x16x32_bf16(
              af[mi].b, bfr[ni].b, acc[mi][ni], 0, 0, 0);
    }
  }
#pragma unroll
  for (int mi = 0; mi < 2; ++mi)
#pragma unroll
    for (int ni = 0; ni < 2; ++ni) {
      int mbase = m0 + mq + 16 * mi + 4 * lg;
      int n = n0 + nq + 16 * ni + lr;
      *(f32x4*)(Cf + ((size_t)b * 256 + n) * 256 + mbase) = acc[mi][ni];
    }
}

// ---------------- DMA-staged 64x128 GEMM ----------------
// V=1: kv = w_qkv[512x256] x x_t[N][K] -> Kb [b][h][p][d] (m<256), Vt [b][h][d][p] (m>=256)
// V=2: out = w_proj[256x256] x o_buf[N][K] + bias + x -> f32
template <int V>
__global__ __launch_bounds__(256) void k_gemmx(
    const u16* __restrict__ A, const u16* __restrict__ Bh, float* __restrict__ Cf,
    u16* __restrict__ Kb, u16* __restrict__ Vt,
    const float* __restrict__ bias, const float* __restrict__ Xres) {
  const int t = threadIdx.x, lane = t & 63, wv = t >> 6;
  const int lr = lane & 15, lg = lane >> 4;
  // XCD-grouped decode: blocks sharing a B tile land on the same XCD slot
  int bid = blockIdx.x;
  int s = bid & 7, w = bid >> 3;
  int gid, mt;
  if constexpr (V == 1) { gid = (w & ~7) | s; mt = w & 7; }
  else { gid = ((w >> 2) << 3) | s; mt = w & 3; }
  const int nt = gid & 31, b = gid >> 5;
  const int m0 = mt * 64, n0 = nt * 128;

  __shared__ __align__(16) u16 ldsAB[192 * 64];  // A rows 0..63, B rows 64..191, linear + src-swizzled

  f32x4 acc[2][4] = {};
  const int mq = (wv >> 1) * 32, nq = (wv & 1) * 64;
  const size_t bOff = (size_t)b * 4096 * 256;
  const int sub = lane >> 3, c = lane & 7;

  for (int k0 = 0; k0 < 256; k0 += 64) {
    __syncthreads();
#pragma unroll
    for (int i = wv; i < 24; i += 4) {
      const u16* g;
      if (i < 8) g = A + (size_t)(m0 + i * 8 + sub) * 256 + k0 + ((c ^ sub) << 3);
      else g = Bh + bOff + (size_t)(n0 + i * 8 + sub - 64) * 256 + k0 + ((c ^ sub) << 3);
      gl16(g, &ldsAB[i * 512]);
    }
    __syncthreads();
#pragma unroll
    for (int kk = 0; kk < 2; ++kk) {
      Frag af[2], bfr[4];
#pragma unroll
      for (int mi = 0; mi < 2; ++mi) {
        int r = mq + 16 * mi + lr;
        af[mi].u = *(const u16x8*)&ldsAB[r * 64 + (((kk * 4 + lg) ^ (r & 7)) << 3)];
      }
#pragma unroll
      for (int ni = 0; ni < 4; ++ni) {
        int rn = nq + 16 * ni + lr;
        bfr[ni].u = *(const u16x8*)&ldsAB[(64 + rn) * 64 + (((kk * 4 + lg) ^ (rn & 7)) << 3)];
      }
#pragma unroll
      for (int mi = 0; mi < 2; ++mi)
#pragma unroll
        for (int ni = 0; ni < 4; ++ni)
          acc[mi][ni] = __builtin_amdgcn_mfma_f32_16x16x32_bf16(
              af[mi].b, bfr[ni].b, acc[mi][ni], 0, 0, 0);
    }
  }

  if constexpr (V == 1) {
    if (m0 < 256) {  // K heads -> Kb [b][h][p][d]
#pragma unroll
      for (int mi = 0; mi < 2; ++mi)
#pragma unroll
        for (int ni = 0; ni < 4; ++ni) {
          int mbase = m0 + mq + 16 * mi + 4 * lg;
          int n = n0 + nq + 16 * ni + lr;
          u16x4 pk;
#pragma unroll
          for (int j = 0; j < 4; ++j) pk[j] = f2bf(acc[mi][ni][j]);
          int head = mbase >> 5, d = mbase & 31;
          *(u16x4*)(Kb + ((size_t)(b * 8 + head) * 4096 + n) * 32 + d) = pk;
        }
    } else {  // V heads -> Vt [b][h][d][p] via 2-round LDS transpose
      float(*lds_t)[68] = (float(*)[68])ldsAB;
#pragma unroll 1
      for (int r = 0; r < 2; ++r) {
        __syncthreads();
        if ((wv & 1) == r) {
#pragma unroll
          for (int mi = 0; mi < 2; ++mi)
#pragma unroll
            for (int ni = 0; ni < 4; ++ni)
#pragma unroll
              for (int j = 0; j < 4; ++j)
                lds_t[mq + 16 * mi + 4 * lg + j][16 * ni + lr] = acc[mi][ni][j];
        }
        __syncthreads();
        int dloc = t >> 2, nc = (t & 3) * 16;
        int dg = (m0 - 256) + dloc;
        int head = dg >> 5, d = dg & 31;
        u16x8 o0, o1;
#pragma unroll
        for (int i = 0; i < 8; ++i) {
          o0[i] = f2bf(lds_t[dloc][nc + i]);
          o1[i] = f2bf(lds_t[dloc][nc + 8 + i]);
        }
        u16* dst = Vt + ((size_t)(b * 8 + head) * 32 + d) * 4096 + n0 + 64 * r + nc;
        *(u16x8*)dst = o0;
        *(u16x8*)(dst + 8) = o1;
      }
    }
  } else {
#pragma unroll
    for (int mi = 0; mi < 2; ++mi)
#pragma unroll
      for (int ni = 0; ni < 4; ++ni) {
        int mbase = m0 + mq + 16 * mi + 4 * lg;
        int n = n0 + nq + 16 * ni + lr;
#pragma unroll
        for (int j = 0; j < 4; ++j) {
          int m = mbase + j;
          size_t off = ((size_t)b * 256 + m) * 4096 + n;
          Cf[off] = acc[mi][ni][j] + bias[m] + Xres[off];
        }
      }
  }
}

// ---------------- bilinear 16x16 -> 64x64 upsample of qsmall, + qbias, * QSC ----------------
DEVFN void blc(int y, int& i0, int& i1, float& w) {
  float fy = 0.25f * y - 0.375f;
  float ff = floorf(fy);
  w = fy - ff;
  int i = (int)ff;
  i0 = i < 0 ? 0 : i;
  i1 = (i + 1 > 15) ? 15 : i + 1;
}

__global__ __launch_bounds__(256) void k_resize(
    const float* __restrict__ qsmall, const float* __restrict__ qbias,
    u16* __restrict__ Qb) {
  int gid = blockIdx.x * 256 + threadIdx.x;
  int c8 = gid & 31;
  int p = (gid >> 5) & 4095;
  int b = gid >> 17;
  int y = p >> 6, x = p & 63;
  int y0, y1, x0, x1;
  float wy, wx;
  blc(y, y0, y1, wy);
  blc(x, x0, x1, wx);
  const float* base = qsmall + (size_t)b * 65536;
  int o0 = c8 * 8;
  const float* r00 = base + (y0 * 16 + x0) * 256 + o0;
  const float* r01 = base + (y0 * 16 + x1) * 256 + o0;
  const float* r10 = base + (y1 * 16 + x0) * 256 + o0;
  const float* r11 = base + (y1 * 16 + x1) * 256 + o0;
  float w00 = (1 - wy) * (1 - wx), w01 = (1 - wy) * wx;
  float w10 = wy * (1 - wx), w11 = wy * wx;
  u16x8 outv;
#pragma unroll
  for (int i = 0; i < 8; ++i) {
    float v = w00 * r00[i] + w01 * r01[i] + w10 * r10[i] + w11 * r11[i] + qbias[o0 + i];
    outv[i] = f2bf(v * QSC);
  }
  int head = o0 >> 5, d = o0 & 31;
  *(u16x8*)(Qb + ((size_t)(b * 8 + head) * 4096 + p) * 32 + d) = outv;
}

// ---------------- MFMA attention (all heads) ----------------
// P-network NOTE: ds_bpermute pulls the SOURCE lane's data operand, so the
// half-select must happen at the DESTINATION, after the permute. Full path:
// 8 bpermutes (pk0..pk3 raw) + dest-side selects. ws4/ws2: 4 bpermutes + select-0.
__global__ __launch_bounds__(256) void k_attn(
    const u16* __restrict__ Qb, const u16* __restrict__ Kb,
    const u16* __restrict__ Vt, u16* __restrict__ Ob) {
  const int t = threadIdx.x, lane = t & 63, wv = t >> 6;
  const int lr = lane & 15, lg = lane >> 4;
  const int bid = blockIdx.x;
  const bool split = (bid < 512);

  __shared__ float sm_o[4][4][4][64];  // [wave][frag][j][lane], one h-phase at a time
  __shared__ float sm_l[4][4][16];

  const int addrA = (32 * (lg & 1) + lr) * 4;
  const int addrB = addrA + 64;
  const bool lo_half = (lg < 2);

  // 4-bpermute network for 16-key paths (second half zero)
  auto pnet16 = [&](unsigned pk0, unsigned pk1, Frag& out) {
    union { unsigned w[4]; Frag fr; } pb;
    int a0 = __builtin_amdgcn_ds_bpermute(addrA, (int)pk0);
    int a1 = __builtin_amdgcn_ds_bpermute(addrA, (int)pk1);
    int a2 = __builtin_amdgcn_ds_bpermute(addrB, (int)pk0);
    int a3 = __builtin_amdgcn_ds_bpermute(addrB, (int)pk1);
    pb.w[0] = lo_half ? (unsigned)a0 : 0u;
    pb.w[1] = lo_half ? (unsigned)a1 : 0u;
    pb.w[2] = lo_half ? (unsigned)a2 : 0u;
    pb.w[3] = lo_half ? (unsigned)a3 : 0u;
    out = pb.fr;
  };

  int b, head, lws, i0, by, bx, j_begin, j_end;
  if (split) {
    int idx = bid;
    b = idx >> 6;
    int qg = idx & 63;
    head = 4; lws = 5;
    int w = qg >> 4;
    i0 = (qg & 15) * 64;
    by = (w >> 1) * 32;
    bx = (w & 1) * 32;
    j_begin = wv * 256;
    j_end = j_begin + 256;
  } else {
    int u = (bid - 512) * 4 + wv;
    if (u >= 3072) {  // ---- ws=2 (head 0): 4 windows of 4 keys per frag, masked ----
      int r = u - 3072;
      int b2 = r >> 6;
      int qw = r & 63;
      const size_t hb0 = (size_t)(b2 * 8 + 0) * 131072;
      const u16* vb0 = Vt + hb0 + (size_t)lr * 4096;
      const u16* vb1 = Vt + hb0 + (size_t)(16 + lr) * 4096;
      const bool valid = (lg == (lr >> 2));
      const int lgm = lg & 1;
#pragma unroll
      for (int f = 0; f < 4; ++f) {
        int g = qw * 4 + f;              // frag index: windows g*4 .. g*4+3
        int W = g * 4 + (lr >> 2);       // this lane's window (q slot lr)
        int wbase = (W >> 5) * 128 + (W & 31) * 2;
        int qj = lr & 3;
        int posq = wbase + ((qj >> 1) << 6) + (qj & 1);
        Frag qf2, kf2;
        qf2.u = *(const u16x8*)(Qb + hb0 + (size_t)posq * 32 + 8 * lg);
        kf2.u = *(const u16x8*)(Kb + hb0 + (size_t)posq * 32 + 8 * lg);
        int W0 = g * 4 + 2 * lgm;
        int base0 = (W0 >> 5) * 128 + (W0 & 31) * 2;
        int W1 = W0 + 1;
        int base1 = (W1 >> 5) * 128 + (W1 & 31) * 2;
        Frag22 v0u, v1u;
        v0u.q[0] = *(const u16x2*)(vb0 + base0);
        v0u.q[1] = *(const u16x2*)(vb0 + base0 + 64);
        v0u.q[2] = *(const u16x2*)(vb0 + base1);
        v0u.q[3] = *(const u16x2*)(vb0 + base1 + 64);
        v1u.q[0] = *(const u16x2*)(vb1 + base0);
        v1u.q[1] = *(const u16x2*)(vb1 + base0 + 64);
        v1u.q[2] = *(const u16x2*)(vb1 + base1);
        v1u.q[3] = *(const u16x2*)(vb1 + base1 + 64);
        f32x4 zz = {};
        f32x4 s0 = __builtin_amdgcn_mfma_f32_16x16x32_bf16(kf2.b, qf2.b, zz, 0, 0, 0);
        float p[4];
        float ls = 0.f;
#pragma unroll
        for (int j = 0; j < 4; ++j) {
          p[j] = valid ? fexp2(s0[j]) : 0.f;
          ls += p[j];
        }
        unsigned pk0, pk1;
        asm("v_cvt_pk_bf16_f32 %0, %1, %2" : "=v"(pk0) : "v"(p[0]), "v"(p[1]));
        asm("v_cvt_pk_bf16_f32 %0, %1, %2" : "=v"(pk1) : "v"(p[2]), "v"(p[3]));
        Frag pfr;
        pnet16(pk0, pk1, pfr);
        f32x4 o0 = {}, o1 = {};
        o0 = __builtin_amdgcn_mfma_f32_16x16x32_bf16(v0u.b, pfr.b, o0, 0, 0, 0);
        o1 = __builtin_amdgcn_mfma_f32_16x16x32_bf16(v1u.b, pfr.b, o1, 0, 0, 0);
        ls += __shfl_xor(ls, 16, 64);
        ls += __shfl_xor(ls, 32, 64);
        float inv = 1.f / ls;
        u16x4 lo4, hi4;
#pragma unroll
        for (int j = 0; j < 4; ++j) {
          lo4[j] = f2bf(o0[j] * inv);
          hi4[j] = f2bf(o1[j] * inv);
        }
        u16* dst = Ob + ((size_t)b2 * 4096 + posq) * 256;
        *(u16x4*)(dst + 4 * lg) = lo4;
        *(u16x4*)(dst + 16 + 4 * lg) = hi4;
      }
      return;
    }
    if (u >= 2560) {  // ---- ws=4 (head 1) ----
      int r = u - 2560;
      int b4 = r >> 6;
      int qw = r & 63;
      const size_t hb1 = (size_t)(b4 * 8 + 1) * 131072;
      const u16* vb0 = Vt + hb1 + (size_t)lr * 4096;
      const u16* vb1 = Vt + hb1 + (size_t)(16 + lr) * 4096;
#pragma unroll
      for (int f = 0; f < 4; ++f) {
        int w = qw * 4 + f;
        int pbase = ((w >> 4) << 8) + ((w & 15) << 2);
        int posq = pbase + ((lr >> 2) << 6) + (lr & 3);
        Frag qf4, kf4;
        qf4.u = *(const u16x8*)(Qb + hb1 + (size_t)posq * 32 + 8 * lg);
        kf4.u = *(const u16x8*)(Kb + hb1 + (size_t)posq * 32 + 8 * lg);
        int a1 = pbase + 2 * (lg & 1) * 64;
        Frag44 v0u, v1u;
        v0u.h[0] = *(const u16x4*)(vb0 + a1);
        v0u.h[1] = *(const u16x4*)(vb0 + a1 + 64);
        v1u.h[0] = *(const u16x4*)(vb1 + a1);
        v1u.h[1] = *(const u16x4*)(vb1 + a1 + 64);
        f32x4 zz = {};
        f32x4 s0 = __builtin_amdgcn_mfma_f32_16x16x32_bf16(kf4.b, qf4.b, zz, 0, 0, 0);
        float p[4];
        float ls = 0.f;
#pragma unroll
        for (int j = 0; j < 4; ++j) {
          p[j] = fexp2(s0[j]);
          ls += p[j];
        }
        unsigned pk0, pk1;
        asm("v_cvt_pk_bf16_f32 %0, %1, %2" : "=v"(pk0) : "v"(p[0]), "v"(p[1]));
        asm("v_cvt_pk_bf16_f32 %0, %1, %2" : "=v"(pk1) : "v"(p[2]), "v"(p[3]));
        Frag pfr;
        pnet16(pk0, pk1, pfr);
        f32x4 o0 = {}, o1 = {};
        o0 = __builtin_amdgcn_mfma_f32_16x16x32_bf16(v0u.b, pfr.b, o0, 0, 0, 0);
        o1 = __builtin_amdgcn_mfma_f32_16x16x32_bf16(v1u.b, pfr.b, o1, 0, 0, 0);
        ls += __shfl_xor(ls, 16, 64);
        ls += __shfl_xor(ls, 32, 64);
        float inv = 1.f / ls;
        u16x4 lo4, hi4;
#pragma unroll
        for (int j = 0; j < 4; ++j) {
          lo4[j] = f2bf(o0[j] * inv);
          hi4[j] = f2bf(o1[j] * inv);
        }
        u16* dst = Ob + ((size_t)b4 * 4096 + posq) * 256 + 32;
        *(u16x4*)(dst + 4 * lg) = lo4;
        *(u16x4*)(dst + 16 + 4 * lg) = hi4;
      }
      return;
    }
    if (u < 512) {
      head = 3; lws = 4;
      b = u >> 6;
      int qb = (u & 63) << 6;
      int w = qb >> 8;
      i0 = qb & 255;
      by = (w >> 2) * 16;
      bx = (w & 3) * 16;
      j_begin = 0; j_end = 256;
    } else if (u < 1024) {
      head = 2; lws = 3;
      int u2 = u - 512;
      b = u2 >> 6;
      int w = u2 & 63;
      i0 = 0;
      by = (w >> 3) * 8;
      bx = (w & 7) * 8;
      j_begin = 0; j_end = 64;
    } else {
      int r = u - 1024;
      b = r / 192;
      int rr = r % 192;
      head = 5 + (rr >> 6);
      lws = 6;
      by = rr & 63; bx = 0; i0 = 0;
      j_begin = 0; j_end = 64;
    }
  }
  const int wsm = (1 << lws) - 1;
  const size_t hb = (size_t)(b * 8 + head) * 131072;
  auto mapP = [&](int i) { return ((by + (i >> lws)) << 6) + bx + (i & wsm); };

  Frag qf[4];
#pragma unroll
  for (int f = 0; f < 4; ++f)
    qf[f].u = *(const u16x8*)(Qb + hb + (size_t)mapP(i0 + 16 * f + lr) * 32 + 8 * lg);

  f32x4 oT[4][2] = {};
  float lsum[4] = {0.f, 0.f, 0.f, 0.f};

  auto chunk = [&](const Frag& k0, const Frag& k1, const Frag& v0, const Frag& v1) {
#pragma unroll
    for (int f = 0; f < 4; ++f) {
      f32x4 zz = {};
      f32x4 s0 = __builtin_amdgcn_mfma_f32_16x16x32_bf16(k0.b, qf[f].b, zz, 0, 0, 0);
      f32x4 s1 = __builtin_amdgcn_mfma_f32_16x16x32_bf16(k1.b, qf[f].b, zz, 0, 0, 0);
      float p[8];
#pragma unroll
      for (int j = 0; j < 4; ++j) {
        p[j] = fexp2(s0[j]);
        p[4 + j] = fexp2(s1[j]);
      }
#pragma unroll
      for (int j = 0; j < 8; ++j) lsum[f] += p[j];
      unsigned pk0, pk1, pk2, pk3;
      asm("v_cvt_pk_bf16_f32 %0, %1, %2" : "=v"(pk0) : "v"(p[0]), "v"(p[1]));
      asm("v_cvt_pk_bf16_f32 %0, %1, %2" : "=v"(pk1) : "v"(p[2]), "v"(p[3]));
      asm("v_cvt_pk_bf16_f32 %0, %1, %2" : "=v"(pk2) : "v"(p[4]), "v"(p[5]));
      asm("v_cvt_pk_bf16_f32 %0, %1, %2" : "=v"(pk3) : "v"(p[6]), "v"(p[7]));
      int a0 = __builtin_amdgcn_ds_bpermute(addrA, (int)pk0);
      int a1 = __builtin_amdgcn_ds_bpermute(addrA, (int)pk1);
      int a2 = __builtin_amdgcn_ds_bpermute(addrB, (int)pk0);
      int a3 = __builtin_amdgcn_ds_bpermute(addrB, (int)pk1);
      int b0 = __builtin_amdgcn_ds_bpermute(addrA, (int)pk2);
      int b1 = __builtin_amdgcn_ds_bpermute(addrA, (int)pk3);
      int b2 = __builtin_amdgcn_ds_bpermute(addrB, (int)pk2);
      int b3 = __builtin_amdgcn_ds_bpermute(addrB, (int)pk3);
      union { unsigned w[4]; Frag fr; } pb;
      pb.w[0] = (unsigned)(lo_half ? a0 : b0);
      pb.w[1] = (unsigned)(lo_half ? a1 : b1);
      pb.w[2] = (unsigned)(lo_half ? a2 : b2);
      pb.w[3] = (unsigned)(lo_half ? a3 : b3);
      oT[f][0] = __builtin_amdgcn_mfma_f32_16x16x32_bf16(v0.b, pb.fr.b, oT[f][0], 0, 0, 0);
      oT[f][1] = __builtin_amdgcn_mfma_f32_16x16x32_bf16(v1.b, pb.fr.b, oT[f][1], 0, 0, 0);
    }
  };

  Frag k0A, k1A, v0A, v1A, k0B, k1B, v0B, v1B;
  auto loadKV = [&](int j0, Frag& a, Frag& c, Frag& d, Frag& e) {
    a.u = *(const u16x8*)(Kb + hb + (size_t)mapP(j0 + lr) * 32 + 8 * lg);
    c.u = *(const u16x8*)(Kb + hb + (size_t)mapP(j0 + 16 + lr) * 32 + 8 * lg);
    int pv = mapP(j0 + 8 * lg);
    d.u = *(const u16x8*)(Vt + hb + (size_t)lr * 4096 + pv);
    e.u = *(const u16x8*)(Vt + hb + (size_t)(16 + lr) * 4096 + pv);
  };

  loadKV(j_begin, k0A, k1A, v0A, v1A);
  for (int j0 = j_begin; j0 < j_end; j0 += 64) {
    loadKV(j0 + 32, k0B, k1B, v0B, v1B);
    chunk(k0A, k1A, v0A, v1A);
    if (j0 + 64 < j_end) loadKV(j0 + 64, k0A, k1A, v0A, v1A);
    chunk(k0B, k1B, v0B, v1B);
  }

  if (!split) {
#pragma unroll
    for (int f = 0; f < 4; ++f) {
      float s = lsum[f];
      s += __shfl_xor(s, 16, 64);
      s += __shfl_xor(s, 32, 64);
      float inv = 1.f / s;
      int q = i0 + 16 * f + lr;
      u16x4 lo, hi;
#pragma unroll
      for (int j = 0; j < 4; ++j) {
        lo[j] = f2bf(oT[f][0][j] * inv);
        hi[j] = f2bf(oT[f][1][j] * inv);
      }
      if (head < 5) {
        int p = mapP(q);
        u16* dst = Ob + ((size_t)b * 4096 + p) * 256 + head * 32;
        *(u16x4*)(dst + 4 * lg) = lo;
        *(u16x4*)(dst + 16 + 4 * lg) = hi;
      } else {
        int n = head - 5;
        int g32 = ((n * 64 + by) << 6) + q;
        int m3 = g32 % 3, sp = g32 / 3;
        u16* dst = Ob + ((size_t)b * 4096 + sp) * 256 + 160 + 32 * m3;
        *(u16x4*)(dst + 4 * lg) = lo;
        *(u16x4*)(dst + 16 + 4 * lg) = hi;
      }
    }
  } else {
    // split-K combine: two h-phases through 17KB LDS
    float ot0[4], ot1[4];
    float ls = 0.f;
#pragma unroll 1
    for (int h = 0; h < 2; ++h) {
      __syncthreads();
#pragma unroll
      for (int f = 0; f < 4; ++f) {
#pragma unroll
        for (int j = 0; j < 4; ++j) sm_o[wv][f][j][lane] = oT[f][h][j];
        if (h == 0) {
          float s = lsum[f];
          s += __shfl_xor(s, 16, 64);
          s += __shfl_xor(s, 32, 64);
          if (lg == 0) sm_l[wv][f][lr] = s;
        }
      }
      __syncthreads();
      int f = wv;
      float* ot = (h == 0) ? ot0 : ot1;
#pragma unroll
      for (int j = 0; j < 4; ++j) ot[j] = 0.f;
#pragma unroll
      for (int w = 0; w < 4; ++w) {
        if (h == 0) ls += sm_l[w][f][lr];
#pragma unroll
        for (int j = 0; j < 4; ++j) ot[j] += sm_o[w][f][j][lane];
      }
    }
    float inv = 1.f / ls;
    int f = wv;
    int q = i0 + 16 * f + lr;
    int p = mapP(q);
    u16x4 lo, hi;
#pragma unroll
    for (int j = 0; j < 4; ++j) {
      lo[j] = f2bf(ot0[j] * inv);
      hi[j] = f2bf(ot1[j] * inv);
    }
    u16* dst = Ob + ((size_t)b * 4096 + p) * 256 + head * 32;
    *(u16x4*)(dst + 4 * lg) = lo;
    *(u16x4*)(dst + 16 + 4 * lg) = hi;
  }
}

extern "C" void kernel_launch(void* const* d_in, const int* in_sizes, int n_in,
                              void* d_out, int out_size, void* d_ws, size_t ws_size,
                              hipStream_t stream) {
  const float* x = (const float*)d_in[0];
  const float* temp = (const float*)d_in[1];
  const float* w_qkv = (const float*)d_in[2];
  const float* w_v = (const float*)d_in[3];
  const float* w_proj = (const float*)d_in[4];
  const float* b_proj = (const float*)d_in[5];
  const float* w_temp = (const float*)d_in[6];
  const float* b_temp = (const float*)d_in[7];
  (void)in_sizes; (void)n_in; (void)out_size; (void)ws_size;

  char* ws = (char*)d_ws;
  u16* w_qt = (u16*)(ws + 0);              // 262144 B
  u16* w_qkv_bf = (u16*)(ws + 262144);     // 262144 B
  u16* w_proj_bf = (u16*)(ws + 524288);    // 131072 B
  float* qbias = (float*)(ws + 655360);    // 1024 B
  float* qsmall = (float*)(ws + 656384);   // 2097152 B  [b][p16][o]
  u16* q_buf = (u16*)(ws + 2753536);       // 16777216 B [b][h][p][d]
  u16* k_buf = (u16*)(ws + 19530752);      // 16777216 B [b][h][p][d]
  u16* v_t = (u16*)(ws + 53085184);        // 16777216 B [b][h][d][p]
  u16* o_buf = (u16*)(ws + 69862400);      // 16777216 B [b][p][c]  (aliased: x_t before attn)
  u16* x_t = o_buf;                        // [b][p][c] bf16 — dead before o_buf written
  float* out = (float*)d_out;

  k_prep<<<1024, 256, 0, stream>>>(w_qkv, w_v, w_proj, w_temp, b_temp,
                                   w_qt, qbias, w_qkv_bf, w_proj_bf);
  k_xt<<<2048, 256, 0, stream>>>(x, x_t);
  k_gemm0<<<dim3(4, 4, 8), 256, 0, stream>>>(w_qt, temp, qsmall);
  k_resize<<<4096, 256, 0, stream>>>(qsmall, qbias, q_buf);
  k_gemmx<1><<<2048, 256, 0, stream>>>(w_qkv_bf, x_t, nullptr, k_buf, v_t,
                                       nullptr, nullptr);
  k_attn<<<1408, 256, 0, stream>>>(q_buf, k_buf, v_t, o_buf);
  k_gemmx<2><<<1024, 256, 0, stream>>>(w_proj_bf, o_buf, out, nullptr, nullptr,
                                       b_proj, x);
}

// Round 9
// 120.132 us; speedup vs baseline: 1.0358x; 1.0011x over previous
//
#include <hip/hip_runtime.h>

typedef unsigned short u16;
typedef float f32x4 __attribute__((ext_vector_type(4)));
typedef unsigned short u16x8 __attribute__((ext_vector_type(8)));
typedef unsigned short u16x4 __attribute__((ext_vector_type(4)));
typedef unsigned short u16x2 __attribute__((ext_vector_type(2)));
typedef __bf16 bf16x8 __attribute__((ext_vector_type(8)));

union Frag { u16x8 u; bf16x8 b; };
union Frag44 { u16x4 h[2]; u16x8 u; bf16x8 b; };
union Frag22 { u16x2 q[4]; u16x8 u; bf16x8 b; };

#define DEVFN static __device__ __forceinline__

DEVFN u16 f2bf(float f) {
  unsigned u = __builtin_bit_cast(unsigned, f);
  u += 0x7FFFu + ((u >> 16) & 1u);
  return (u16)(u >> 16);
}
DEVFN float bf2f(u16 h) {
  return __builtin_bit_cast(float, ((unsigned)h) << 16);
}
DEVFN int bswz(int n, int k) { return k ^ ((((n >> 4) ^ n) & 7) << 3); }

// raw v_exp_f32: args are bounded (|s| ~< 1) so OCML's range/denormal fixup
// is pure overhead.
DEVFN float fexp2(float x) {
#if __has_builtin(__builtin_amdgcn_exp2f)
  return __builtin_amdgcn_exp2f(x);
#else
  float r;
  asm volatile("v_exp_f32 %0, %1\n\ts_nop 1" : "=v"(r) : "v"(x));
  return r;
#endif
}

DEVFN void gl16(const u16* g, u16* l) {
  __builtin_amdgcn_global_load_lds(
      (const __attribute__((address_space(1))) unsigned int*)g,
      (__attribute__((address_space(3))) unsigned int*)l, 16, 0, 0);
}

// combined scale folded into Q: softmax(s*SCALE) == normalize(2^(s*SCALE*log2e))
#define QSC (0.17677669529663687f * 1.44269504088896341f)

// ---------------- prep ----------------
__global__ __launch_bounds__(256) void k_prep(
    const float* __restrict__ w_qkv, const float* __restrict__ w_v,
    const float* __restrict__ w_proj, const float* __restrict__ w_temp,
    const float* __restrict__ b_temp,
    u16* __restrict__ w_qt, float* __restrict__ qbias,
    u16* __restrict__ w_qkv_bf, u16* __restrict__ w_proj_bf) {
  __shared__ float wvr[256];
  __shared__ float red[256];
  int t = threadIdx.x, blk = blockIdx.x;
  if (blk < 256) {
    wvr[t] = w_v[blk * 256 + t];
    __syncthreads();
    for (int c = t; c < 512; c += 256) {
      float acc = 0.f;
      for (int m = 0; m < 256; ++m) acc += wvr[m] * w_temp[m * 512 + c];
      w_qt[blk * 512 + c] = f2bf(acc);
    }
    red[t] = wvr[t] * b_temp[t];
    __syncthreads();
    for (int s = 128; s > 0; s >>= 1) {
      if (t < s) red[t] += red[t + s];
      __syncthreads();
    }
    if (t == 0) qbias[blk] = red[0];
  } else {
    int e = (blk - 256) * 256 + t;
    if (e < 512 * 256) w_qkv_bf[e] = f2bf(w_qkv[e]);
    else {
      int e2 = e - 512 * 256;
      w_proj_bf[e2] = f2bf(w_proj[e2]);
    }
  }
}

// ---------------- x transpose+cvt: [b][c=256][p=4096] f32 -> [b][p][c] bf16 ----------------
__global__ __launch_bounds__(256) void k_xt(
    const float* __restrict__ x, u16* __restrict__ xt) {
  __shared__ float lds[64][65];
  int t = threadIdx.x, bid = blockIdx.x;
  int b = bid >> 8, rem = bid & 255;
  int c0 = (rem >> 6) << 6;
  int p0 = (rem & 63) << 6;
  int cr = t >> 2, pc = (t & 3) * 16;
  const float* src = x + (size_t)(b * 256 + c0 + cr) * 4096 + p0 + pc;
#pragma unroll
  for (int i = 0; i < 4; ++i) {
    f32x4 v = *(const f32x4*)(src + 4 * i);
#pragma unroll
    for (int j = 0; j < 4; ++j) lds[cr][pc + 4 * i + j] = v[j];
  }
  __syncthreads();
  int pr = t >> 2, cq = (t & 3) * 16;
  u16x8 o0, o1;
#pragma unroll
  for (int j = 0; j < 8; ++j) {
    o0[j] = f2bf(lds[cq + j][pr]);
    o1[j] = f2bf(lds[cq + 8 + j][pr]);
  }
  u16* dst = xt + ((size_t)(b * 4096) + p0 + pr) * 256 + c0 + cq;
  *(u16x8*)dst = o0;
  *(u16x8*)(dst + 8) = o1;
}

// ---------------- qsmall GEMM (64x64, reg staging, f32 B) ----------------
__global__ __launch_bounds__(256) void k_gemm0(
    const u16* __restrict__ A, const float* __restrict__ Bf, float* __restrict__ Cf) {
  constexpr int N = 256, K = 512;
  const int t = threadIdx.x;
  const int lane = t & 63;
  const int wv = t >> 6;
  const int n0 = blockIdx.x * 64;
  const int m0 = blockIdx.y * 64;
  const int b = blockIdx.z;

  __shared__ __align__(16) u16 lds[2 * 64 * 72];
  u16(*lds_a)[72] = (u16(*)[72])lds;
  u16(*lds_b)[72] = (u16(*)[72])(lds + 64 * 72);

  f32x4 acc[2][2] = {};
  const int mq = (wv >> 1) * 32, nq = (wv & 1) * 32;
  const int lr = lane & 15, lg = lane >> 4;

  for (int k0 = 0; k0 < K; k0 += 64) {
    __syncthreads();
    {
      int m = t >> 2, c0 = (t & 3) * 16;
      const u16* src = A + (size_t)(m0 + m) * K + k0 + c0;
      *(u16x8*)&lds_a[m][c0] = *(const u16x8*)src;
      *(u16x8*)&lds_a[m][c0 + 8] = *(const u16x8*)(src + 8);
    }
    {
      int k = t >> 2, nn0 = (t & 3) * 16;
      const float* src = Bf + (size_t)b * K * N + (size_t)(k0 + k) * N + n0 + nn0;
#pragma unroll
      for (int i4 = 0; i4 < 4; ++i4) {
        f32x4 v = *(const f32x4*)(src + i4 * 4);
#pragma unroll
        for (int j = 0; j < 4; ++j) {
          int n = nn0 + i4 * 4 + j;
          lds_b[n][bswz(n, k)] = f2bf(v[j]);
        }
      }
    }
    __syncthreads();
#pragma unroll
    for (int kk = 0; kk < 2; ++kk) {
      Frag af[2], bfr[2];
#pragma unroll
      for (int i = 0; i < 2; ++i) {
        af[i].u = *(const u16x8*)&lds_a[mq + 16 * i + lr][kk * 32 + 8 * lg];
        int n = nq + 16 * i + lr;
        bfr[i].u = *(const u16x8*)&lds_b[n][bswz(n, kk * 32 + 8 * lg)];
      }
#pragma unroll
      for (int mi = 0; mi < 2; ++mi)
#pragma unroll
        for (int ni = 0; ni < 2; ++ni)
          acc[mi][ni] = __builtin_amdgcn_mfma_f32_16x16x32_bf16(
              af[mi].b, bfr[ni].b, acc[mi][ni], 0, 0, 0);
    }
  }
#pragma unroll
  for (int mi = 0; mi < 2; ++mi)
#pragma unroll
    for (int ni = 0; ni < 2; ++ni) {
      int mbase = m0 + mq + 16 * mi + 4 * lg;
      int n = n0 + nq + 16 * ni + lr;
      *(f32x4*)(Cf + ((size_t)b * 256 + n) * 256 + mbase) = acc[mi][ni];
    }
}

// ---------------- DMA-staged 64x128 GEMM ----------------
// V=1: kv = w_qkv[512x256] x x_t[N][K=256 row] -> Kb [b][h][p][d] (m<256), Vt [b][h][d][p]
// V=2: out = w_proj[256x256] x o_buf (PLANE layout [b][h][p][32]) + bias + x -> f32
template <int V>
__global__ __launch_bounds__(256) void k_gemmx(
    const u16* __restrict__ A, const u16* __restrict__ Bh, float* __restrict__ Cf,
    u16* __restrict__ Kb, u16* __restrict__ Vt,
    const float* __restrict__ bias, const float* __restrict__ Xres) {
  const int t = threadIdx.x, lane = t & 63, wv = t >> 6;
  const int lr = lane & 15, lg = lane >> 4;
  // XCD-grouped decode: blocks sharing a B tile land on the same XCD slot
  int bid = blockIdx.x;
  int s = bid & 7, w = bid >> 3;
  int gid, mt;
  if constexpr (V == 1) { gid = (w & ~7) | s; mt = w & 7; }
  else { gid = ((w >> 2) << 3) | s; mt = w & 3; }
  const int nt = gid & 31, b = gid >> 5;
  const int m0 = mt * 64, n0 = nt * 128;

  __shared__ __align__(16) u16 ldsAB[192 * 64];  // A rows 0..63, B rows 64..191, linear + src-swizzled

  f32x4 acc[2][4] = {};
  const int mq = (wv >> 1) * 32, nq = (wv & 1) * 64;
  const size_t bOff = (size_t)b * 4096 * 256;
  const int sub = lane >> 3, c = lane & 7;

  for (int k0 = 0; k0 < 256; k0 += 64) {
    __syncthreads();
#pragma unroll
    for (int i = wv; i < 24; i += 4) {
      const u16* g;
      if (i < 8) {
        g = A + (size_t)(m0 + i * 8 + sub) * 256 + k0 + ((c ^ sub) << 3);
      } else {
        int rn = n0 + i * 8 + sub - 64;
        int ch = k0 + ((c ^ sub) << 3);
        if constexpr (V == 1)
          g = Bh + bOff + (size_t)rn * 256 + ch;
        else  // plane gather: channel -> (head plane, d)
          g = Bh + ((size_t)(b * 8 + (ch >> 5)) * 4096 + rn) * 32 + (ch & 31);
      }
      gl16(g, &ldsAB[i * 512]);
    }
    __syncthreads();
#pragma unroll
    for (int kk = 0; kk < 2; ++kk) {
      Frag af[2], bfr[4];
#pragma unroll
      for (int mi = 0; mi < 2; ++mi) {
        int r = mq + 16 * mi + lr;
        af[mi].u = *(const u16x8*)&ldsAB[r * 64 + (((kk * 4 + lg) ^ (r & 7)) << 3)];
      }
#pragma unroll
      for (int ni = 0; ni < 4; ++ni) {
        int rn = nq + 16 * ni + lr;
        bfr[ni].u = *(const u16x8*)&ldsAB[(64 + rn) * 64 + (((kk * 4 + lg) ^ (rn & 7)) << 3)];
      }
#pragma unroll
      for (int mi = 0; mi < 2; ++mi)
#pragma unroll
        for (int ni = 0; ni < 4; ++ni)
          acc[mi][ni] = __builtin_amdgcn_mfma_f32_16x16x32_bf16(
              af[mi].b, bfr[ni].b, acc[mi][ni], 0, 0, 0);
    }
  }

  if constexpr (V == 1) {
    if (m0 < 256) {  // K heads -> Kb [b][h][p][d]
#pragma unroll
      for (int mi = 0; mi < 2; ++mi)
#pragma unroll
        for (int ni = 0; ni < 4; ++ni) {
          int mbase = m0 + mq + 16 * mi + 4 * lg;
          int n = n0 + nq + 16 * ni + lr;
          u16x4 pk;
#pragma unroll
          for (int j = 0; j < 4; ++j) pk[j] = f2bf(acc[mi][ni][j]);
          int head = mbase >> 5, d = mbase & 31;
          *(u16x4*)(Kb + ((size_t)(b * 8 + head) * 4096 + n) * 32 + d) = pk;
        }
    } else {  // V heads -> Vt [b][h][d][p] via 2-round LDS transpose
      float(*lds_t)[68] = (float(*)[68])ldsAB;
#pragma unroll 1
      for (int r = 0; r < 2; ++r) {
        __syncthreads();
        if ((wv & 1) == r) {
#pragma unroll
          for (int mi = 0; mi < 2; ++mi)
#pragma unroll
            for (int ni = 0; ni < 4; ++ni)
#pragma unroll
              for (int j = 0; j < 4; ++j)
                lds_t[mq + 16 * mi + 4 * lg + j][16 * ni + lr] = acc[mi][ni][j];
        }
        __syncthreads();
        int dloc = t >> 2, nc = (t & 3) * 16;
        int dg = (m0 - 256) + dloc;
        int head = dg >> 5, d = dg & 31;
        u16x8 o0, o1;
#pragma unroll
        for (int i = 0; i < 8; ++i) {
          o0[i] = f2bf(lds_t[dloc][nc + i]);
          o1[i] = f2bf(lds_t[dloc][nc + 8 + i]);
        }
        u16* dst = Vt + ((size_t)(b * 8 + head) * 32 + d) * 4096 + n0 + 64 * r + nc;
        *(u16x8*)dst = o0;
        *(u16x8*)(dst + 8) = o1;
      }
    }
  } else {
#pragma unroll
    for (int mi = 0; mi < 2; ++mi)
#pragma unroll
      for (int ni = 0; ni < 4; ++ni) {
        int mbase = m0 + mq + 16 * mi + 4 * lg;
        int n = n0 + nq + 16 * ni + lr;
#pragma unroll
        for (int j = 0; j < 4; ++j) {
          int m = mbase + j;
          size_t off = ((size_t)b * 256 + m) * 4096 + n;
          Cf[off] = acc[mi][ni][j] + bias[m] + Xres[off];
        }
      }
  }
}

// ---------------- bilinear 16x16 -> 64x64 upsample of qsmall, + qbias, * QSC ----------------
DEVFN void blc(int y, int& i0, int& i1, float& w) {
  float fy = 0.25f * y - 0.375f;
  float ff = floorf(fy);
  w = fy - ff;
  int i = (int)ff;
  i0 = i < 0 ? 0 : i;
  i1 = (i + 1 > 15) ? 15 : i + 1;
}

__global__ __launch_bounds__(256) void k_resize(
    const float* __restrict__ qsmall, const float* __restrict__ qbias,
    u16* __restrict__ Qb) {
  int gid = blockIdx.x * 256 + threadIdx.x;
  int c8 = gid & 31;
  int p = (gid >> 5) & 4095;
  int b = gid >> 17;
  int y = p >> 6, x = p & 63;
  int y0, y1, x0, x1;
  float wy, wx;
  blc(y, y0, y1, wy);
  blc(x, x0, x1, wx);
  const float* base = qsmall + (size_t)b * 65536;
  int o0 = c8 * 8;
  const float* r00 = base + (y0 * 16 + x0) * 256 + o0;
  const float* r01 = base + (y0 * 16 + x1) * 256 + o0;
  const float* r10 = base + (y1 * 16 + x0) * 256 + o0;
  const float* r11 = base + (y1 * 16 + x1) * 256 + o0;
  float w00 = (1 - wy) * (1 - wx), w01 = (1 - wy) * wx;
  float w10 = wy * (1 - wx), w11 = wy * wx;
  u16x8 outv;
#pragma unroll
  for (int i = 0; i < 8; ++i) {
    float v = w00 * r00[i] + w01 * r01[i] + w10 * r10[i] + w11 * r11[i] + qbias[o0 + i];
    outv[i] = f2bf(v * QSC);
  }
  int head = o0 >> 5, d = o0 & 31;
  *(u16x8*)(Qb + ((size_t)(b * 8 + head) * 4096 + p) * 32 + d) = outv;
}

// ---------------- MFMA attention (all heads) ----------------
// Output Ob is per-head PLANES [b][h][p][32]: each 64-B line = one (p, head),
// written entirely by one wave -> full-line writes, no cross-XCD partial-line RMW.
__global__ __launch_bounds__(256) void k_attn(
    const u16* __restrict__ Qb, const u16* __restrict__ Kb,
    const u16* __restrict__ Vt, u16* __restrict__ Ob) {
  const int t = threadIdx.x, lane = t & 63, wv = t >> 6;
  const int lr = lane & 15, lg = lane >> 4;
  const int bid = blockIdx.x;
  const bool split = (bid < 512);

  __shared__ float sm_o[4][4][4][64];  // [wave][frag][j][lane], one h-phase at a time
  __shared__ float sm_l[4][4][16];

  const int addrA = (32 * (lg & 1) + lr) * 4;
  const int addrB = addrA + 64;
  const bool lo_half = (lg < 2);

  // 4-bpermute network for 16-key paths (second half zero)
  auto pnet16 = [&](unsigned pk0, unsigned pk1, Frag& out) {
    union { unsigned w[4]; Frag fr; } pb;
    int a0 = __builtin_amdgcn_ds_bpermute(addrA, (int)pk0);
    int a1 = __builtin_amdgcn_ds_bpermute(addrA, (int)pk1);
    int a2 = __builtin_amdgcn_ds_bpermute(addrB, (int)pk0);
    int a3 = __builtin_amdgcn_ds_bpermute(addrB, (int)pk1);
    pb.w[0] = lo_half ? (unsigned)a0 : 0u;
    pb.w[1] = lo_half ? (unsigned)a1 : 0u;
    pb.w[2] = lo_half ? (unsigned)a2 : 0u;
    pb.w[3] = lo_half ? (unsigned)a3 : 0u;
    out = pb.fr;
  };

  int b, head, lws, i0, by, bx, j_begin, j_end;
  if (split) {
    int idx = bid;
    b = idx >> 6;
    int qg = idx & 63;
    head = 4; lws = 5;
    int w = qg >> 4;
    i0 = (qg & 15) * 64;
    by = (w >> 1) * 32;
    bx = (w & 1) * 32;
    j_begin = wv * 256;
    j_end = j_begin + 256;
  } else {
    int u = (bid - 512) * 4 + wv;
    if (u >= 3072) {  // ---- ws=2 (head 0): 4 windows of 4 keys per frag, masked ----
      int r = u - 3072;
      int b2 = r >> 6;
      int qw = r & 63;
      const size_t hb0 = (size_t)(b2 * 8 + 0) * 131072;
      const u16* vb0 = Vt + hb0 + (size_t)lr * 4096;
      const u16* vb1 = Vt + hb0 + (size_t)(16 + lr) * 4096;
      const bool valid = (lg == (lr >> 2));
      const int lgm = lg & 1;
#pragma unroll
      for (int f = 0; f < 4; ++f) {
        int g = qw * 4 + f;              // frag index: windows g*4 .. g*4+3
        int W = g * 4 + (lr >> 2);       // this lane's window (q slot lr)
        int wbase = (W >> 5) * 128 + (W & 31) * 2;
        int qj = lr & 3;
        int posq = wbase + ((qj >> 1) << 6) + (qj & 1);
        Frag qf2, kf2;
        qf2.u = *(const u16x8*)(Qb + hb0 + (size_t)posq * 32 + 8 * lg);
        kf2.u = *(const u16x8*)(Kb + hb0 + (size_t)posq * 32 + 8 * lg);
        int W0 = g * 4 + 2 * lgm;
        int base0 = (W0 >> 5) * 128 + (W0 & 31) * 2;
        int W1 = W0 + 1;
        int base1 = (W1 >> 5) * 128 + (W1 & 31) * 2;
        Frag22 v0u, v1u;
        v0u.q[0] = *(const u16x2*)(vb0 + base0);
        v0u.q[1] = *(const u16x2*)(vb0 + base0 + 64);
        v0u.q[2] = *(const u16x2*)(vb0 + base1);
        v0u.q[3] = *(const u16x2*)(vb0 + base1 + 64);
        v1u.q[0] = *(const u16x2*)(vb1 + base0);
        v1u.q[1] = *(const u16x2*)(vb1 + base0 + 64);
        v1u.q[2] = *(const u16x2*)(vb1 + base1);
        v1u.q[3] = *(const u16x2*)(vb1 + base1 + 64);
        f32x4 zz = {};
        f32x4 s0 = __builtin_amdgcn_mfma_f32_16x16x32_bf16(kf2.b, qf2.b, zz, 0, 0, 0);
        float p[4];
        float ls = 0.f;
#pragma unroll
        for (int j = 0; j < 4; ++j) {
          p[j] = valid ? fexp2(s0[j]) : 0.f;
          ls += p[j];
        }
        unsigned pk0, pk1;
        asm("v_cvt_pk_bf16_f32 %0, %1, %2" : "=v"(pk0) : "v"(p[0]), "v"(p[1]));
        asm("v_cvt_pk_bf16_f32 %0, %1, %2" : "=v"(pk1) : "v"(p[2]), "v"(p[3]));
        Frag pfr;
        pnet16(pk0, pk1, pfr);
        f32x4 o0 = {}, o1 = {};
        o0 = __builtin_amdgcn_mfma_f32_16x16x32_bf16(v0u.b, pfr.b, o0, 0, 0, 0);
        o1 = __builtin_amdgcn_mfma_f32_16x16x32_bf16(v1u.b, pfr.b, o1, 0, 0, 0);
        ls += __shfl_xor(ls, 16, 64);
        ls += __shfl_xor(ls, 32, 64);
        float inv = 1.f / ls;
        u16x4 lo4, hi4;
#pragma unroll
        for (int j = 0; j < 4; ++j) {
          lo4[j] = f2bf(o0[j] * inv);
          hi4[j] = f2bf(o1[j] * inv);
        }
        u16* dst = Ob + ((size_t)(b2 * 8 + 0) * 4096 + posq) * 32;
        *(u16x4*)(dst + 4 * lg) = lo4;
        *(u16x4*)(dst + 16 + 4 * lg) = hi4;
      }
      return;
    }
    if (u >= 2560) {  // ---- ws=4 (head 1) ----
      int r = u - 2560;
      int b4 = r >> 6;
      int qw = r & 63;
      const size_t hb1 = (size_t)(b4 * 8 + 1) * 131072;
      const u16* vb0 = Vt + hb1 + (size_t)lr * 4096;
      const u16* vb1 = Vt + hb1 + (size_t)(16 + lr) * 4096;
#pragma unroll
      for (int f = 0; f < 4; ++f) {
        int w = qw * 4 + f;
        int pbase = ((w >> 4) << 8) + ((w & 15) << 2);
        int posq = pbase + ((lr >> 2) << 6) + (lr & 3);
        Frag qf4, kf4;
        qf4.u = *(const u16x8*)(Qb + hb1 + (size_t)posq * 32 + 8 * lg);
        kf4.u = *(const u16x8*)(Kb + hb1 + (size_t)posq * 32 + 8 * lg);
        int a1 = pbase + 2 * (lg & 1) * 64;
        Frag44 v0u, v1u;
        v0u.h[0] = *(const u16x4*)(vb0 + a1);
        v0u.h[1] = *(const u16x4*)(vb0 + a1 + 64);
        v1u.h[0] = *(const u16x4*)(vb1 + a1);
        v1u.h[1] = *(const u16x4*)(vb1 + a1 + 64);
        f32x4 zz = {};
        f32x4 s0 = __builtin_amdgcn_mfma_f32_16x16x32_bf16(kf4.b, qf4.b, zz, 0, 0, 0);
        float p[4];
        float ls = 0.f;
#pragma unroll
        for (int j = 0; j < 4; ++j) {
          p[j] = fexp2(s0[j]);
          ls += p[j];
        }
        unsigned pk0, pk1;
        asm("v_cvt_pk_bf16_f32 %0, %1, %2" : "=v"(pk0) : "v"(p[0]), "v"(p[1]));
        asm("v_cvt_pk_bf16_f32 %0, %1, %2" : "=v"(pk1) : "v"(p[2]), "v"(p[3]));
        Frag pfr;
        pnet16(pk0, pk1, pfr);
        f32x4 o0 = {}, o1 = {};
        o0 = __builtin_amdgcn_mfma_f32_16x16x32_bf16(v0u.b, pfr.b, o0, 0, 0, 0);
        o1 = __builtin_amdgcn_mfma_f32_16x16x32_bf16(v1u.b, pfr.b, o1, 0, 0, 0);
        ls += __shfl_xor(ls, 16, 64);
        ls += __shfl_xor(ls, 32, 64);
        float inv = 1.f / ls;
        u16x4 lo4, hi4;
#pragma unroll
        for (int j = 0; j < 4; ++j) {
          lo4[j] = f2bf(o0[j] * inv);
          hi4[j] = f2bf(o1[j] * inv);
        }
        u16* dst = Ob + ((size_t)(b4 * 8 + 1) * 4096 + posq) * 32;
        *(u16x4*)(dst + 4 * lg) = lo4;
        *(u16x4*)(dst + 16 + 4 * lg) = hi4;
      }
      return;
    }
    if (u < 512) {
      head = 3; lws = 4;
      b = u >> 6;
      int qb = (u & 63) << 6;
      int w = qb >> 8;
      i0 = qb & 255;
      by = (w >> 2) * 16;
      bx = (w & 3) * 16;
      j_begin = 0; j_end = 256;
    } else if (u < 1024) {
      head = 2; lws = 3;
      int u2 = u - 512;
      b = u2 >> 6;
      int w = u2 & 63;
      i0 = 0;
      by = (w >> 3) * 8;
      bx = (w & 7) * 8;
      j_begin = 0; j_end = 64;
    } else {
      int r = u - 1024;
      b = r / 192;
      int rr = r % 192;
      head = 5 + (rr >> 6);
      lws = 6;
      by = rr & 63; bx = 0; i0 = 0;
      j_begin = 0; j_end = 64;
    }
  }
  const int wsm = (1 << lws) - 1;
  const size_t hb = (size_t)(b * 8 + head) * 131072;
  auto mapP = [&](int i) { return ((by + (i >> lws)) << 6) + bx + (i & wsm); };

  Frag qf[4];
#pragma unroll
  for (int f = 0; f < 4; ++f)
    qf[f].u = *(const u16x8*)(Qb + hb + (size_t)mapP(i0 + 16 * f + lr) * 32 + 8 * lg);

  f32x4 oT[4][2] = {};
  float lsum[4] = {0.f, 0.f, 0.f, 0.f};

  auto chunk = [&](const Frag& k0, const Frag& k1, const Frag& v0, const Frag& v1) {
#pragma unroll
    for (int f = 0; f < 4; ++f) {
      f32x4 zz = {};
      f32x4 s0 = __builtin_amdgcn_mfma_f32_16x16x32_bf16(k0.b, qf[f].b, zz, 0, 0, 0);
      f32x4 s1 = __builtin_amdgcn_mfma_f32_16x16x32_bf16(k1.b, qf[f].b, zz, 0, 0, 0);
      float p[8];
#pragma unroll
      for (int j = 0; j < 4; ++j) {
        p[j] = fexp2(s0[j]);
        p[4 + j] = fexp2(s1[j]);
      }
#pragma unroll
      for (int j = 0; j < 8; ++j) lsum[f] += p[j];
      unsigned pk0, pk1, pk2, pk3;
      asm("v_cvt_pk_bf16_f32 %0, %1, %2" : "=v"(pk0) : "v"(p[0]), "v"(p[1]));
      asm("v_cvt_pk_bf16_f32 %0, %1, %2" : "=v"(pk1) : "v"(p[2]), "v"(p[3]));
      asm("v_cvt_pk_bf16_f32 %0, %1, %2" : "=v"(pk2) : "v"(p[4]), "v"(p[5]));
      asm("v_cvt_pk_bf16_f32 %0, %1, %2" : "=v"(pk3) : "v"(p[6]), "v"(p[7]));
      int a0 = __builtin_amdgcn_ds_bpermute(addrA, (int)pk0);
      int a1 = __builtin_amdgcn_ds_bpermute(addrA, (int)pk1);
      int a2 = __builtin_amdgcn_ds_bpermute(addrB, (int)pk0);
      int a3 = __builtin_amdgcn_ds_bpermute(addrB, (int)pk1);
      int b0 = __builtin_amdgcn_ds_bpermute(addrA, (int)pk2);
      int b1 = __builtin_amdgcn_ds_bpermute(addrA, (int)pk3);
      int b2 = __builtin_amdgcn_ds_bpermute(addrB, (int)pk2);
      int b3 = __builtin_amdgcn_ds_bpermute(addrB, (int)pk3);
      union { unsigned w[4]; Frag fr; } pb;
      pb.w[0] = (unsigned)(lo_half ? a0 : b0);
      pb.w[1] = (unsigned)(lo_half ? a1 : b1);
      pb.w[2] = (unsigned)(lo_half ? a2 : b2);
      pb.w[3] = (unsigned)(lo_half ? a3 : b3);
      oT[f][0] = __builtin_amdgcn_mfma_f32_16x16x32_bf16(v0.b, pb.fr.b, oT[f][0], 0, 0, 0);
      oT[f][1] = __builtin_amdgcn_mfma_f32_16x16x32_bf16(v1.b, pb.fr.b, oT[f][1], 0, 0, 0);
    }
  };

  Frag k0A, k1A, v0A, v1A, k0B, k1B, v0B, v1B;
  auto loadKV = [&](int j0, Frag& a, Frag& c, Frag& d, Frag& e) {
    a.u = *(const u16x8*)(Kb + hb + (size_t)mapP(j0 + lr) * 32 + 8 * lg);
    c.u = *(const u16x8*)(Kb + hb + (size_t)mapP(j0 + 16 + lr) * 32 + 8 * lg);
    int pv = mapP(j0 + 8 * lg);
    d.u = *(const u16x8*)(Vt + hb + (size_t)lr * 4096 + pv);
    e.u = *(const u16x8*)(Vt + hb + (size_t)(16 + lr) * 4096 + pv);
  };

  loadKV(j_begin, k0A, k1A, v0A, v1A);
  for (int j0 = j_begin; j0 < j_end; j0 += 64) {
    loadKV(j0 + 32, k0B, k1B, v0B, v1B);
    chunk(k0A, k1A, v0A, v1A);
    if (j0 + 64 < j_end) loadKV(j0 + 64, k0A, k1A, v0A, v1A);
    chunk(k0B, k1B, v0B, v1B);
  }

  if (!split) {
#pragma unroll
    for (int f = 0; f < 4; ++f) {
      float s = lsum[f];
      s += __shfl_xor(s, 16, 64);
      s += __shfl_xor(s, 32, 64);
      float inv = 1.f / s;
      int q = i0 + 16 * f + lr;
      u16x4 lo, hi;
#pragma unroll
      for (int j = 0; j < 4; ++j) {
        lo[j] = f2bf(oT[f][0][j] * inv);
        hi[j] = f2bf(oT[f][1][j] * inv);
      }
      if (head < 5) {
        int p = mapP(q);
        u16* dst = Ob + ((size_t)(b * 8 + head) * 4096 + p) * 32;
        *(u16x4*)(dst + 4 * lg) = lo;
        *(u16x4*)(dst + 16 + 4 * lg) = hi;
      } else {
        int n = head - 5;
        int g32 = ((n * 64 + by) << 6) + q;
        int m3 = g32 % 3, sp = g32 / 3;
        u16* dst = Ob + ((size_t)(b * 8 + 5 + m3) * 4096 + sp) * 32;
        *(u16x4*)(dst + 4 * lg) = lo;
        *(u16x4*)(dst + 16 + 4 * lg) = hi;
      }
    }
  } else {
    // split-K combine: two h-phases through 17KB LDS
    float ot0[4], ot1[4];
    float ls = 0.f;
#pragma unroll 1
    for (int h = 0; h < 2; ++h) {
      __syncthreads();
#pragma unroll
      for (int f = 0; f < 4; ++f) {
#pragma unroll
        for (int j = 0; j < 4; ++j) sm_o[wv][f][j][lane] = oT[f][h][j];
        if (h == 0) {
          float s = lsum[f];
          s += __shfl_xor(s, 16, 64);
          s += __shfl_xor(s, 32, 64);
          if (lg == 0) sm_l[wv][f][lr] = s;
        }
      }
      __syncthreads();
      int f = wv;
      float* ot = (h == 0) ? ot0 : ot1;
#pragma unroll
      for (int j = 0; j < 4; ++j) ot[j] = 0.f;
#pragma unroll
      for (int w = 0; w < 4; ++w) {
        if (h == 0) ls += sm_l[w][f][lr];
#pragma unroll
        for (int j = 0; j < 4; ++j) ot[j] += sm_o[w][f][j][lane];
      }
    }
    float inv = 1.f / ls;
    int f = wv;
    int q = i0 + 16 * f + lr;
    int p = mapP(q);
    u16x4 lo, hi;
#pragma unroll
    for (int j = 0; j < 4; ++j) {
      lo[j] = f2bf(ot0[j] * inv);
      hi[j] = f2bf(ot1[j] * inv);
    }
    u16* dst = Ob + ((size_t)(b * 8 + head) * 4096 + p) * 32;
    *(u16x4*)(dst + 4 * lg) = lo;
    *(u16x4*)(dst + 16 + 4 * lg) = hi;
  }
}

extern "C" void kernel_launch(void* const* d_in, const int* in_sizes, int n_in,
                              void* d_out, int out_size, void* d_ws, size_t ws_size,
                              hipStream_t stream) {
  const float* x = (const float*)d_in[0];
  const float* temp = (const float*)d_in[1];
  const float* w_qkv = (const float*)d_in[2];
  const float* w_v = (const float*)d_in[3];
  const float* w_proj = (const float*)d_in[4];
  const float* b_proj = (const float*)d_in[5];
  const float* w_temp = (const float*)d_in[6];
  const float* b_temp = (const float*)d_in[7];
  (void)in_sizes; (void)n_in; (void)out_size; (void)ws_size;

  char* ws = (char*)d_ws;
  u16* w_qt = (u16*)(ws + 0);              // 262144 B
  u16* w_qkv_bf = (u16*)(ws + 262144);     // 262144 B
  u16* w_proj_bf = (u16*)(ws + 524288);    // 131072 B
  float* qbias = (float*)(ws + 655360);    // 1024 B
  float* qsmall = (float*)(ws + 656384);   // 2097152 B  [b][p16][o]
  u16* q_buf = (u16*)(ws + 2753536);       // 16777216 B [b][h][p][d]
  u16* k_buf = (u16*)(ws + 19530752);      // 16777216 B [b][h][p][d]
  u16* v_t = (u16*)(ws + 53085184);        // 16777216 B [b][h][d][p]
  u16* o_buf = (u16*)(ws + 69862400);      // 16777216 B [b][h][p][32] planes (aliased: x_t before attn)
  u16* x_t = o_buf;                        // [b][p][c] bf16 — dead before o_buf written
  float* out = (float*)d_out;

  k_prep<<<1024, 256, 0, stream>>>(w_qkv, w_v, w_proj, w_temp, b_temp,
                                   w_qt, qbias, w_qkv_bf, w_proj_bf);
  k_xt<<<2048, 256, 0, stream>>>(x, x_t);
  k_gemm0<<<dim3(4, 4, 8), 256, 0, stream>>>(w_qt, temp, qsmall);
  k_resize<<<4096, 256, 0, stream>>>(qsmall, qbias, q_buf);
  k_gemmx<1><<<2048, 256, 0, stream>>>(w_qkv_bf, x_t, nullptr, k_buf, v_t,
                                       nullptr, nullptr);
  k_attn<<<1408, 256, 0, stream>>>(q_buf, k_buf, v_t, o_buf);
  k_gemmx<2><<<1024, 256, 0, stream>>>(w_proj_bf, o_buf, out, nullptr, nullptr,
                                       b_proj, x);
}

// Round 10
// 116.546 us; speedup vs baseline: 1.0677x; 1.0308x over previous
//
#include <hip/hip_runtime.h>

typedef unsigned short u16;
typedef float f32x4 __attribute__((ext_vector_type(4)));
typedef unsigned short u16x8 __attribute__((ext_vector_type(8)));
typedef unsigned short u16x4 __attribute__((ext_vector_type(4)));
typedef unsigned short u16x2 __attribute__((ext_vector_type(2)));
typedef __bf16 bf16x8 __attribute__((ext_vector_type(8)));

union Frag { u16x8 u; bf16x8 b; };
union Frag44 { u16x4 h[2]; u16x8 u; bf16x8 b; };
union Frag22 { u16x2 q[4]; u16x8 u; bf16x8 b; };

#define DEVFN static __device__ __forceinline__

DEVFN u16 f2bf(float f) {
  unsigned u = __builtin_bit_cast(unsigned, f);
  u += 0x7FFFu + ((u >> 16) & 1u);
  return (u16)(u >> 16);
}
DEVFN float bf2f(u16 h) {
  return __builtin_bit_cast(float, ((unsigned)h) << 16);
}
DEVFN int bswz(int n, int k) { return k ^ ((((n >> 4) ^ n) & 7) << 3); }

DEVFN float fexp2(float x) {
#if __has_builtin(__builtin_amdgcn_exp2f)
  return __builtin_amdgcn_exp2f(x);
#else
  float r;
  asm volatile("v_exp_f32 %0, %1\n\ts_nop 1" : "=v"(r) : "v"(x));
  return r;
#endif
}

DEVFN void gl16(const u16* g, u16* l) {
  __builtin_amdgcn_global_load_lds(
      (const __attribute__((address_space(1))) unsigned int*)g,
      (__attribute__((address_space(3))) unsigned int*)l, 16, 0, 0);
}

#define QSC (0.17677669529663687f * 1.44269504088896341f)

// ---------------- prep ----------------
__global__ __launch_bounds__(256) void k_prep(
    const float* __restrict__ w_qkv, const float* __restrict__ w_v,
    const float* __restrict__ w_proj, const float* __restrict__ w_temp,
    const float* __restrict__ b_temp,
    u16* __restrict__ w_qt, float* __restrict__ qbias,
    u16* __restrict__ w_qkv_bf, u16* __restrict__ w_proj_bf) {
  __shared__ float wvr[256];
  __shared__ float red[256];
  int t = threadIdx.x, blk = blockIdx.x;
  if (blk < 256) {
    wvr[t] = w_v[blk * 256 + t];
    __syncthreads();
    for (int c = t; c < 512; c += 256) {
      float acc = 0.f;
      for (int m = 0; m < 256; ++m) acc += wvr[m] * w_temp[m * 512 + c];
      w_qt[blk * 512 + c] = f2bf(acc);
    }
    red[t] = wvr[t] * b_temp[t];
    __syncthreads();
    for (int s = 128; s > 0; s >>= 1) {
      if (t < s) red[t] += red[t + s];
      __syncthreads();
    }
    if (t == 0) qbias[blk] = red[0];
  } else {
    int e = (blk - 256) * 256 + t;
    if (e < 512 * 256) w_qkv_bf[e] = f2bf(w_qkv[e]);
    else {
      int e2 = e - 512 * 256;
      w_proj_bf[e2] = f2bf(w_proj[e2]);
    }
  }
}

// ---------------- x transpose+cvt ----------------
__global__ __launch_bounds__(256) void k_xt(
    const float* __restrict__ x, u16* __restrict__ xt) {
  __shared__ float lds[64][65];
  int t = threadIdx.x, bid = blockIdx.x;
  int b = bid >> 8, rem = bid & 255;
  int c0 = (rem >> 6) << 6;
  int p0 = (rem & 63) << 6;
  int cr = t >> 2, pc = (t & 3) * 16;
  const float* src = x + (size_t)(b * 256 + c0 + cr) * 4096 + p0 + pc;
#pragma unroll
  for (int i = 0; i < 4; ++i) {
    f32x4 v = *(const f32x4*)(src + 4 * i);
#pragma unroll
    for (int j = 0; j < 4; ++j) lds[cr][pc + 4 * i + j] = v[j];
  }
  __syncthreads();
  int pr = t >> 2, cq = (t & 3) * 16;
  u16x8 o0, o1;
#pragma unroll
  for (int j = 0; j < 8; ++j) {
    o0[j] = f2bf(lds[cq + j][pr]);
    o1[j] = f2bf(lds[cq + 8 + j][pr]);
  }
  u16* dst = xt + ((size_t)(b * 4096) + p0 + pr) * 256 + c0 + cq;
  *(u16x8*)dst = o0;
  *(u16x8*)(dst + 8) = o1;
}

// ---------------- qsmall GEMM ----------------
__global__ __launch_bounds__(256) void k_gemm0(
    const u16* __restrict__ A, const float* __restrict__ Bf, float* __restrict__ Cf) {
  constexpr int N = 256, K = 512;
  const int t = threadIdx.x;
  const int lane = t & 63;
  const int wv = t >> 6;
  const int n0 = blockIdx.x * 64;
  const int m0 = blockIdx.y * 64;
  const int b = blockIdx.z;

  __shared__ __align__(16) u16 lds[2 * 64 * 72];
  u16(*lds_a)[72] = (u16(*)[72])lds;
  u16(*lds_b)[72] = (u16(*)[72])(lds + 64 * 72);

  f32x4 acc[2][2] = {};
  const int mq = (wv >> 1) * 32, nq = (wv & 1) * 32;
  const int lr = lane & 15, lg = lane >> 4;

  for (int k0 = 0; k0 < K; k0 += 64) {
    __syncthreads();
    {
      int m = t >> 2, c0 = (t & 3) * 16;
      const u16* src = A + (size_t)(m0 + m) * K + k0 + c0;
      *(u16x8*)&lds_a[m][c0] = *(const u16x8*)src;
      *(u16x8*)&lds_a[m][c0 + 8] = *(const u16x8*)(src + 8);
    }
    {
      int k = t >> 2, nn0 = (t & 3) * 16;
      const float* src = Bf + (size_t)b * K * N + (size_t)(k0 + k) * N + n0 + nn0;
#pragma unroll
      for (int i4 = 0; i4 < 4; ++i4) {
        f32x4 v = *(const f32x4*)(src + i4 * 4);
#pragma unroll
        for (int j = 0; j < 4; ++j) {
          int n = nn0 + i4 * 4 + j;
          lds_b[n][bswz(n, k)] = f2bf(v[j]);
        }
      }
    }
    __syncthreads();
#pragma unroll
    for (int kk = 0; kk < 2; ++kk) {
      Frag af[2], bfr[2];
#pragma unroll
      for (int i = 0; i < 2; ++i) {
        af[i].u = *(const u16x8*)&lds_a[mq + 16 * i + lr][kk * 32 + 8 * lg];
        int n = nq + 16 * i + lr;
        bfr[i].u = *(const u16x8*)&lds_b[n][bswz(n, kk * 32 + 8 * lg)];
      }
#pragma unroll
      for (int mi = 0; mi < 2; ++mi)
#pragma unroll
        for (int ni = 0; ni < 2; ++ni)
          acc[mi][ni] = __builtin_amdgcn_mfma_f32_16x16x32_bf16(
              af[mi].b, bfr[ni].b, acc[mi][ni], 0, 0, 0);
    }
  }
#pragma unroll
  for (int mi = 0; mi < 2; ++mi)
#pragma unroll
    for (int ni = 0; ni < 2; ++ni) {
      int mbase = m0 + mq + 16 * mi + 4 * lg;
      int n = n0 + nq + 16 * ni + lr;
      *(f32x4*)(Cf + ((size_t)b * 256 + n) * 256 + mbase) = acc[mi][ni];
    }
}

// ---------------- DMA-staged 64x128 GEMM ----------------
template <int V>
__global__ __launch_bounds__(256) void k_gemmx(
    const u16* __restrict__ A, const u16* __restrict__ Bh, float* __restrict__ Cf,
    u16* __restrict__ Kb, u16* __restrict__ Vt,
    const float* __restrict__ bias, const float* __restrict__ Xres) {
  const int t = threadIdx.x, lane = t & 63, wv = t >> 6;
  const int lr = lane & 15, lg = lane >> 4;
  int bid = blockIdx.x;
  int s = bid & 7, w = bid >> 3;
  int gid, mt;
  if constexpr (V == 1) { gid = (w & ~7) | s; mt = w & 7; }
  else { gid = ((w >> 2) << 3) | s; mt = w & 3; }
  const int nt = gid & 31, b = gid >> 5;
  const int m0 = mt * 64, n0 = nt * 128;

  __shared__ __align__(16) u16 ldsAB[192 * 64];

  f32x4 acc[2][4] = {};
  const int mq = (wv >> 1) * 32, nq = (wv & 1) * 64;
  const size_t bOff = (size_t)b * 4096 * 256;
  const int sub = lane >> 3, c = lane & 7;

  for (int k0 = 0; k0 < 256; k0 += 64) {
    __syncthreads();
#pragma unroll
    for (int i = wv; i < 24; i += 4) {
      const u16* g;
      if (i < 8) {
        g = A + (size_t)(m0 + i * 8 + sub) * 256 + k0 + ((c ^ sub) << 3);
      } else {
        int rn = n0 + i * 8 + sub - 64;
        int ch = k0 + ((c ^ sub) << 3);
        if constexpr (V == 1)
          g = Bh + bOff + (size_t)rn * 256 + ch;
        else
          g = Bh + ((size_t)(b * 8 + (ch >> 5)) * 4096 + rn) * 32 + (ch & 31);
      }
      gl16(g, &ldsAB[i * 512]);
    }
    __syncthreads();
#pragma unroll
    for (int kk = 0; kk < 2; ++kk) {
      Frag af[2], bfr[4];
#pragma unroll
      for (int mi = 0; mi < 2; ++mi) {
        int r = mq + 16 * mi + lr;
        af[mi].u = *(const u16x8*)&ldsAB[r * 64 + (((kk * 4 + lg) ^ (r & 7)) << 3)];
      }
#pragma unroll
      for (int ni = 0; ni < 4; ++ni) {
        int rn = nq + 16 * ni + lr;
        bfr[ni].u = *(const u16x8*)&ldsAB[(64 + rn) * 64 + (((kk * 4 + lg) ^ (rn & 7)) << 3)];
      }
#pragma unroll
      for (int mi = 0; mi < 2; ++mi)
#pragma unroll
        for (int ni = 0; ni < 4; ++ni)
          acc[mi][ni] = __builtin_amdgcn_mfma_f32_16x16x32_bf16(
              af[mi].b, bfr[ni].b, acc[mi][ni], 0, 0, 0);
    }
  }

  if constexpr (V == 1) {
    if (m0 < 256) {
#pragma unroll
      for (int mi = 0; mi < 2; ++mi)
#pragma unroll
        for (int ni = 0; ni < 4; ++ni) {
          int mbase = m0 + mq + 16 * mi + 4 * lg;
          int n = n0 + nq + 16 * ni + lr;
          u16x4 pk;
#pragma unroll
          for (int j = 0; j < 4; ++j) pk[j] = f2bf(acc[mi][ni][j]);
          int head = mbase >> 5, d = mbase & 31;
          *(u16x4*)(Kb + ((size_t)(b * 8 + head) * 4096 + n) * 32 + d) = pk;
        }
    } else {
      float(*lds_t)[68] = (float(*)[68])ldsAB;
#pragma unroll 1
      for (int r = 0; r < 2; ++r) {
        __syncthreads();
        if ((wv & 1) == r) {
#pragma unroll
          for (int mi = 0; mi < 2; ++mi)
#pragma unroll
            for (int ni = 0; ni < 4; ++ni)
#pragma unroll
              for (int j = 0; j < 4; ++j)
                lds_t[mq + 16 * mi + 4 * lg + j][16 * ni + lr] = acc[mi][ni][j];
        }
        __syncthreads();
        int dloc = t >> 2, nc = (t & 3) * 16;
        int dg = (m0 - 256) + dloc;
        int head = dg >> 5, d = dg & 31;
        u16x8 o0, o1;
#pragma unroll
        for (int i = 0; i < 8; ++i) {
          o0[i] = f2bf(lds_t[dloc][nc + i]);
          o1[i] = f2bf(lds_t[dloc][nc + 8 + i]);
        }
        u16* dst = Vt + ((size_t)(b * 8 + head) * 32 + d) * 4096 + n0 + 64 * r + nc;
        *(u16x8*)dst = o0;
        *(u16x8*)(dst + 8) = o1;
      }
    }
  } else {
#pragma unroll
    for (int mi = 0; mi < 2; ++mi)
#pragma unroll
      for (int ni = 0; ni < 4; ++ni) {
        int mbase = m0 + mq + 16 * mi + 4 * lg;
        int n = n0 + nq + 16 * ni + lr;
#pragma unroll
        for (int j = 0; j < 4; ++j) {
          int m = mbase + j;
          size_t off = ((size_t)b * 256 + m) * 4096 + n;
          Cf[off] = acc[mi][ni][j] + bias[m] + Xres[off];
        }
      }
  }
}

// ---------------- bilinear resize ----------------
DEVFN void blc(int y, int& i0, int& i1, float& w) {
  float fy = 0.25f * y - 0.375f;
  float ff = floorf(fy);
  w = fy - ff;
  int i = (int)ff;
  i0 = i < 0 ? 0 : i;
  i1 = (i + 1 > 15) ? 15 : i + 1;
}

__global__ __launch_bounds__(256) void k_resize(
    const float* __restrict__ qsmall, const float* __restrict__ qbias,
    u16* __restrict__ Qb) {
  int gid = blockIdx.x * 256 + threadIdx.x;
  int c8 = gid & 31;
  int p = (gid >> 5) & 4095;
  int b = gid >> 17;
  int y = p >> 6, x = p & 63;
  int y0, y1, x0, x1;
  float wy, wx;
  blc(y, y0, y1, wy);
  blc(x, x0, x1, wx);
  const float* base = qsmall + (size_t)b * 65536;
  int o0 = c8 * 8;
  const float* r00 = base + (y0 * 16 + x0) * 256 + o0;
  const float* r01 = base + (y0 * 16 + x1) * 256 + o0;
  const float* r10 = base + (y1 * 16 + x0) * 256 + o0;
  const float* r11 = base + (y1 * 16 + x1) * 256 + o0;
  float w00 = (1 - wy) * (1 - wx), w01 = (1 - wy) * wx;
  float w10 = wy * (1 - wx), w11 = wy * wx;
  u16x8 outv;
#pragma unroll
  for (int i = 0; i < 8; ++i) {
    float v = w00 * r00[i] + w01 * r01[i] + w10 * r10[i] + w11 * r11[i] + qbias[o0 + i];
    outv[i] = f2bf(v * QSC);
  }
  int head = o0 >> 5, d = o0 & 31;
  *(u16x8*)(Qb + ((size_t)(b * 8 + head) * 4096 + p) * 32 + d) = outv;
}

// ---------------- MFMA attention body (NF frags per wave) ----------------
template <int NF>
DEVFN void attn_body(const u16* __restrict__ Qb, const u16* __restrict__ Kb,
                     const u16* __restrict__ Vt, u16* __restrict__ Ob,
                     int b, int head, int lws, int i0, int by, int bx,
                     int j_begin, int j_end, int split,
                     int lane, int wv, float* smo, float* sml) {
  const int lr = lane & 15, lg = lane >> 4;
  const int addrA = (32 * (lg & 1) + lr) * 4;
  const int addrB = addrA + 64;
  const bool lo_half = (lg < 2);
  const int wsm = (1 << lws) - 1;
  const size_t hb = (size_t)(b * 8 + head) * 131072;
  auto mapP = [&](int i) { return ((by + (i >> lws)) << 6) + bx + (i & wsm); };

  Frag qf[NF];
#pragma unroll
  for (int f = 0; f < NF; ++f)
    qf[f].u = *(const u16x8*)(Qb + hb + (size_t)mapP(i0 + 16 * f + lr) * 32 + 8 * lg);

  f32x4 oT[NF][2] = {};
  float lsum[NF] = {};

  auto chunk = [&](const Frag& k0, const Frag& k1, const Frag& v0, const Frag& v1) {
#pragma unroll
    for (int f = 0; f < NF; ++f) {
      f32x4 zz = {};
      f32x4 s0 = __builtin_amdgcn_mfma_f32_16x16x32_bf16(k0.b, qf[f].b, zz, 0, 0, 0);
      f32x4 s1 = __builtin_amdgcn_mfma_f32_16x16x32_bf16(k1.b, qf[f].b, zz, 0, 0, 0);
      float p[8];
#pragma unroll
      for (int j = 0; j < 4; ++j) {
        p[j] = fexp2(s0[j]);
        p[4 + j] = fexp2(s1[j]);
      }
#pragma unroll
      for (int j = 0; j < 8; ++j) lsum[f] += p[j];
      unsigned pk0, pk1, pk2, pk3;
      asm("v_cvt_pk_bf16_f32 %0, %1, %2" : "=v"(pk0) : "v"(p[0]), "v"(p[1]));
      asm("v_cvt_pk_bf16_f32 %0, %1, %2" : "=v"(pk1) : "v"(p[2]), "v"(p[3]));
      asm("v_cvt_pk_bf16_f32 %0, %1, %2" : "=v"(pk2) : "v"(p[4]), "v"(p[5]));
      asm("v_cvt_pk_bf16_f32 %0, %1, %2" : "=v"(pk3) : "v"(p[6]), "v"(p[7]));
      int a0 = __builtin_amdgcn_ds_bpermute(addrA, (int)pk0);
      int a1 = __builtin_amdgcn_ds_bpermute(addrA, (int)pk1);
      int a2 = __builtin_amdgcn_ds_bpermute(addrB, (int)pk0);
      int a3 = __builtin_amdgcn_ds_bpermute(addrB, (int)pk1);
      int b0 = __builtin_amdgcn_ds_bpermute(addrA, (int)pk2);
      int b1 = __builtin_amdgcn_ds_bpermute(addrA, (int)pk3);
      int b2 = __builtin_amdgcn_ds_bpermute(addrB, (int)pk2);
      int b3 = __builtin_amdgcn_ds_bpermute(addrB, (int)pk3);
      union { unsigned w[4]; Frag fr; } pb;
      pb.w[0] = (unsigned)(lo_half ? a0 : b0);
      pb.w[1] = (unsigned)(lo_half ? a1 : b1);
      pb.w[2] = (unsigned)(lo_half ? a2 : b2);
      pb.w[3] = (unsigned)(lo_half ? a3 : b3);
      oT[f][0] = __builtin_amdgcn_mfma_f32_16x16x32_bf16(v0.b, pb.fr.b, oT[f][0], 0, 0, 0);
      oT[f][1] = __builtin_amdgcn_mfma_f32_16x16x32_bf16(v1.b, pb.fr.b, oT[f][1], 0, 0, 0);
    }
  };

  Frag k0A, k1A, v0A, v1A, k0B, k1B, v0B, v1B;
  auto loadKV = [&](int j0, Frag& a, Frag& c, Frag& d, Frag& e) {
    a.u = *(const u16x8*)(Kb + hb + (size_t)mapP(j0 + lr) * 32 + 8 * lg);
    c.u = *(const u16x8*)(Kb + hb + (size_t)mapP(j0 + 16 + lr) * 32 + 8 * lg);
    int pv = mapP(j0 + 8 * lg);
    d.u = *(const u16x8*)(Vt + hb + (size_t)lr * 4096 + pv);
    e.u = *(const u16x8*)(Vt + hb + (size_t)(16 + lr) * 4096 + pv);
  };

  loadKV(j_begin, k0A, k1A, v0A, v1A);
  for (int j0 = j_begin; j0 < j_end; j0 += 64) {
    loadKV(j0 + 32, k0B, k1B, v0B, v1B);
    chunk(k0A, k1A, v0A, v1A);
    if (j0 + 64 < j_end) loadKV(j0 + 64, k0A, k1A, v0A, v1A);
    chunk(k0B, k1B, v0B, v1B);
  }

  if (!split) {
#pragma unroll
    for (int f = 0; f < NF; ++f) {
      float s = lsum[f];
      s += __shfl_xor(s, 16, 64);
      s += __shfl_xor(s, 32, 64);
      float inv = 1.f / s;
      int q = i0 + 16 * f + lr;
      u16x4 lo, hi;
#pragma unroll
      for (int j = 0; j < 4; ++j) {
        lo[j] = f2bf(oT[f][0][j] * inv);
        hi[j] = f2bf(oT[f][1][j] * inv);
      }
      if (head < 5) {
        int p = mapP(q);
        u16* dst = Ob + ((size_t)(b * 8 + head) * 4096 + p) * 32;
        *(u16x4*)(dst + 4 * lg) = lo;
        *(u16x4*)(dst + 16 + 4 * lg) = hi;
      } else {
        int n = head - 5;
        int g32 = ((n * 64 + by) << 6) + q;
        int m3 = g32 % 3, sp = g32 / 3;
        u16* dst = Ob + ((size_t)(b * 8 + 5 + m3) * 4096 + sp) * 32;
        *(u16x4*)(dst + 4 * lg) = lo;
        *(u16x4*)(dst + 16 + 4 * lg) = hi;
      }
    }
    return;
  }

  if constexpr (NF == 2) {
#pragma unroll
    for (int f = 0; f < 2; ++f) {
      float s = lsum[f];
      s += __shfl_xor(s, 16, 64);
      s += __shfl_xor(s, 32, 64);
      if (lg == 0) sml[(wv * 2 + f) * 16 + lr] = s;
#pragma unroll
      for (int h = 0; h < 2; ++h)
#pragma unroll
        for (int j = 0; j < 4; ++j)
          smo[(((wv * 2 + f) * 2 + h) * 4 + j) * 64 + lane] = oT[f][h][j];
    }
    __syncthreads();
    int f = wv & 1, h = wv >> 1;
    float ot[4] = {0.f, 0.f, 0.f, 0.f};
    float ls = 0.f;
#pragma unroll
    for (int w = 0; w < 4; ++w) {
      ls += sml[(w * 2 + f) * 16 + lr];
#pragma unroll
      for (int j = 0; j < 4; ++j)
        ot[j] += smo[(((w * 2 + f) * 2 + h) * 4 + j) * 64 + lane];
    }
    float inv = 1.f / ls;
    int q = i0 + 16 * f + lr;
    int p = mapP(q);
    u16x4 v4;
#pragma unroll
    for (int j = 0; j < 4; ++j) v4[j] = f2bf(ot[j] * inv);
    u16* dst = Ob + ((size_t)(b * 8 + head) * 4096 + p) * 32 + h * 16;
    *(u16x4*)(dst + 4 * lg) = v4;
  } else {
    float ot0[4], ot1[4];
    float ls = 0.f;
#pragma unroll 1
    for (int h = 0; h < 2; ++h) {
      __syncthreads();
#pragma unroll
      for (int f = 0; f < 4; ++f) {
#pragma unroll
        for (int j = 0; j < 4; ++j) smo[((wv * 4 + f) * 4 + j) * 64 + lane] = oT[f][h][j];
        if (h == 0) {
          float s = lsum[f];
          s += __shfl_xor(s, 16, 64);
          s += __shfl_xor(s, 32, 64);
          if (lg == 0) sml[(wv * 4 + f) * 16 + lr] = s;
        }
      }
      __syncthreads();
      int f = wv;
      float* ot = (h == 0) ? ot0 : ot1;
#pragma unroll
      for (int j = 0; j < 4; ++j) ot[j] = 0.f;
#pragma unroll
      for (int w = 0; w < 4; ++w) {
        if (h == 0) ls += sml[(w * 4 + f) * 16 + lr];
#pragma unroll
        for (int j = 0; j < 4; ++j) ot[j] += smo[((w * 4 + f) * 4 + j) * 64 + lane];
      }
    }
    float inv = 1.f / ls;
    int f = wv;
    int q = i0 + 16 * f + lr;
    int p = mapP(q);
    u16x4 lo, hi;
#pragma unroll
    for (int j = 0; j < 4; ++j) {
      lo[j] = f2bf(ot0[j] * inv);
      hi[j] = f2bf(ot1[j] * inv);
    }
    u16* dst = Ob + ((size_t)(b * 8 + head) * 4096 + p) * 32;
    *(u16x4*)(dst + 4 * lg) = lo;
    *(u16x4*)(dst + 16 + 4 * lg) = hi;
  }
}

// ---------------- MFMA attention dispatcher ----------------
__global__ __launch_bounds__(256) void k_attn(
    const u16* __restrict__ Qb, const u16* __restrict__ Kb,
    const u16* __restrict__ Vt, u16* __restrict__ Ob, int base) {
  const int t = threadIdx.x, lane = t & 63, wv = t >> 6;
  const int lr = lane & 15, lg = lane >> 4;

  __shared__ float smo[4096];
  __shared__ float sml[256];

  int vbid = base + blockIdx.x;
  if (vbid < 1024) {  // head4: 32-query split blocks, XCD-grouped
    int L = (vbid & 7) * 128 + (vbid >> 3);
    int b = L >> 7, g = L & 127;
    int w = g >> 5;
    attn_body<2>(Qb, Kb, Vt, Ob, b, 4, 5, (g & 31) * 32, (w >> 1) * 32, (w & 1) * 32,
                 wv * 256, wv * 256 + 256, 1, lane, wv, smo, sml);
    return;
  }
  if (vbid < 1536) {  // head3: 64q blocks, split-K 64 keys/wave
    int r = vbid - 1024;
    int b = r >> 6, g = r & 63;
    int w = g >> 2;
    attn_body<4>(Qb, Kb, Vt, Ob, b, 3, 4, (g & 3) * 64, (w >> 2) * 16, (w & 3) * 16,
                 wv * 64, wv * 64 + 64, 1, lane, wv, smo, sml);
    return;
  }
  int u = (vbid - 1536) * 4 + wv;
  const int addrA = (32 * (lg & 1) + lr) * 4;
  const int addrB = addrA + 64;
  const bool lo_half = (lg < 2);
  auto pnet16 = [&](unsigned pk0, unsigned pk1, Frag& out) {
    union { unsigned w[4]; Frag fr; } pb;
    int a0 = __builtin_amdgcn_ds_bpermute(addrA, (int)pk0);
    int a1 = __builtin_amdgcn_ds_bpermute(addrA, (int)pk1);
    int a2 = __builtin_amdgcn_ds_bpermute(addrB, (int)pk0);
    int a3 = __builtin_amdgcn_ds_bpermute(addrB, (int)pk1);
    pb.w[0] = lo_half ? (unsigned)a0 : 0u;
    pb.w[1] = lo_half ? (unsigned)a1 : 0u;
    pb.w[2] = lo_half ? (unsigned)a2 : 0u;
    pb.w[3] = lo_half ? (unsigned)a3 : 0u;
    out = pb.fr;
  };

  if (u >= 2560) {  // ws=2 (head 0)
    int r = u - 2560;
    int b2 = r >> 6;
    int qw = r & 63;
    const size_t hb0 = (size_t)(b2 * 8 + 0) * 131072;
    const u16* vb0 = Vt + hb0 + (size_t)lr * 4096;
    const u16* vb1 = Vt + hb0 + (size_t)(16 + lr) * 4096;
    const bool valid = (lg == (lr >> 2));
    const int lgm = lg & 1;
#pragma unroll
    for (int f = 0; f < 4; ++f) {
      int g = qw * 4 + f;
      int W = g * 4 + (lr >> 2);
      int wbase = (W >> 5) * 128 + (W & 31) * 2;
      int qj = lr & 3;
      int posq = wbase + ((qj >> 1) << 6) + (qj & 1);
      Frag qf2, kf2;
      qf2.u = *(const u16x8*)(Qb + hb0 + (size_t)posq * 32 + 8 * lg);
      kf2.u = *(const u16x8*)(Kb + hb0 + (size_t)posq * 32 + 8 * lg);
      int W0 = g * 4 + 2 * lgm;
      int base0 = (W0 >> 5) * 128 + (W0 & 31) * 2;
      int W1 = W0 + 1;
      int base1 = (W1 >> 5) * 128 + (W1 & 31) * 2;
      Frag22 v0u, v1u;
      v0u.q[0] = *(const u16x2*)(vb0 + base0);
      v0u.q[1] = *(const u16x2*)(vb0 + base0 + 64);
      v0u.q[2] = *(const u16x2*)(vb0 + base1);
      v0u.q[3] = *(const u16x2*)(vb0 + base1 + 64);
      v1u.q[0] = *(const u16x2*)(vb1 + base0);
      v1u.q[1] = *(const u16x2*)(vb1 + base0 + 64);
      v1u.q[2] = *(const u16x2*)(vb1 + base1);
      v1u.q[3] = *(const u16x2*)(vb1 + base1 + 64);
      f32x4 zz = {};
      f32x4 s0 = __builtin_amdgcn_mfma_f32_16x16x32_bf16(kf2.b, qf2.b, zz, 0, 0, 0);
      float p[4];
      float ls = 0.f;
#pragma unroll
      for (int j = 0; j < 4; ++j) {
        p[j] = valid ? fexp2(s0[j]) : 0.f;
        ls += p[j];
      }
      unsigned pk0, pk1;
      asm("v_cvt_pk_bf16_f32 %0, %1, %2" : "=v"(pk0) : "v"(p[0]), "v"(p[1]));
      asm("v_cvt_pk_bf16_f32 %0, %1, %2" : "=v"(pk1) : "v"(p[2]), "v"(p[3]));
      Frag pfr;
      pnet16(pk0, pk1, pfr);
      f32x4 o0 = {}, o1 = {};
      o0 = __builtin_amdgcn_mfma_f32_16x16x32_bf16(v0u.b, pfr.b, o0, 0, 0, 0);
      o1 = __builtin_amdgcn_mfma_f32_16x16x32_bf16(v1u.b, pfr.b, o1, 0, 0, 0);
      ls += __shfl_xor(ls, 16, 64);
      ls += __shfl_xor(ls, 32, 64);
      float inv = 1.f / ls;
      u16x4 lo4, hi4;
#pragma unroll
      for (int j = 0; j < 4; ++j) {
        lo4[j] = f2bf(o0[j] * inv);
        hi4[j] = f2bf(o1[j] * inv);
      }
      u16* dst = Ob + ((size_t)(b2 * 8 + 0) * 4096 + posq) * 32;
      *(u16x4*)(dst + 4 * lg) = lo4;
      *(u16x4*)(dst + 16 + 4 * lg) = hi4;
    }
    return;
  }
  if (u >= 2048) {  // ws=4 (head 1)
    int r = u - 2048;
    int b4 = r >> 6;
    int qw = r & 63;
    const size_t hb1 = (size_t)(b4 * 8 + 1) * 131072;
    const u16* vb0 = Vt + hb1 + (size_t)lr * 4096;
    const u16* vb1 = Vt + hb1 + (size_t)(16 + lr) * 4096;
#pragma unroll
    for (int f = 0; f < 4; ++f) {
      int w = qw * 4 + f;
      int pbase = ((w >> 4) << 8) + ((w & 15) << 2);
      int posq = pbase + ((lr >> 2) << 6) + (lr & 3);
      Frag qf4, kf4;
      qf4.u = *(const u16x8*)(Qb + hb1 + (size_t)posq * 32 + 8 * lg);
      kf4.u = *(const u16x8*)(Kb + hb1 + (size_t)posq * 32 + 8 * lg);
      int a1 = pbase + 2 * (lg & 1) * 64;
      Frag44 v0u, v1u;
      v0u.h[0] = *(const u16x4*)(vb0 + a1);
      v0u.h[1] = *(const u16x4*)(vb0 + a1 + 64);
      v1u.h[0] = *(const u16x4*)(vb1 + a1);
      v1u.h[1] = *(const u16x4*)(vb1 + a1 + 64);
      f32x4 zz = {};
      f32x4 s0 = __builtin_amdgcn_mfma_f32_16x16x32_bf16(kf4.b, qf4.b, zz, 0, 0, 0);
      float p[4];
      float ls = 0.f;
#pragma unroll
      for (int j = 0; j < 4; ++j) {
        p[j] = fexp2(s0[j]);
        ls += p[j];
      }
      unsigned pk0, pk1;
      asm("v_cvt_pk_bf16_f32 %0, %1, %2" : "=v"(pk0) : "v"(p[0]), "v"(p[1]));
      asm("v_cvt_pk_bf16_f32 %0, %1, %2" : "=v"(pk1) : "v"(p[2]), "v"(p[3]));
      Frag pfr;
      pnet16(pk0, pk1, pfr);
      f32x4 o0 = {}, o1 = {};
      o0 = __builtin_amdgcn_mfma_f32_16x16x32_bf16(v0u.b, pfr.b, o0, 0, 0, 0);
      o1 = __builtin_amdgcn_mfma_f32_16x16x32_bf16(v1u.b, pfr.b, o1, 0, 0, 0);
      ls += __shfl_xor(ls, 16, 64);
      ls += __shfl_xor(ls, 32, 64);
      float inv = 1.f / ls;
      u16x4 lo4, hi4;
#pragma unroll
      for (int j = 0; j < 4; ++j) {
        lo4[j] = f2bf(o0[j] * inv);
        hi4[j] = f2bf(o1[j] * inv);
      }
      u16* dst = Ob + ((size_t)(b4 * 8 + 1) * 4096 + posq) * 32;
      *(u16x4*)(dst + 4 * lg) = lo4;
      *(u16x4*)(dst + 16 + 4 * lg) = hi4;
    }
    return;
  }
  if (u < 512) {  // head2
    int b = u >> 6;
    int w = u & 63;
    attn_body<4>(Qb, Kb, Vt, Ob, b, 2, 3, 0, (w >> 3) * 8, (w & 7) * 8,
                 0, 64, 0, lane, wv, smo, sml);
  } else {  // row-heads 5..7
    int r = u - 512;
    int b = r / 192;
    int rr = r % 192;
    attn_body<4>(Qb, Kb, Vt, Ob, b, 5 + (rr >> 6), 6, 0, rr & 63, 0,
                 0, 64, 0, lane, wv, smo, sml);
  }
}

extern "C" void kernel_launch(void* const* d_in, const int* in_sizes, int n_in,
                              void* d_out, int out_size, void* d_ws, size_t ws_size,
                              hipStream_t stream) {
  const float* x = (const float*)d_in[0];
  const float* temp = (const float*)d_in[1];
  const float* w_qkv = (const float*)d_in[2];
  const float* w_v = (const float*)d_in[3];
  const float* w_proj = (const float*)d_in[4];
  const float* b_proj = (const float*)d_in[5];
  const float* w_temp = (const float*)d_in[6];
  const float* b_temp = (const float*)d_in[7];
  (void)in_sizes; (void)n_in; (void)out_size; (void)ws_size;

  char* ws = (char*)d_ws;
  u16* w_qt = (u16*)(ws + 0);
  u16* w_qkv_bf = (u16*)(ws + 262144);
  u16* w_proj_bf = (u16*)(ws + 524288);
  float* qbias = (float*)(ws + 655360);
  float* qsmall = (float*)(ws + 656384);
  u16* q_buf = (u16*)(ws + 2753536);
  u16* k_buf = (u16*)(ws + 19530752);
  u16* v_t = (u16*)(ws + 53085184);
  u16* o_buf = (u16*)(ws + 69862400);  // [b][h][p][32] planes (aliased: x_t before attn)
  u16* x_t = o_buf;
  float* out = (float*)d_out;

  k_prep<<<1024, 256, 0, stream>>>(w_qkv, w_v, w_proj, w_temp, b_temp,
                                   w_qt, qbias, w_qkv_bf, w_proj_bf);
  k_xt<<<2048, 256, 0, stream>>>(x, x_t);
  k_gemm0<<<dim3(4, 4, 8), 256, 0, stream>>>(w_qt, temp, qsmall);
  k_resize<<<4096, 256, 0, stream>>>(qsmall, qbias, q_buf);
  k_gemmx<1><<<2048, 256, 0, stream>>>(w_qkv_bf, x_t, nullptr, k_buf, v_t,
                                       nullptr, nullptr);
  k_attn<<<1024, 256, 0, stream>>>(q_buf, k_buf, v_t, o_buf, 0);
  k_attn<<<1280, 256, 0, stream>>>(q_buf, k_buf, v_t, o_buf, 1024);
  k_gemmx<2><<<1024, 256, 0, stream>>>(w_proj_bf, o_buf, out, nullptr, nullptr,
                                       b_proj, x);
}

// Round 11
// 95.721 us; speedup vs baseline: 1.3000x; 1.2176x over previous
//
#include <hip/hip_runtime.h>

typedef unsigned short u16;
typedef float f32x4 __attribute__((ext_vector_type(4)));
typedef unsigned short u16x8 __attribute__((ext_vector_type(8)));
typedef unsigned short u16x4 __attribute__((ext_vector_type(4)));
typedef unsigned short u16x2 __attribute__((ext_vector_type(2)));
typedef __bf16 bf16x8 __attribute__((ext_vector_type(8)));

union Frag { u16x8 u; bf16x8 b; };
union Frag44 { u16x4 h[2]; u16x8 u; bf16x8 b; };
union Frag22 { u16x2 q[4]; u16x8 u; bf16x8 b; };

#define DEVFN static __device__ __forceinline__

DEVFN u16 f2bf(float f) {
  unsigned u = __builtin_bit_cast(unsigned, f);
  u += 0x7FFFu + ((u >> 16) & 1u);
  return (u16)(u >> 16);
}
DEVFN float bf2f(u16 h) {
  return __builtin_bit_cast(float, ((unsigned)h) << 16);
}
DEVFN int bswz(int n, int k) { return k ^ ((((n >> 4) ^ n) & 7) << 3); }

DEVFN float fexp2(float x) {
#if __has_builtin(__builtin_amdgcn_exp2f)
  return __builtin_amdgcn_exp2f(x);
#else
  float r;
  asm volatile("v_exp_f32 %0, %1\n\ts_nop 1" : "=v"(r) : "v"(x));
  return r;
#endif
}

DEVFN void gl16(const u16* g, u16* l) {
  __builtin_amdgcn_global_load_lds(
      (const __attribute__((address_space(1))) unsigned int*)g,
      (__attribute__((address_space(3))) unsigned int*)l, 16, 0, 0);
}

#define QSC (0.17677669529663687f * 1.44269504088896341f)

// ---------------- stage0: prep (blocks 0..1023)  ||  x-transpose (1024..3071) ----------------
__global__ __launch_bounds__(256) void k_stage0(
    const float* __restrict__ x, const float* __restrict__ w_qkv,
    const float* __restrict__ w_v, const float* __restrict__ w_proj,
    const float* __restrict__ w_temp, const float* __restrict__ b_temp,
    u16* __restrict__ w_qt, float* __restrict__ qbias,
    u16* __restrict__ w_qkv_bf, u16* __restrict__ w_proj_bf,
    u16* __restrict__ xt) {
  __shared__ float smem[64 * 65];
  int t = threadIdx.x, blk = blockIdx.x;
  if (blk < 1024) {  // ---- prep ----
    float* wvr = smem;
    float* red = smem + 256;
    if (blk < 256) {
      wvr[t] = w_v[blk * 256 + t];
      __syncthreads();
      for (int c = t; c < 512; c += 256) {
        float acc = 0.f;
        for (int m = 0; m < 256; ++m) acc += wvr[m] * w_temp[m * 512 + c];
        w_qt[blk * 512 + c] = f2bf(acc);
      }
      red[t] = wvr[t] * b_temp[t];
      __syncthreads();
      for (int s = 128; s > 0; s >>= 1) {
        if (t < s) red[t] += red[t + s];
        __syncthreads();
      }
      if (t == 0) qbias[blk] = red[0];
    } else {
      int e = (blk - 256) * 256 + t;
      if (e < 512 * 256) w_qkv_bf[e] = f2bf(w_qkv[e]);
      else {
        int e2 = e - 512 * 256;
        w_proj_bf[e2] = f2bf(w_proj[e2]);
      }
    }
    return;
  }
  // ---- x transpose+cvt: [b][c=256][p=4096] f32 -> [b][p][c] bf16 ----
  float(*lds)[65] = (float(*)[65])smem;
  int bid = blk - 1024;
  int b = bid >> 8, rem = bid & 255;
  int c0 = (rem >> 6) << 6;
  int p0 = (rem & 63) << 6;
  int cr = t >> 2, pc = (t & 3) * 16;
  const float* src = x + (size_t)(b * 256 + c0 + cr) * 4096 + p0 + pc;
#pragma unroll
  for (int i = 0; i < 4; ++i) {
    f32x4 v = *(const f32x4*)(src + 4 * i);
#pragma unroll
    for (int j = 0; j < 4; ++j) lds[cr][pc + 4 * i + j] = v[j];
  }
  __syncthreads();
  int pr = t >> 2, cq = (t & 3) * 16;
  u16x8 o0, o1;
#pragma unroll
  for (int j = 0; j < 8; ++j) {
    o0[j] = f2bf(lds[cq + j][pr]);
    o1[j] = f2bf(lds[cq + 8 + j][pr]);
  }
  u16* dst = xt + ((size_t)(b * 4096) + p0 + pr) * 256 + c0 + cq;
  *(u16x8*)dst = o0;
  *(u16x8*)(dst + 8) = o1;
}

// ---------------- stage1: gemm0 (blocks 0..127)  ||  DMA-staged kv GEMM (128..2175) ----------------
__global__ __launch_bounds__(256) void k_stage1(
    const u16* __restrict__ Awqt, const float* __restrict__ temp,
    float* __restrict__ qsmall,
    const u16* __restrict__ Awqkv, const u16* __restrict__ xt,
    u16* __restrict__ Kb, u16* __restrict__ Vt) {
  const int t = threadIdx.x, lane = t & 63, wv = t >> 6;
  const int lr = lane & 15, lg = lane >> 4;
  __shared__ __align__(16) u16 ldsAB[192 * 64];  // 24 KB shared by both paths
  const int blk = blockIdx.x;

  if (blk < 128) {  // ---- qsmall GEMM (64x64, reg staging, f32 B) ----
    constexpr int N = 256, K = 512;
    const int n0 = (blk & 3) * 64;
    const int m0 = ((blk >> 2) & 3) * 64;
    const int b = blk >> 4;
    u16(*lds_a)[72] = (u16(*)[72])ldsAB;
    u16(*lds_b)[72] = (u16(*)[72])(ldsAB + 64 * 72);

    f32x4 acc[2][2] = {};
    const int mq = (wv >> 1) * 32, nq = (wv & 1) * 32;

    for (int k0 = 0; k0 < K; k0 += 64) {
      __syncthreads();
      {
        int m = t >> 2, c0 = (t & 3) * 16;
        const u16* src = Awqt + (size_t)(m0 + m) * K + k0 + c0;
        *(u16x8*)&lds_a[m][c0] = *(const u16x8*)src;
        *(u16x8*)&lds_a[m][c0 + 8] = *(const u16x8*)(src + 8);
      }
      {
        int k = t >> 2, nn0 = (t & 3) * 16;
        const float* src = temp + (size_t)b * K * N + (size_t)(k0 + k) * N + n0 + nn0;
#pragma unroll
        for (int i4 = 0; i4 < 4; ++i4) {
          f32x4 v = *(const f32x4*)(src + i4 * 4);
#pragma unroll
          for (int j = 0; j < 4; ++j) {
            int n = nn0 + i4 * 4 + j;
            lds_b[n][bswz(n, k)] = f2bf(v[j]);
          }
        }
      }
      __syncthreads();
#pragma unroll
      for (int kk = 0; kk < 2; ++kk) {
        Frag af[2], bfr[2];
#pragma unroll
        for (int i = 0; i < 2; ++i) {
          af[i].u = *(const u16x8*)&lds_a[mq + 16 * i + lr][kk * 32 + 8 * lg];
          int n = nq + 16 * i + lr;
          bfr[i].u = *(const u16x8*)&lds_b[n][bswz(n, kk * 32 + 8 * lg)];
        }
#pragma unroll
        for (int mi = 0; mi < 2; ++mi)
#pragma unroll
          for (int ni = 0; ni < 2; ++ni)
            acc[mi][ni] = __builtin_amdgcn_mfma_f32_16x16x32_bf16(
                af[mi].b, bfr[ni].b, acc[mi][ni], 0, 0, 0);
      }
    }
#pragma unroll
    for (int mi = 0; mi < 2; ++mi)
#pragma unroll
      for (int ni = 0; ni < 2; ++ni) {
        int mbase = m0 + mq + 16 * mi + 4 * lg;
        int n = n0 + nq + 16 * ni + lr;
        *(f32x4*)(qsmall + ((size_t)b * 256 + n) * 256 + mbase) = acc[mi][ni];
      }
    return;
  }

  // ---- kv GEMM: w_qkv[512x256] x xt[N][K] -> Kb (m<256), Vt (m>=256) ----
  int bid = blk - 128;
  int s = bid & 7, w = bid >> 3;
  int gid = (w & ~7) | s, mt = w & 7;
  const int nt = gid & 31, b = gid >> 5;
  const int m0 = mt * 64, n0 = nt * 128;

  f32x4 acc[2][4] = {};
  const int mq = (wv >> 1) * 32, nq = (wv & 1) * 64;
  const size_t bOff = (size_t)b * 4096 * 256;
  const int sub = lane >> 3, c = lane & 7;

  for (int k0 = 0; k0 < 256; k0 += 64) {
    __syncthreads();
#pragma unroll
    for (int i = wv; i < 24; i += 4) {
      const u16* g;
      if (i < 8) g = Awqkv + (size_t)(m0 + i * 8 + sub) * 256 + k0 + ((c ^ sub) << 3);
      else g = xt + bOff + (size_t)(n0 + i * 8 + sub - 64) * 256 + k0 + ((c ^ sub) << 3);
      gl16(g, &ldsAB[i * 512]);
    }
    __syncthreads();
#pragma unroll
    for (int kk = 0; kk < 2; ++kk) {
      Frag af[2], bfr[4];
#pragma unroll
      for (int mi = 0; mi < 2; ++mi) {
        int r = mq + 16 * mi + lr;
        af[mi].u = *(const u16x8*)&ldsAB[r * 64 + (((kk * 4 + lg) ^ (r & 7)) << 3)];
      }
#pragma unroll
      for (int ni = 0; ni < 4; ++ni) {
        int rn = nq + 16 * ni + lr;
        bfr[ni].u = *(const u16x8*)&ldsAB[(64 + rn) * 64 + (((kk * 4 + lg) ^ (rn & 7)) << 3)];
      }
#pragma unroll
      for (int mi = 0; mi < 2; ++mi)
#pragma unroll
        for (int ni = 0; ni < 4; ++ni)
          acc[mi][ni] = __builtin_amdgcn_mfma_f32_16x16x32_bf16(
              af[mi].b, bfr[ni].b, acc[mi][ni], 0, 0, 0);
    }
  }

  if (m0 < 256) {
#pragma unroll
    for (int mi = 0; mi < 2; ++mi)
#pragma unroll
      for (int ni = 0; ni < 4; ++ni) {
        int mbase = m0 + mq + 16 * mi + 4 * lg;
        int n = n0 + nq + 16 * ni + lr;
        u16x4 pk;
#pragma unroll
        for (int j = 0; j < 4; ++j) pk[j] = f2bf(acc[mi][ni][j]);
        int head = mbase >> 5, d = mbase & 31;
        *(u16x4*)(Kb + ((size_t)(b * 8 + head) * 4096 + n) * 32 + d) = pk;
      }
  } else {
    float(*lds_t)[68] = (float(*)[68])ldsAB;
#pragma unroll 1
    for (int r = 0; r < 2; ++r) {
      __syncthreads();
      if ((wv & 1) == r) {
#pragma unroll
        for (int mi = 0; mi < 2; ++mi)
#pragma unroll
          for (int ni = 0; ni < 4; ++ni)
#pragma unroll
            for (int j = 0; j < 4; ++j)
              lds_t[mq + 16 * mi + 4 * lg + j][16 * ni + lr] = acc[mi][ni][j];
      }
      __syncthreads();
      int dloc = t >> 2, nc = (t & 3) * 16;
      int dg = (m0 - 256) + dloc;
      int head = dg >> 5, d = dg & 31;
      u16x8 o0, o1;
#pragma unroll
      for (int i = 0; i < 8; ++i) {
        o0[i] = f2bf(lds_t[dloc][nc + i]);
        o1[i] = f2bf(lds_t[dloc][nc + 8 + i]);
      }
      u16* dst = Vt + ((size_t)(b * 8 + head) * 32 + d) * 4096 + n0 + 64 * r + nc;
      *(u16x8*)dst = o0;
      *(u16x8*)(dst + 8) = o1;
    }
  }
}

// ---------------- proj GEMM (DMA-staged 64x128, plane-gathered B) ----------------
__global__ __launch_bounds__(256) void k_gemm2(
    const u16* __restrict__ A, const u16* __restrict__ Bh, float* __restrict__ Cf,
    const float* __restrict__ bias, const float* __restrict__ Xres) {
  const int t = threadIdx.x, lane = t & 63, wv = t >> 6;
  const int lr = lane & 15, lg = lane >> 4;
  int bid = blockIdx.x;
  int s = bid & 7, w = bid >> 3;
  int gid = ((w >> 2) << 3) | s, mt = w & 3;
  const int nt = gid & 31, b = gid >> 5;
  const int m0 = mt * 64, n0 = nt * 128;

  __shared__ __align__(16) u16 ldsAB[192 * 64];

  f32x4 acc[2][4] = {};
  const int mq = (wv >> 1) * 32, nq = (wv & 1) * 64;
  const int sub = lane >> 3, c = lane & 7;

  for (int k0 = 0; k0 < 256; k0 += 64) {
    __syncthreads();
#pragma unroll
    for (int i = wv; i < 24; i += 4) {
      const u16* g;
      if (i < 8) {
        g = A + (size_t)(m0 + i * 8 + sub) * 256 + k0 + ((c ^ sub) << 3);
      } else {
        int rn = n0 + i * 8 + sub - 64;
        int ch = k0 + ((c ^ sub) << 3);
        g = Bh + ((size_t)(b * 8 + (ch >> 5)) * 4096 + rn) * 32 + (ch & 31);
      }
      gl16(g, &ldsAB[i * 512]);
    }
    __syncthreads();
#pragma unroll
    for (int kk = 0; kk < 2; ++kk) {
      Frag af[2], bfr[4];
#pragma unroll
      for (int mi = 0; mi < 2; ++mi) {
        int r = mq + 16 * mi + lr;
        af[mi].u = *(const u16x8*)&ldsAB[r * 64 + (((kk * 4 + lg) ^ (r & 7)) << 3)];
      }
#pragma unroll
      for (int ni = 0; ni < 4; ++ni) {
        int rn = nq + 16 * ni + lr;
        bfr[ni].u = *(const u16x8*)&ldsAB[(64 + rn) * 64 + (((kk * 4 + lg) ^ (rn & 7)) << 3)];
      }
#pragma unroll
      for (int mi = 0; mi < 2; ++mi)
#pragma unroll
        for (int ni = 0; ni < 4; ++ni)
          acc[mi][ni] = __builtin_amdgcn_mfma_f32_16x16x32_bf16(
              af[mi].b, bfr[ni].b, acc[mi][ni], 0, 0, 0);
    }
  }

#pragma unroll
  for (int mi = 0; mi < 2; ++mi)
#pragma unroll
    for (int ni = 0; ni < 4; ++ni) {
      int mbase = m0 + mq + 16 * mi + 4 * lg;
      int n = n0 + nq + 16 * ni + lr;
#pragma unroll
      for (int j = 0; j < 4; ++j) {
        int m = mbase + j;
        size_t off = ((size_t)b * 256 + m) * 4096 + n;
        Cf[off] = acc[mi][ni][j] + bias[m] + Xres[off];
      }
    }
}

// ---------------- bilinear resize ----------------
DEVFN void blc(int y, int& i0, int& i1, float& w) {
  float fy = 0.25f * y - 0.375f;
  float ff = floorf(fy);
  w = fy - ff;
  int i = (int)ff;
  i0 = i < 0 ? 0 : i;
  i1 = (i + 1 > 15) ? 15 : i + 1;
}

__global__ __launch_bounds__(256) void k_resize(
    const float* __restrict__ qsmall, const float* __restrict__ qbias,
    u16* __restrict__ Qb) {
  int gid = blockIdx.x * 256 + threadIdx.x;
  int c8 = gid & 31;
  int p = (gid >> 5) & 4095;
  int b = gid >> 17;
  int y = p >> 6, x = p & 63;
  int y0, y1, x0, x1;
  float wy, wx;
  blc(y, y0, y1, wy);
  blc(x, x0, x1, wx);
  const float* base = qsmall + (size_t)b * 65536;
  int o0 = c8 * 8;
  const float* r00 = base + (y0 * 16 + x0) * 256 + o0;
  const float* r01 = base + (y0 * 16 + x1) * 256 + o0;
  const float* r10 = base + (y1 * 16 + x0) * 256 + o0;
  const float* r11 = base + (y1 * 16 + x1) * 256 + o0;
  float w00 = (1 - wy) * (1 - wx), w01 = (1 - wy) * wx;
  float w10 = wy * (1 - wx), w11 = wy * wx;
  u16x8 outv;
#pragma unroll
  for (int i = 0; i < 8; ++i) {
    float v = w00 * r00[i] + w01 * r01[i] + w10 * r10[i] + w11 * r11[i] + qbias[o0 + i];
    outv[i] = f2bf(v * QSC);
  }
  int head = o0 >> 5, d = o0 & 31;
  *(u16x8*)(Qb + ((size_t)(b * 8 + head) * 4096 + p) * 32 + d) = outv;
}

// ---------------- MFMA attention body (NF frags per wave) ----------------
template <int NF>
DEVFN void attn_body(const u16* __restrict__ Qb, const u16* __restrict__ Kb,
                     const u16* __restrict__ Vt, u16* __restrict__ Ob,
                     int b, int head, int lws, int i0, int by, int bx,
                     int j_begin, int j_end, int split,
                     int lane, int wv, float* smo, float* sml) {
  const int lr = lane & 15, lg = lane >> 4;
  const int addrA = (32 * (lg & 1) + lr) * 4;
  const int addrB = addrA + 64;
  const bool lo_half = (lg < 2);
  const int wsm = (1 << lws) - 1;
  const size_t hb = (size_t)(b * 8 + head) * 131072;
  auto mapP = [&](int i) { return ((by + (i >> lws)) << 6) + bx + (i & wsm); };

  Frag qf[NF];
#pragma unroll
  for (int f = 0; f < NF; ++f)
    qf[f].u = *(const u16x8*)(Qb + hb + (size_t)mapP(i0 + 16 * f + lr) * 32 + 8 * lg);

  f32x4 oT[NF][2] = {};
  float lsum[NF] = {};

  auto chunk = [&](const Frag& k0, const Frag& k1, const Frag& v0, const Frag& v1) {
#pragma unroll
    for (int f = 0; f < NF; ++f) {
      f32x4 zz = {};
      f32x4 s0 = __builtin_amdgcn_mfma_f32_16x16x32_bf16(k0.b, qf[f].b, zz, 0, 0, 0);
      f32x4 s1 = __builtin_amdgcn_mfma_f32_16x16x32_bf16(k1.b, qf[f].b, zz, 0, 0, 0);
      float p[8];
#pragma unroll
      for (int j = 0; j < 4; ++j) {
        p[j] = fexp2(s0[j]);
        p[4 + j] = fexp2(s1[j]);
      }
#pragma unroll
      for (int j = 0; j < 8; ++j) lsum[f] += p[j];
      unsigned pk0, pk1, pk2, pk3;
      asm("v_cvt_pk_bf16_f32 %0, %1, %2" : "=v"(pk0) : "v"(p[0]), "v"(p[1]));
      asm("v_cvt_pk_bf16_f32 %0, %1, %2" : "=v"(pk1) : "v"(p[2]), "v"(p[3]));
      asm("v_cvt_pk_bf16_f32 %0, %1, %2" : "=v"(pk2) : "v"(p[4]), "v"(p[5]));
      asm("v_cvt_pk_bf16_f32 %0, %1, %2" : "=v"(pk3) : "v"(p[6]), "v"(p[7]));
      int a0 = __builtin_amdgcn_ds_bpermute(addrA, (int)pk0);
      int a1 = __builtin_amdgcn_ds_bpermute(addrA, (int)pk1);
      int a2 = __builtin_amdgcn_ds_bpermute(addrB, (int)pk0);
      int a3 = __builtin_amdgcn_ds_bpermute(addrB, (int)pk1);
      int b0 = __builtin_amdgcn_ds_bpermute(addrA, (int)pk2);
      int b1 = __builtin_amdgcn_ds_bpermute(addrA, (int)pk3);
      int b2 = __builtin_amdgcn_ds_bpermute(addrB, (int)pk2);
      int b3 = __builtin_amdgcn_ds_bpermute(addrB, (int)pk3);
      union { unsigned w[4]; Frag fr; } pb;
      pb.w[0] = (unsigned)(lo_half ? a0 : b0);
      pb.w[1] = (unsigned)(lo_half ? a1 : b1);
      pb.w[2] = (unsigned)(lo_half ? a2 : b2);
      pb.w[3] = (unsigned)(lo_half ? a3 : b3);
      oT[f][0] = __builtin_amdgcn_mfma_f32_16x16x32_bf16(v0.b, pb.fr.b, oT[f][0], 0, 0, 0);
      oT[f][1] = __builtin_amdgcn_mfma_f32_16x16x32_bf16(v1.b, pb.fr.b, oT[f][1], 0, 0, 0);
    }
  };

  Frag k0A, k1A, v0A, v1A, k0B, k1B, v0B, v1B;
  auto loadKV = [&](int j0, Frag& a, Frag& c, Frag& d, Frag& e) {
    a.u = *(const u16x8*)(Kb + hb + (size_t)mapP(j0 + lr) * 32 + 8 * lg);
    c.u = *(const u16x8*)(Kb + hb + (size_t)mapP(j0 + 16 + lr) * 32 + 8 * lg);
    int pv = mapP(j0 + 8 * lg);
    d.u = *(const u16x8*)(Vt + hb + (size_t)lr * 4096 + pv);
    e.u = *(const u16x8*)(Vt + hb + (size_t)(16 + lr) * 4096 + pv);
  };

  loadKV(j_begin, k0A, k1A, v0A, v1A);
  for (int j0 = j_begin; j0 < j_end; j0 += 64) {
    loadKV(j0 + 32, k0B, k1B, v0B, v1B);
    chunk(k0A, k1A, v0A, v1A);
    if (j0 + 64 < j_end) loadKV(j0 + 64, k0A, k1A, v0A, v1A);
    chunk(k0B, k1B, v0B, v1B);
  }

  if (!split) {
#pragma unroll
    for (int f = 0; f < NF; ++f) {
      float s = lsum[f];
      s += __shfl_xor(s, 16, 64);
      s += __shfl_xor(s, 32, 64);
      float inv = 1.f / s;
      int q = i0 + 16 * f + lr;
      u16x4 lo, hi;
#pragma unroll
      for (int j = 0; j < 4; ++j) {
        lo[j] = f2bf(oT[f][0][j] * inv);
        hi[j] = f2bf(oT[f][1][j] * inv);
      }
      if (head < 5) {
        int p = mapP(q);
        u16* dst = Ob + ((size_t)(b * 8 + head) * 4096 + p) * 32;
        *(u16x4*)(dst + 4 * lg) = lo;
        *(u16x4*)(dst + 16 + 4 * lg) = hi;
      } else {
        int n = head - 5;
        int g32 = ((n * 64 + by) << 6) + q;
        int m3 = g32 % 3, sp = g32 / 3;
        u16* dst = Ob + ((size_t)(b * 8 + 5 + m3) * 4096 + sp) * 32;
        *(u16x4*)(dst + 4 * lg) = lo;
        *(u16x4*)(dst + 16 + 4 * lg) = hi;
      }
    }
    return;
  }

  if constexpr (NF == 2) {
#pragma unroll
    for (int f = 0; f < 2; ++f) {
      float s = lsum[f];
      s += __shfl_xor(s, 16, 64);
      s += __shfl_xor(s, 32, 64);
      if (lg == 0) sml[(wv * 2 + f) * 16 + lr] = s;
#pragma unroll
      for (int h = 0; h < 2; ++h)
#pragma unroll
        for (int j = 0; j < 4; ++j)
          smo[(((wv * 2 + f) * 2 + h) * 4 + j) * 64 + lane] = oT[f][h][j];
    }
    __syncthreads();
    int f = wv & 1, h = wv >> 1;
    float ot[4] = {0.f, 0.f, 0.f, 0.f};
    float ls = 0.f;
#pragma unroll
    for (int w = 0; w < 4; ++w) {
      ls += sml[(w * 2 + f) * 16 + lr];
#pragma unroll
      for (int j = 0; j < 4; ++j)
        ot[j] += smo[(((w * 2 + f) * 2 + h) * 4 + j) * 64 + lane];
    }
    float inv = 1.f / ls;
    int q = i0 + 16 * f + lr;
    int p = mapP(q);
    u16x4 v4;
#pragma unroll
    for (int j = 0; j < 4; ++j) v4[j] = f2bf(ot[j] * inv);
    u16* dst = Ob + ((size_t)(b * 8 + head) * 4096 + p) * 32 + h * 16;
    *(u16x4*)(dst + 4 * lg) = v4;
  } else {
    float ot0[4], ot1[4];
    float ls = 0.f;
#pragma unroll 1
    for (int h = 0; h < 2; ++h) {
      __syncthreads();
#pragma unroll
      for (int f = 0; f < 4; ++f) {
#pragma unroll
        for (int j = 0; j < 4; ++j) smo[((wv * 4 + f) * 4 + j) * 64 + lane] = oT[f][h][j];
        if (h == 0) {
          float s = lsum[f];
          s += __shfl_xor(s, 16, 64);
          s += __shfl_xor(s, 32, 64);
          if (lg == 0) sml[(wv * 4 + f) * 16 + lr] = s;
        }
      }
      __syncthreads();
      int f = wv;
      float* ot = (h == 0) ? ot0 : ot1;
#pragma unroll
      for (int j = 0; j < 4; ++j) ot[j] = 0.f;
#pragma unroll
      for (int w = 0; w < 4; ++w) {
        if (h == 0) ls += sml[(w * 4 + f) * 16 + lr];
#pragma unroll
        for (int j = 0; j < 4; ++j) ot[j] += smo[((w * 4 + f) * 4 + j) * 64 + lane];
      }
    }
    float inv = 1.f / ls;
    int f = wv;
    int q = i0 + 16 * f + lr;
    int p = mapP(q);
    u16x4 lo, hi;
#pragma unroll
    for (int j = 0; j < 4; ++j) {
      lo[j] = f2bf(ot0[j] * inv);
      hi[j] = f2bf(ot1[j] * inv);
    }
    u16* dst = Ob + ((size_t)(b * 8 + head) * 4096 + p) * 32;
    *(u16x4*)(dst + 4 * lg) = lo;
    *(u16x4*)(dst + 16 + 4 * lg) = hi;
  }
}

// ---------------- MFMA attention dispatcher (single 2304-block dispatch) ----------------
__global__ __launch_bounds__(256) void k_attn(
    const u16* __restrict__ Qb, const u16* __restrict__ Kb,
    const u16* __restrict__ Vt, u16* __restrict__ Ob) {
  const int t = threadIdx.x, lane = t & 63, wv = t >> 6;
  const int lr = lane & 15, lg = lane >> 4;

  __shared__ float smo[4096];
  __shared__ float sml[256];

  int vbid = blockIdx.x;
  if (vbid < 1024) {  // head4: 32-query split blocks, XCD-grouped
    int L = (vbid & 7) * 128 + (vbid >> 3);
    int b = L >> 7, g = L & 127;
    int w = g >> 5;
    attn_body<2>(Qb, Kb, Vt, Ob, b, 4, 5, (g & 31) * 32, (w >> 1) * 32, (w & 1) * 32,
                 wv * 256, wv * 256 + 256, 1, lane, wv, smo, sml);
    return;
  }
  if (vbid < 1536) {  // head3: 64q blocks, split-K 64 keys/wave
    int r = vbid - 1024;
    int b = r >> 6, g = r & 63;
    int w = g >> 2;
    attn_body<4>(Qb, Kb, Vt, Ob, b, 3, 4, (g & 3) * 64, (w >> 2) * 16, (w & 3) * 16,
                 wv * 64, wv * 64 + 64, 1, lane, wv, smo, sml);
    return;
  }
  int u = (vbid - 1536) * 4 + wv;
  const int addrA = (32 * (lg & 1) + lr) * 4;
  const int addrB = addrA + 64;
  const bool lo_half = (lg < 2);
  auto pnet16 = [&](unsigned pk0, unsigned pk1, Frag& out) {
    union { unsigned w[4]; Frag fr; } pb;
    int a0 = __builtin_amdgcn_ds_bpermute(addrA, (int)pk0);
    int a1 = __builtin_amdgcn_ds_bpermute(addrA, (int)pk1);
    int a2 = __builtin_amdgcn_ds_bpermute(addrB, (int)pk0);
    int a3 = __builtin_amdgcn_ds_bpermute(addrB, (int)pk1);
    pb.w[0] = lo_half ? (unsigned)a0 : 0u;
    pb.w[1] = lo_half ? (unsigned)a1 : 0u;
    pb.w[2] = lo_half ? (unsigned)a2 : 0u;
    pb.w[3] = lo_half ? (unsigned)a3 : 0u;
    out = pb.fr;
  };

  if (u >= 2560) {  // ws=2 (head 0)
    int r = u - 2560;
    int b2 = r >> 6;
    int qw = r & 63;
    const size_t hb0 = (size_t)(b2 * 8 + 0) * 131072;
    const u16* vb0 = Vt + hb0 + (size_t)lr * 4096;
    const u16* vb1 = Vt + hb0 + (size_t)(16 + lr) * 4096;
    const bool valid = (lg == (lr >> 2));
    const int lgm = lg & 1;
#pragma unroll
    for (int f = 0; f < 4; ++f) {
      int g = qw * 4 + f;
      int W = g * 4 + (lr >> 2);
      int wbase = (W >> 5) * 128 + (W & 31) * 2;
      int qj = lr & 3;
      int posq = wbase + ((qj >> 1) << 6) + (qj & 1);
      Frag qf2, kf2;
      qf2.u = *(const u16x8*)(Qb + hb0 + (size_t)posq * 32 + 8 * lg);
      kf2.u = *(const u16x8*)(Kb + hb0 + (size_t)posq * 32 + 8 * lg);
      int W0 = g * 4 + 2 * lgm;
      int base0 = (W0 >> 5) * 128 + (W0 & 31) * 2;
      int W1 = W0 + 1;
      int base1 = (W1 >> 5) * 128 + (W1 & 31) * 2;
      Frag22 v0u, v1u;
      v0u.q[0] = *(const u16x2*)(vb0 + base0);
      v0u.q[1] = *(const u16x2*)(vb0 + base0 + 64);
      v0u.q[2] = *(const u16x2*)(vb0 + base1);
      v0u.q[3] = *(const u16x2*)(vb0 + base1 + 64);
      v1u.q[0] = *(const u16x2*)(vb1 + base0);
      v1u.q[1] = *(const u16x2*)(vb1 + base0 + 64);
      v1u.q[2] = *(const u16x2*)(vb1 + base1);
      v1u.q[3] = *(const u16x2*)(vb1 + base1 + 64);
      f32x4 zz = {};
      f32x4 s0 = __builtin_amdgcn_mfma_f32_16x16x32_bf16(kf2.b, qf2.b, zz, 0, 0, 0);
      float p[4];
      float ls = 0.f;
#pragma unroll
      for (int j = 0; j < 4; ++j) {
        p[j] = valid ? fexp2(s0[j]) : 0.f;
        ls += p[j];
      }
      unsigned pk0, pk1;
      asm("v_cvt_pk_bf16_f32 %0, %1, %2" : "=v"(pk0) : "v"(p[0]), "v"(p[1]));
      asm("v_cvt_pk_bf16_f32 %0, %1, %2" : "=v"(pk1) : "v"(p[2]), "v"(p[3]));
      Frag pfr;
      pnet16(pk0, pk1, pfr);
      f32x4 o0 = {}, o1 = {};
      o0 = __builtin_amdgcn_mfma_f32_16x16x32_bf16(v0u.b, pfr.b, o0, 0, 0, 0);
      o1 = __builtin_amdgcn_mfma_f32_16x16x32_bf16(v1u.b, pfr.b, o1, 0, 0, 0);
      ls += __shfl_xor(ls, 16, 64);
      ls += __shfl_xor(ls, 32, 64);
      float inv = 1.f / ls;
      u16x4 lo4, hi4;
#pragma unroll
      for (int j = 0; j < 4; ++j) {
        lo4[j] = f2bf(o0[j] * inv);
        hi4[j] = f2bf(o1[j] * inv);
      }
      u16* dst = Ob + ((size_t)(b2 * 8 + 0) * 4096 + posq) * 32;
      *(u16x4*)(dst + 4 * lg) = lo4;
      *(u16x4*)(dst + 16 + 4 * lg) = hi4;
    }
    return;
  }
  if (u >= 2048) {  // ws=4 (head 1)
    int r = u - 2048;
    int b4 = r >> 6;
    int qw = r & 63;
    const size_t hb1 = (size_t)(b4 * 8 + 1) * 131072;
    const u16* vb0 = Vt + hb1 + (size_t)lr * 4096;
    const u16* vb1 = Vt + hb1 + (size_t)(16 + lr) * 4096;
#pragma unroll
    for (int f = 0; f < 4; ++f) {
      int w = qw * 4 + f;
      int pbase = ((w >> 4) << 8) + ((w & 15) << 2);
      int posq = pbase + ((lr >> 2) << 6) + (lr & 3);
      Frag qf4, kf4;
      qf4.u = *(const u16x8*)(Qb + hb1 + (size_t)posq * 32 + 8 * lg);
      kf4.u = *(const u16x8*)(Kb + hb1 + (size_t)posq * 32 + 8 * lg);
      int a1 = pbase + 2 * (lg & 1) * 64;
      Frag44 v0u, v1u;
      v0u.h[0] = *(const u16x4*)(vb0 + a1);
      v0u.h[1] = *(const u16x4*)(vb0 + a1 + 64);
      v1u.h[0] = *(const u16x4*)(vb1 + a1);
      v1u.h[1] = *(const u16x4*)(vb1 + a1 + 64);
      f32x4 zz = {};
      f32x4 s0 = __builtin_amdgcn_mfma_f32_16x16x32_bf16(kf4.b, qf4.b, zz, 0, 0, 0);
      float p[4];
      float ls = 0.f;
#pragma unroll
      for (int j = 0; j < 4; ++j) {
        p[j] = fexp2(s0[j]);
        ls += p[j];
      }
      unsigned pk0, pk1;
      asm("v_cvt_pk_bf16_f32 %0, %1, %2" : "=v"(pk0) : "v"(p[0]), "v"(p[1]));
      asm("v_cvt_pk_bf16_f32 %0, %1, %2" : "=v"(pk1) : "v"(p[2]), "v"(p[3]));
      Frag pfr;
      pnet16(pk0, pk1, pfr);
      f32x4 o0 = {}, o1 = {};
      o0 = __builtin_amdgcn_mfma_f32_16x16x32_bf16(v0u.b, pfr.b, o0, 0, 0, 0);
      o1 = __builtin_amdgcn_mfma_f32_16x16x32_bf16(v1u.b, pfr.b, o1, 0, 0, 0);
      ls += __shfl_xor(ls, 16, 64);
      ls += __shfl_xor(ls, 32, 64);
      float inv = 1.f / ls;
      u16x4 lo4, hi4;
#pragma unroll
      for (int j = 0; j < 4; ++j) {
        lo4[j] = f2bf(o0[j] * inv);
        hi4[j] = f2bf(o1[j] * inv);
      }
      u16* dst = Ob + ((size_t)(b4 * 8 + 1) * 4096 + posq) * 32;
      *(u16x4*)(dst + 4 * lg) = lo4;
      *(u16x4*)(dst + 16 + 4 * lg) = hi4;
    }
    return;
  }
  if (u < 512) {  // head2
    int b = u >> 6;
    int w = u & 63;
    attn_body<4>(Qb, Kb, Vt, Ob, b, 2, 3, 0, (w >> 3) * 8, (w & 7) * 8,
                 0, 64, 0, lane, wv, smo, sml);
  } else {  // row-heads 5..7
    int r = u - 512;
    int b = r / 192;
    int rr = r % 192;
    attn_body<4>(Qb, Kb, Vt, Ob, b, 5 + (rr >> 6), 6, 0, rr & 63, 0,
                 0, 64, 0, lane, wv, smo, sml);
  }
}

extern "C" void kernel_launch(void* const* d_in, const int* in_sizes, int n_in,
                              void* d_out, int out_size, void* d_ws, size_t ws_size,
                              hipStream_t stream) {
  const float* x = (const float*)d_in[0];
  const float* temp = (const float*)d_in[1];
  const float* w_qkv = (const float*)d_in[2];
  const float* w_v = (const float*)d_in[3];
  const float* w_proj = (const float*)d_in[4];
  const float* b_proj = (const float*)d_in[5];
  const float* w_temp = (const float*)d_in[6];
  const float* b_temp = (const float*)d_in[7];
  (void)in_sizes; (void)n_in; (void)out_size; (void)ws_size;

  char* ws = (char*)d_ws;
  u16* w_qt = (u16*)(ws + 0);
  u16* w_qkv_bf = (u16*)(ws + 262144);
  u16* w_proj_bf = (u16*)(ws + 524288);
  float* qbias = (float*)(ws + 655360);
  float* qsmall = (float*)(ws + 656384);
  u16* q_buf = (u16*)(ws + 2753536);
  u16* k_buf = (u16*)(ws + 19530752);
  u16* v_t = (u16*)(ws + 53085184);
  u16* o_buf = (u16*)(ws + 69862400);  // [b][h][p][32] planes (aliased: x_t before attn)
  u16* x_t = o_buf;
  float* out = (float*)d_out;

  k_stage0<<<3072, 256, 0, stream>>>(x, w_qkv, w_v, w_proj, w_temp, b_temp,
                                     w_qt, qbias, w_qkv_bf, w_proj_bf, x_t);
  k_stage1<<<2176, 256, 0, stream>>>(w_qt, temp, qsmall, w_qkv_bf, x_t, k_buf, v_t);
  k_resize<<<4096, 256, 0, stream>>>(qsmall, qbias, q_buf);
  k_attn<<<2304, 256, 0, stream>>>(q_buf, k_buf, v_t, o_buf);
  k_gemm2<<<1024, 256, 0, stream>>>(w_proj_bf, o_buf, out, b_proj, x);
}

// Round 12
// 92.678 us; speedup vs baseline: 1.3427x; 1.0328x over previous
//
#include <hip/hip_runtime.h>

typedef unsigned short u16;
typedef float f32x4 __attribute__((ext_vector_type(4)));
typedef unsigned short u16x8 __attribute__((ext_vector_type(8)));
typedef unsigned short u16x4 __attribute__((ext_vector_type(4)));
typedef unsigned short u16x2 __attribute__((ext_vector_type(2)));
typedef __bf16 bf16x8 __attribute__((ext_vector_type(8)));

union Frag { u16x8 u; bf16x8 b; };
union Frag44 { u16x4 h[2]; u16x8 u; bf16x8 b; };
union Frag22 { u16x2 q[4]; u16x8 u; bf16x8 b; };

#define DEVFN static __device__ __forceinline__

DEVFN u16 f2bf(float f) {
  unsigned u = __builtin_bit_cast(unsigned, f);
  u += 0x7FFFu + ((u >> 16) & 1u);
  return (u16)(u >> 16);
}
DEVFN float bf2f(u16 h) {
  return __builtin_bit_cast(float, ((unsigned)h) << 16);
}
DEVFN int bswz(int n, int k) { return k ^ ((((n >> 4) ^ n) & 7) << 3); }

DEVFN float fexp2(float x) {
#if __has_builtin(__builtin_amdgcn_exp2f)
  return __builtin_amdgcn_exp2f(x);
#else
  float r;
  asm volatile("v_exp_f32 %0, %1\n\ts_nop 1" : "=v"(r) : "v"(x));
  return r;
#endif
}

DEVFN void gl16(const u16* g, u16* l) {
  __builtin_amdgcn_global_load_lds(
      (const __attribute__((address_space(1))) unsigned int*)g,
      (__attribute__((address_space(3))) unsigned int*)l, 16, 0, 0);
}

// Fragment-native V layout: Vt2[b*8+h][ptile=p>>5][oct=(p>>3)&3][d:32][8 keys]
// (2 KB tile per 32 pixels; a V-frag load = 4x256B contiguous runs, 100% line use)
DEVFN size_t vt2idx(size_t hb, int d, int p) {
  return hb + (size_t)(p >> 5) * 1024 + (size_t)((((p >> 3) & 3) * 32 + d) * 8 + (p & 7));
}

#define QSC (0.17677669529663687f * 1.44269504088896341f)

// ---------------- stage0: prep (blocks 0..1023)  ||  x-transpose (1024..3071) ----------------
__global__ __launch_bounds__(256) void k_stage0(
    const float* __restrict__ x, const float* __restrict__ w_qkv,
    const float* __restrict__ w_v, const float* __restrict__ w_proj,
    const float* __restrict__ w_temp, const float* __restrict__ b_temp,
    u16* __restrict__ w_qt, float* __restrict__ qbias,
    u16* __restrict__ w_qkv_bf, u16* __restrict__ w_proj_bf,
    u16* __restrict__ xt) {
  __shared__ float smem[64 * 65];
  int t = threadIdx.x, blk = blockIdx.x;
  if (blk < 1024) {  // ---- prep ----
    float* wvr = smem;
    float* red = smem + 256;
    if (blk < 256) {
      wvr[t] = w_v[blk * 256 + t];
      __syncthreads();
      for (int c = t; c < 512; c += 256) {
        float acc = 0.f;
        for (int m = 0; m < 256; ++m) acc += wvr[m] * w_temp[m * 512 + c];
        w_qt[blk * 512 + c] = f2bf(acc);
      }
      red[t] = wvr[t] * b_temp[t];
      __syncthreads();
      for (int s = 128; s > 0; s >>= 1) {
        if (t < s) red[t] += red[t + s];
        __syncthreads();
      }
      if (t == 0) qbias[blk] = red[0];
    } else {
      int e = (blk - 256) * 256 + t;
      if (e < 512 * 256) w_qkv_bf[e] = f2bf(w_qkv[e]);
      else {
        int e2 = e - 512 * 256;
        w_proj_bf[e2] = f2bf(w_proj[e2]);
      }
    }
    return;
  }
  // ---- x transpose+cvt: [b][c=256][p=4096] f32 -> [b][p][c] bf16 ----
  float(*lds)[65] = (float(*)[65])smem;
  int bid = blk - 1024;
  int b = bid >> 8, rem = bid & 255;
  int c0 = (rem >> 6) << 6;
  int p0 = (rem & 63) << 6;
  int cr = t >> 2, pc = (t & 3) * 16;
  const float* src = x + (size_t)(b * 256 + c0 + cr) * 4096 + p0 + pc;
#pragma unroll
  for (int i = 0; i < 4; ++i) {
    f32x4 v = *(const f32x4*)(src + 4 * i);
#pragma unroll
    for (int j = 0; j < 4; ++j) lds[cr][pc + 4 * i + j] = v[j];
  }
  __syncthreads();
  int pr = t >> 2, cq = (t & 3) * 16;
  u16x8 o0, o1;
#pragma unroll
  for (int j = 0; j < 8; ++j) {
    o0[j] = f2bf(lds[cq + j][pr]);
    o1[j] = f2bf(lds[cq + 8 + j][pr]);
  }
  u16* dst = xt + ((size_t)(b * 4096) + p0 + pr) * 256 + c0 + cq;
  *(u16x8*)dst = o0;
  *(u16x8*)(dst + 8) = o1;
}

// ---------------- stage1: gemm0 (blocks 0..127)  ||  DMA-staged kv GEMM (128..2175) ----------------
__global__ __launch_bounds__(256) void k_stage1(
    const u16* __restrict__ Awqt, const float* __restrict__ temp,
    float* __restrict__ qsmall,
    const u16* __restrict__ Awqkv, const u16* __restrict__ xt,
    u16* __restrict__ Kb, u16* __restrict__ Vt) {
  const int t = threadIdx.x, lane = t & 63, wv = t >> 6;
  const int lr = lane & 15, lg = lane >> 4;
  __shared__ __align__(16) u16 ldsAB[192 * 64];
  const int blk = blockIdx.x;

  if (blk < 128) {  // ---- qsmall GEMM (64x64, reg staging, f32 B) ----
    constexpr int N = 256, K = 512;
    const int n0 = (blk & 3) * 64;
    const int m0 = ((blk >> 2) & 3) * 64;
    const int b = blk >> 4;
    u16(*lds_a)[72] = (u16(*)[72])ldsAB;
    u16(*lds_b)[72] = (u16(*)[72])(ldsAB + 64 * 72);

    f32x4 acc[2][2] = {};
    const int mq = (wv >> 1) * 32, nq = (wv & 1) * 32;

    for (int k0 = 0; k0 < K; k0 += 64) {
      __syncthreads();
      {
        int m = t >> 2, c0 = (t & 3) * 16;
        const u16* src = Awqt + (size_t)(m0 + m) * K + k0 + c0;
        *(u16x8*)&lds_a[m][c0] = *(const u16x8*)src;
        *(u16x8*)&lds_a[m][c0 + 8] = *(const u16x8*)(src + 8);
      }
      {
        int k = t >> 2, nn0 = (t & 3) * 16;
        const float* src = temp + (size_t)b * K * N + (size_t)(k0 + k) * N + n0 + nn0;
#pragma unroll
        for (int i4 = 0; i4 < 4; ++i4) {
          f32x4 v = *(const f32x4*)(src + i4 * 4);
#pragma unroll
          for (int j = 0; j < 4; ++j) {
            int n = nn0 + i4 * 4 + j;
            lds_b[n][bswz(n, k)] = f2bf(v[j]);
          }
        }
      }
      __syncthreads();
#pragma unroll
      for (int kk = 0; kk < 2; ++kk) {
        Frag af[2], bfr[2];
#pragma unroll
        for (int i = 0; i < 2; ++i) {
          af[i].u = *(const u16x8*)&lds_a[mq + 16 * i + lr][kk * 32 + 8 * lg];
          int n = nq + 16 * i + lr;
          bfr[i].u = *(const u16x8*)&lds_b[n][bswz(n, kk * 32 + 8 * lg)];
        }
#pragma unroll
        for (int mi = 0; mi < 2; ++mi)
#pragma unroll
          for (int ni = 0; ni < 2; ++ni)
            acc[mi][ni] = __builtin_amdgcn_mfma_f32_16x16x32_bf16(
                af[mi].b, bfr[ni].b, acc[mi][ni], 0, 0, 0);
      }
    }
#pragma unroll
    for (int mi = 0; mi < 2; ++mi)
#pragma unroll
      for (int ni = 0; ni < 2; ++ni) {
        int mbase = m0 + mq + 16 * mi + 4 * lg;
        int n = n0 + nq + 16 * ni + lr;
        *(f32x4*)(qsmall + ((size_t)b * 256 + n) * 256 + mbase) = acc[mi][ni];
      }
    return;
  }

  // ---- kv GEMM: w_qkv[512x256] x xt[N][K] -> Kb (m<256), Vt2 (m>=256) ----
  int bid = blk - 128;
  int s = bid & 7, w = bid >> 3;
  int gid = (w & ~7) | s, mt = w & 7;
  const int nt = gid & 31, b = gid >> 5;
  const int m0 = mt * 64, n0 = nt * 128;

  f32x4 acc[2][4] = {};
  const int mq = (wv >> 1) * 32, nq = (wv & 1) * 64;
  const size_t bOff = (size_t)b * 4096 * 256;
  const int sub = lane >> 3, c = lane & 7;

  for (int k0 = 0; k0 < 256; k0 += 64) {
    __syncthreads();
#pragma unroll
    for (int i = wv; i < 24; i += 4) {
      const u16* g;
      if (i < 8) g = Awqkv + (size_t)(m0 + i * 8 + sub) * 256 + k0 + ((c ^ sub) << 3);
      else g = xt + bOff + (size_t)(n0 + i * 8 + sub - 64) * 256 + k0 + ((c ^ sub) << 3);
      gl16(g, &ldsAB[i * 512]);
    }
    __syncthreads();
#pragma unroll
    for (int kk = 0; kk < 2; ++kk) {
      Frag af[2], bfr[4];
#pragma unroll
      for (int mi = 0; mi < 2; ++mi) {
        int r = mq + 16 * mi + lr;
        af[mi].u = *(const u16x8*)&ldsAB[r * 64 + (((kk * 4 + lg) ^ (r & 7)) << 3)];
      }
#pragma unroll
      for (int ni = 0; ni < 4; ++ni) {
        int rn = nq + 16 * ni + lr;
        bfr[ni].u = *(const u16x8*)&ldsAB[(64 + rn) * 64 + (((kk * 4 + lg) ^ (rn & 7)) << 3)];
      }
#pragma unroll
      for (int mi = 0; mi < 2; ++mi)
#pragma unroll
        for (int ni = 0; ni < 4; ++ni)
          acc[mi][ni] = __builtin_amdgcn_mfma_f32_16x16x32_bf16(
              af[mi].b, bfr[ni].b, acc[mi][ni], 0, 0, 0);
    }
  }

  if (m0 < 256) {
#pragma unroll
    for (int mi = 0; mi < 2; ++mi)
#pragma unroll
      for (int ni = 0; ni < 4; ++ni) {
        int mbase = m0 + mq + 16 * mi + 4 * lg;
        int n = n0 + nq + 16 * ni + lr;
        u16x4 pk;
#pragma unroll
        for (int j = 0; j < 4; ++j) pk[j] = f2bf(acc[mi][ni][j]);
        int head = mbase >> 5, d = mbase & 31;
        *(u16x4*)(Kb + ((size_t)(b * 8 + head) * 4096 + n) * 32 + d) = pk;
      }
  } else {
    float(*lds_t)[68] = (float(*)[68])ldsAB;
#pragma unroll 1
    for (int r = 0; r < 2; ++r) {
      __syncthreads();
      if ((wv & 1) == r) {
#pragma unroll
        for (int mi = 0; mi < 2; ++mi)
#pragma unroll
          for (int ni = 0; ni < 4; ++ni)
#pragma unroll
            for (int j = 0; j < 4; ++j)
              lds_t[mq + 16 * mi + 4 * lg + j][16 * ni + lr] = acc[mi][ni][j];
      }
      __syncthreads();
      int dloc = t >> 2, nc = (t & 3) * 16;
      int dg = (m0 - 256) + dloc;
      int head = dg >> 5, d = dg & 31;
      u16x8 o0, o1;
#pragma unroll
      for (int i = 0; i < 8; ++i) {
        o0[i] = f2bf(lds_t[dloc][nc + i]);
        o1[i] = f2bf(lds_t[dloc][nc + 8 + i]);
      }
      size_t hb2 = (size_t)(b * 8 + head) * 131072;
      int p8 = n0 + 64 * r + nc;  // 8-aligned
      *(u16x8*)(Vt + vt2idx(hb2, d, p8)) = o0;
      *(u16x8*)(Vt + vt2idx(hb2, d, p8 + 8)) = o1;
    }
  }
}

// ---------------- proj GEMM (DMA-staged 64x128, plane-gathered B) ----------------
__global__ __launch_bounds__(256) void k_gemm2(
    const u16* __restrict__ A, const u16* __restrict__ Bh, float* __restrict__ Cf,
    const float* __restrict__ bias, const float* __restrict__ Xres) {
  const int t = threadIdx.x, lane = t & 63, wv = t >> 6;
  const int lr = lane & 15, lg = lane >> 4;
  int bid = blockIdx.x;
  int s = bid & 7, w = bid >> 3;
  int gid = ((w >> 2) << 3) | s, mt = w & 3;
  const int nt = gid & 31, b = gid >> 5;
  const int m0 = mt * 64, n0 = nt * 128;

  __shared__ __align__(16) u16 ldsAB[192 * 64];

  f32x4 acc[2][4] = {};
  const int mq = (wv >> 1) * 32, nq = (wv & 1) * 64;
  const int sub = lane >> 3, c = lane & 7;

  for (int k0 = 0; k0 < 256; k0 += 64) {
    __syncthreads();
#pragma unroll
    for (int i = wv; i < 24; i += 4) {
      const u16* g;
      if (i < 8) {
        g = A + (size_t)(m0 + i * 8 + sub) * 256 + k0 + ((c ^ sub) << 3);
      } else {
        int rn = n0 + i * 8 + sub - 64;
        int ch = k0 + ((c ^ sub) << 3);
        g = Bh + ((size_t)(b * 8 + (ch >> 5)) * 4096 + rn) * 32 + (ch & 31);
      }
      gl16(g, &ldsAB[i * 512]);
    }
    __syncthreads();
#pragma unroll
    for (int kk = 0; kk < 2; ++kk) {
      Frag af[2], bfr[4];
#pragma unroll
      for (int mi = 0; mi < 2; ++mi) {
        int r = mq + 16 * mi + lr;
        af[mi].u = *(const u16x8*)&ldsAB[r * 64 + (((kk * 4 + lg) ^ (r & 7)) << 3)];
      }
#pragma unroll
      for (int ni = 0; ni < 4; ++ni) {
        int rn = nq + 16 * ni + lr;
        bfr[ni].u = *(const u16x8*)&ldsAB[(64 + rn) * 64 + (((kk * 4 + lg) ^ (rn & 7)) << 3)];
      }
#pragma unroll
      for (int mi = 0; mi < 2; ++mi)
#pragma unroll
        for (int ni = 0; ni < 4; ++ni)
          acc[mi][ni] = __builtin_amdgcn_mfma_f32_16x16x32_bf16(
              af[mi].b, bfr[ni].b, acc[mi][ni], 0, 0, 0);
    }
  }

#pragma unroll
  for (int mi = 0; mi < 2; ++mi)
#pragma unroll
    for (int ni = 0; ni < 4; ++ni) {
      int mbase = m0 + mq + 16 * mi + 4 * lg;
      int n = n0 + nq + 16 * ni + lr;
#pragma unroll
      for (int j = 0; j < 4; ++j) {
        int m = mbase + j;
        size_t off = ((size_t)b * 256 + m) * 4096 + n;
        Cf[off] = acc[mi][ni][j] + bias[m] + Xres[off];
      }
    }
}

// ---------------- bilinear resize ----------------
DEVFN void blc(int y, int& i0, int& i1, float& w) {
  float fy = 0.25f * y - 0.375f;
  float ff = floorf(fy);
  w = fy - ff;
  int i = (int)ff;
  i0 = i < 0 ? 0 : i;
  i1 = (i + 1 > 15) ? 15 : i + 1;
}

__global__ __launch_bounds__(256) void k_resize(
    const float* __restrict__ qsmall, const float* __restrict__ qbias,
    u16* __restrict__ Qb) {
  int gid = blockIdx.x * 256 + threadIdx.x;
  int c8 = gid & 31;
  int p = (gid >> 5) & 4095;
  int b = gid >> 17;
  int y = p >> 6, x = p & 63;
  int y0, y1, x0, x1;
  float wy, wx;
  blc(y, y0, y1, wy);
  blc(x, x0, x1, wx);
  const float* base = qsmall + (size_t)b * 65536;
  int o0 = c8 * 8;
  const float* r00 = base + (y0 * 16 + x0) * 256 + o0;
  const float* r01 = base + (y0 * 16 + x1) * 256 + o0;
  const float* r10 = base + (y1 * 16 + x0) * 256 + o0;
  const float* r11 = base + (y1 * 16 + x1) * 256 + o0;
  float w00 = (1 - wy) * (1 - wx), w01 = (1 - wy) * wx;
  float w10 = wy * (1 - wx), w11 = wy * wx;
  u16x8 outv;
#pragma unroll
  for (int i = 0; i < 8; ++i) {
    float v = w00 * r00[i] + w01 * r01[i] + w10 * r10[i] + w11 * r11[i] + qbias[o0 + i];
    outv[i] = f2bf(v * QSC);
  }
  int head = o0 >> 5, d = o0 & 31;
  *(u16x8*)(Qb + ((size_t)(b * 8 + head) * 4096 + p) * 32 + d) = outv;
}

// ---------------- MFMA attention body (NF frags per wave) ----------------
template <int NF>
DEVFN void attn_body(const u16* __restrict__ Qb, const u16* __restrict__ Kb,
                     const u16* __restrict__ Vt, u16* __restrict__ Ob,
                     int b, int head, int lws, int i0, int by, int bx,
                     int j_begin, int j_end, int split,
                     int lane, int wv, float* smo, float* sml) {
  const int lr = lane & 15, lg = lane >> 4;
  const int addrA = (32 * (lg & 1) + lr) * 4;
  const int addrB = addrA + 64;
  const bool lo_half = (lg < 2);
  const int wsm = (1 << lws) - 1;
  const size_t hb = (size_t)(b * 8 + head) * 131072;
  auto mapP = [&](int i) { return ((by + (i >> lws)) << 6) + bx + (i & wsm); };

  Frag qf[NF];
#pragma unroll
  for (int f = 0; f < NF; ++f)
    qf[f].u = *(const u16x8*)(Qb + hb + (size_t)mapP(i0 + 16 * f + lr) * 32 + 8 * lg);

  f32x4 oT[NF][2] = {};
  float lsum[NF] = {};

  auto chunk = [&](const Frag& k0, const Frag& k1, const Frag& v0, const Frag& v1) {
#pragma unroll
    for (int f = 0; f < NF; ++f) {
      f32x4 zz = {};
      f32x4 s0 = __builtin_amdgcn_mfma_f32_16x16x32_bf16(k0.b, qf[f].b, zz, 0, 0, 0);
      f32x4 s1 = __builtin_amdgcn_mfma_f32_16x16x32_bf16(k1.b, qf[f].b, zz, 0, 0, 0);
      float p[8];
#pragma unroll
      for (int j = 0; j < 4; ++j) {
        p[j] = fexp2(s0[j]);
        p[4 + j] = fexp2(s1[j]);
      }
#pragma unroll
      for (int j = 0; j < 8; ++j) lsum[f] += p[j];
      unsigned pk0, pk1, pk2, pk3;
      asm("v_cvt_pk_bf16_f32 %0, %1, %2" : "=v"(pk0) : "v"(p[0]), "v"(p[1]));
      asm("v_cvt_pk_bf16_f32 %0, %1, %2" : "=v"(pk1) : "v"(p[2]), "v"(p[3]));
      asm("v_cvt_pk_bf16_f32 %0, %1, %2" : "=v"(pk2) : "v"(p[4]), "v"(p[5]));
      asm("v_cvt_pk_bf16_f32 %0, %1, %2" : "=v"(pk3) : "v"(p[6]), "v"(p[7]));
      int a0 = __builtin_amdgcn_ds_bpermute(addrA, (int)pk0);
      int a1 = __builtin_amdgcn_ds_bpermute(addrA, (int)pk1);
      int a2 = __builtin_amdgcn_ds_bpermute(addrB, (int)pk0);
      int a3 = __builtin_amdgcn_ds_bpermute(addrB, (int)pk1);
      int b0 = __builtin_amdgcn_ds_bpermute(addrA, (int)pk2);
      int b1 = __builtin_amdgcn_ds_bpermute(addrA, (int)pk3);
      int b2 = __builtin_amdgcn_ds_bpermute(addrB, (int)pk2);
      int b3 = __builtin_amdgcn_ds_bpermute(addrB, (int)pk3);
      union { unsigned w[4]; Frag fr; } pb;
      pb.w[0] = (unsigned)(lo_half ? a0 : b0);
      pb.w[1] = (unsigned)(lo_half ? a1 : b1);
      pb.w[2] = (unsigned)(lo_half ? a2 : b2);
      pb.w[3] = (unsigned)(lo_half ? a3 : b3);
      oT[f][0] = __builtin_amdgcn_mfma_f32_16x16x32_bf16(v0.b, pb.fr.b, oT[f][0], 0, 0, 0);
      oT[f][1] = __builtin_amdgcn_mfma_f32_16x16x32_bf16(v1.b, pb.fr.b, oT[f][1], 0, 0, 0);
    }
  };

  Frag k0A, k1A, v0A, v1A, k0B, k1B, v0B, v1B;
  auto loadKV = [&](int j0, Frag& a, Frag& c, Frag& d, Frag& e) {
    a.u = *(const u16x8*)(Kb + hb + (size_t)mapP(j0 + lr) * 32 + 8 * lg);
    c.u = *(const u16x8*)(Kb + hb + (size_t)mapP(j0 + 16 + lr) * 32 + 8 * lg);
    int poct = mapP(j0 + 8 * lg);  // 8-aligned pixel base of this lane's key-oct
    d.u = *(const u16x8*)(Vt + vt2idx(hb, lr, poct));
    e.u = *(const u16x8*)(Vt + vt2idx(hb, 16 + lr, poct));
  };

  loadKV(j_begin, k0A, k1A, v0A, v1A);
  for (int j0 = j_begin; j0 < j_end; j0 += 64) {
    loadKV(j0 + 32, k0B, k1B, v0B, v1B);
    chunk(k0A, k1A, v0A, v1A);
    if (j0 + 64 < j_end) loadKV(j0 + 64, k0A, k1A, v0A, v1A);
    chunk(k0B, k1B, v0B, v1B);
  }

  if (!split) {
#pragma unroll
    for (int f = 0; f < NF; ++f) {
      float s = lsum[f];
      s += __shfl_xor(s, 16, 64);
      s += __shfl_xor(s, 32, 64);
      float inv = 1.f / s;
      int q = i0 + 16 * f + lr;
      u16x4 lo, hi;
#pragma unroll
      for (int j = 0; j < 4; ++j) {
        lo[j] = f2bf(oT[f][0][j] * inv);
        hi[j] = f2bf(oT[f][1][j] * inv);
      }
      if (head < 5) {
        int p = mapP(q);
        u16* dst = Ob + ((size_t)(b * 8 + head) * 4096 + p) * 32;
        *(u16x4*)(dst + 4 * lg) = lo;
        *(u16x4*)(dst + 16 + 4 * lg) = hi;
      } else {
        int n = head - 5;
        int g32 = ((n * 64 + by) << 6) + q;
        int m3 = g32 % 3, sp = g32 / 3;
        u16* dst = Ob + ((size_t)(b * 8 + 5 + m3) * 4096 + sp) * 32;
        *(u16x4*)(dst + 4 * lg) = lo;
        *(u16x4*)(dst + 16 + 4 * lg) = hi;
      }
    }
    return;
  }

  if constexpr (NF == 2) {
#pragma unroll
    for (int f = 0; f < 2; ++f) {
      float s = lsum[f];
      s += __shfl_xor(s, 16, 64);
      s += __shfl_xor(s, 32, 64);
      if (lg == 0) sml[(wv * 2 + f) * 16 + lr] = s;
#pragma unroll
      for (int h = 0; h < 2; ++h)
#pragma unroll
        for (int j = 0; j < 4; ++j)
          smo[(((wv * 2 + f) * 2 + h) * 4 + j) * 64 + lane] = oT[f][h][j];
    }
    __syncthreads();
    int f = wv & 1, h = wv >> 1;
    float ot[4] = {0.f, 0.f, 0.f, 0.f};
    float ls = 0.f;
#pragma unroll
    for (int w = 0; w < 4; ++w) {
      ls += sml[(w * 2 + f) * 16 + lr];
#pragma unroll
      for (int j = 0; j < 4; ++j)
        ot[j] += smo[(((w * 2 + f) * 2 + h) * 4 + j) * 64 + lane];
    }
    float inv = 1.f / ls;
    int q = i0 + 16 * f + lr;
    int p = mapP(q);
    u16x4 v4;
#pragma unroll
    for (int j = 0; j < 4; ++j) v4[j] = f2bf(ot[j] * inv);
    u16* dst = Ob + ((size_t)(b * 8 + head) * 4096 + p) * 32 + h * 16;
    *(u16x4*)(dst + 4 * lg) = v4;
  } else {
    float ot0[4], ot1[4];
    float ls = 0.f;
#pragma unroll 1
    for (int h = 0; h < 2; ++h) {
      __syncthreads();
#pragma unroll
      for (int f = 0; f < 4; ++f) {
#pragma unroll
        for (int j = 0; j < 4; ++j) smo[((wv * 4 + f) * 4 + j) * 64 + lane] = oT[f][h][j];
        if (h == 0) {
          float s = lsum[f];
          s += __shfl_xor(s, 16, 64);
          s += __shfl_xor(s, 32, 64);
          if (lg == 0) sml[(wv * 4 + f) * 16 + lr] = s;
        }
      }
      __syncthreads();
      int f = wv;
      float* ot = (h == 0) ? ot0 : ot1;
#pragma unroll
      for (int j = 0; j < 4; ++j) ot[j] = 0.f;
#pragma unroll
      for (int w = 0; w < 4; ++w) {
        if (h == 0) ls += sml[(w * 4 + f) * 16 + lr];
#pragma unroll
        for (int j = 0; j < 4; ++j) ot[j] += smo[((w * 4 + f) * 4 + j) * 64 + lane];
      }
    }
    float inv = 1.f / ls;
    int f = wv;
    int q = i0 + 16 * f + lr;
    int p = mapP(q);
    u16x4 lo, hi;
#pragma unroll
    for (int j = 0; j < 4; ++j) {
      lo[j] = f2bf(ot0[j] * inv);
      hi[j] = f2bf(ot1[j] * inv);
    }
    u16* dst = Ob + ((size_t)(b * 8 + head) * 4096 + p) * 32;
    *(u16x4*)(dst + 4 * lg) = lo;
    *(u16x4*)(dst + 16 + 4 * lg) = hi;
  }
}

// ---------------- MFMA attention dispatcher (single 2304-block dispatch) ----------------
__global__ __launch_bounds__(256) void k_attn(
    const u16* __restrict__ Qb, const u16* __restrict__ Kb,
    const u16* __restrict__ Vt, u16* __restrict__ Ob) {
  const int t = threadIdx.x, lane = t & 63, wv = t >> 6;
  const int lr = lane & 15, lg = lane >> 4;

  __shared__ float smo[4096];
  __shared__ float sml[256];

  int vbid = blockIdx.x;
  if (vbid < 1024) {  // head4: 32-query split blocks, XCD-grouped
    int L = (vbid & 7) * 128 + (vbid >> 3);
    int b = L >> 7, g = L & 127;
    int w = g >> 5;
    attn_body<2>(Qb, Kb, Vt, Ob, b, 4, 5, (g & 31) * 32, (w >> 1) * 32, (w & 1) * 32,
                 wv * 256, wv * 256 + 256, 1, lane, wv, smo, sml);
    return;
  }
  if (vbid < 1536) {  // head3: 64q blocks, split-K 64 keys/wave
    int r = vbid - 1024;
    int b = r >> 6, g = r & 63;
    int w = g >> 2;
    attn_body<4>(Qb, Kb, Vt, Ob, b, 3, 4, (g & 3) * 64, (w >> 2) * 16, (w & 3) * 16,
                 wv * 64, wv * 64 + 64, 1, lane, wv, smo, sml);
    return;
  }
  int u = (vbid - 1536) * 4 + wv;
  const int addrA = (32 * (lg & 1) + lr) * 4;
  const int addrB = addrA + 64;
  const bool lo_half = (lg < 2);
  auto pnet16 = [&](unsigned pk0, unsigned pk1, Frag& out) {
    union { unsigned w[4]; Frag fr; } pb;
    int a0 = __builtin_amdgcn_ds_bpermute(addrA, (int)pk0);
    int a1 = __builtin_amdgcn_ds_bpermute(addrA, (int)pk1);
    int a2 = __builtin_amdgcn_ds_bpermute(addrB, (int)pk0);
    int a3 = __builtin_amdgcn_ds_bpermute(addrB, (int)pk1);
    pb.w[0] = lo_half ? (unsigned)a0 : 0u;
    pb.w[1] = lo_half ? (unsigned)a1 : 0u;
    pb.w[2] = lo_half ? (unsigned)a2 : 0u;
    pb.w[3] = lo_half ? (unsigned)a3 : 0u;
    out = pb.fr;
  };

  if (u >= 2560) {  // ws=2 (head 0)
    int r = u - 2560;
    int b2 = r >> 6;
    int qw = r & 63;
    const size_t hb0 = (size_t)(b2 * 8 + 0) * 131072;
    const bool valid = (lg == (lr >> 2));
    const int lgm = lg & 1;
#pragma unroll
    for (int f = 0; f < 4; ++f) {
      int g = qw * 4 + f;
      int W = g * 4 + (lr >> 2);
      int wbase = (W >> 5) * 128 + (W & 31) * 2;
      int qj = lr & 3;
      int posq = wbase + ((qj >> 1) << 6) + (qj & 1);
      Frag qf2, kf2;
      qf2.u = *(const u16x8*)(Qb + hb0 + (size_t)posq * 32 + 8 * lg);
      kf2.u = *(const u16x8*)(Kb + hb0 + (size_t)posq * 32 + 8 * lg);
      int W0 = g * 4 + 2 * lgm;
      int base0 = (W0 >> 5) * 128 + (W0 & 31) * 2;
      int W1 = W0 + 1;
      int base1 = (W1 >> 5) * 128 + (W1 & 31) * 2;
      Frag22 v0u, v1u;
      v0u.q[0] = *(const u16x2*)(Vt + vt2idx(hb0, lr, base0));
      v0u.q[1] = *(const u16x2*)(Vt + vt2idx(hb0, lr, base0 + 64));
      v0u.q[2] = *(const u16x2*)(Vt + vt2idx(hb0, lr, base1));
      v0u.q[3] = *(const u16x2*)(Vt + vt2idx(hb0, lr, base1 + 64));
      v1u.q[0] = *(const u16x2*)(Vt + vt2idx(hb0, 16 + lr, base0));
      v1u.q[1] = *(const u16x2*)(Vt + vt2idx(hb0, 16 + lr, base0 + 64));
      v1u.q[2] = *(const u16x2*)(Vt + vt2idx(hb0, 16 + lr, base1));
      v1u.q[3] = *(const u16x2*)(Vt + vt2idx(hb0, 16 + lr, base1 + 64));
      f32x4 zz = {};
      f32x4 s0 = __builtin_amdgcn_mfma_f32_16x16x32_bf16(kf2.b, qf2.b, zz, 0, 0, 0);
      float p[4];
      float ls = 0.f;
#pragma unroll
      for (int j = 0; j < 4; ++j) {
        p[j] = valid ? fexp2(s0[j]) : 0.f;
        ls += p[j];
      }
      unsigned pk0, pk1;
      asm("v_cvt_pk_bf16_f32 %0, %1, %2" : "=v"(pk0) : "v"(p[0]), "v"(p[1]));
      asm("v_cvt_pk_bf16_f32 %0, %1, %2" : "=v"(pk1) : "v"(p[2]), "v"(p[3]));
      Frag pfr;
      pnet16(pk0, pk1, pfr);
      f32x4 o0 = {}, o1 = {};
      o0 = __builtin_amdgcn_mfma_f32_16x16x32_bf16(v0u.b, pfr.b, o0, 0, 0, 0);
      o1 = __builtin_amdgcn_mfma_f32_16x16x32_bf16(v1u.b, pfr.b, o1, 0, 0, 0);
      ls += __shfl_xor(ls, 16, 64);
      ls += __shfl_xor(ls, 32, 64);
      float inv = 1.f / ls;
      u16x4 lo4, hi4;
#pragma unroll
      for (int j = 0; j < 4; ++j) {
        lo4[j] = f2bf(o0[j] * inv);
        hi4[j] = f2bf(o1[j] * inv);
      }
      u16* dst = Ob + ((size_t)(b2 * 8 + 0) * 4096 + posq) * 32;
      *(u16x4*)(dst + 4 * lg) = lo4;
      *(u16x4*)(dst + 16 + 4 * lg) = hi4;
    }
    return;
  }
  if (u >= 2048) {  // ws=4 (head 1)
    int r = u - 2048;
    int b4 = r >> 6;
    int qw = r & 63;
    const size_t hb1 = (size_t)(b4 * 8 + 1) * 131072;
#pragma unroll
    for (int f = 0; f < 4; ++f) {
      int w = qw * 4 + f;
      int pbase = ((w >> 4) << 8) + ((w & 15) << 2);
      int posq = pbase + ((lr >> 2) << 6) + (lr & 3);
      Frag qf4, kf4;
      qf4.u = *(const u16x8*)(Qb + hb1 + (size_t)posq * 32 + 8 * lg);
      kf4.u = *(const u16x8*)(Kb + hb1 + (size_t)posq * 32 + 8 * lg);
      int a1 = pbase + 2 * (lg & 1) * 64;
      Frag44 v0u, v1u;
      v0u.h[0] = *(const u16x4*)(Vt + vt2idx(hb1, lr, a1));
      v0u.h[1] = *(const u16x4*)(Vt + vt2idx(hb1, lr, a1 + 64));
      v1u.h[0] = *(const u16x4*)(Vt + vt2idx(hb1, 16 + lr, a1));
      v1u.h[1] = *(const u16x4*)(Vt + vt2idx(hb1, 16 + lr, a1 + 64));
      f32x4 zz = {};
      f32x4 s0 = __builtin_amdgcn_mfma_f32_16x16x32_bf16(kf4.b, qf4.b, zz, 0, 0, 0);
      float p[4];
      float ls = 0.f;
#pragma unroll
      for (int j = 0; j < 4; ++j) {
        p[j] = fexp2(s0[j]);
        ls += p[j];
      }
      unsigned pk0, pk1;
      asm("v_cvt_pk_bf16_f32 %0, %1, %2" : "=v"(pk0) : "v"(p[0]), "v"(p[1]));
      asm("v_cvt_pk_bf16_f32 %0, %1, %2" : "=v"(pk1) : "v"(p[2]), "v"(p[3]));
      Frag pfr;
      pnet16(pk0, pk1, pfr);
      f32x4 o0 = {}, o1 = {};
      o0 = __builtin_amdgcn_mfma_f32_16x16x32_bf16(v0u.b, pfr.b, o0, 0, 0, 0);
      o1 = __builtin_amdgcn_mfma_f32_16x16x32_bf16(v1u.b, pfr.b, o1, 0, 0, 0);
      ls += __shfl_xor(ls, 16, 64);
      ls += __shfl_xor(ls, 32, 64);
      float inv = 1.f / ls;
      u16x4 lo4, hi4;
#pragma unroll
      for (int j = 0; j < 4; ++j) {
        lo4[j] = f2bf(o0[j] * inv);
        hi4[j] = f2bf(o1[j] * inv);
      }
      u16* dst = Ob + ((size_t)(b4 * 8 + 1) * 4096 + posq) * 32;
      *(u16x4*)(dst + 4 * lg) = lo4;
      *(u16x4*)(dst + 16 + 4 * lg) = hi4;
    }
    return;
  }
  if (u < 512) {  // head2
    int b = u >> 6;
    int w = u & 63;
    attn_body<4>(Qb, Kb, Vt, Ob, b, 2, 3, 0, (w >> 3) * 8, (w & 7) * 8,
                 0, 64, 0, lane, wv, smo, sml);
  } else {  // row-heads 5..7
    int r = u - 512;
    int b = r / 192;
    int rr = r % 192;
    attn_body<4>(Qb, Kb, Vt, Ob, b, 5 + (rr >> 6), 6, 0, rr & 63, 0,
                 0, 64, 0, lane, wv, smo, sml);
  }
}

extern "C" void kernel_launch(void* const* d_in, const int* in_sizes, int n_in,
                              void* d_out, int out_size, void* d_ws, size_t ws_size,
                              hipStream_t stream) {
  const float* x = (const float*)d_in[0];
  const float* temp = (const float*)d_in[1];
  const float* w_qkv = (const float*)d_in[2];
  const float* w_v = (const float*)d_in[3];
  const float* w_proj = (const float*)d_in[4];
  const float* b_proj = (const float*)d_in[5];
  const float* w_temp = (const float*)d_in[6];
  const float* b_temp = (const float*)d_in[7];
  (void)in_sizes; (void)n_in; (void)out_size; (void)ws_size;

  char* ws = (char*)d_ws;
  u16* w_qt = (u16*)(ws + 0);
  u16* w_qkv_bf = (u16*)(ws + 262144);
  u16* w_proj_bf = (u16*)(ws + 524288);
  float* qbias = (float*)(ws + 655360);
  float* qsmall = (float*)(ws + 656384);
  u16* q_buf = (u16*)(ws + 2753536);
  u16* k_buf = (u16*)(ws + 19530752);
  u16* v_t = (u16*)(ws + 53085184);    // Vt2 fragment-tiled layout
  u16* o_buf = (u16*)(ws + 69862400);  // [b][h][p][32] planes (aliased: x_t before attn)
  u16* x_t = o_buf;
  float* out = (float*)d_out;

  k_stage0<<<3072, 256, 0, stream>>>(x, w_qkv, w_v, w_proj, w_temp, b_temp,
                                     w_qt, qbias, w_qkv_bf, w_proj_bf, x_t);
  k_stage1<<<2176, 256, 0, stream>>>(w_qt, temp, qsmall, w_qkv_bf, x_t, k_buf, v_t);
  k_resize<<<4096, 256, 0, stream>>>(qsmall, qbias, q_buf);
  k_attn<<<2304, 256, 0, stream>>>(q_buf, k_buf, v_t, o_buf);
  k_gemm2<<<1024, 256, 0, stream>>>(w_proj_bf, o_buf, out, b_proj, x);
}